// Round 11
// baseline (1118.839 us; speedup 1.0000x reference)
//
#include <hip/hip_runtime.h>
#include <cstdint>
#include <cstdio>

#define B_   8
#define L_   4096
#define DM_  1024
#define H_   16
#define D_   64
#define U_   45
#define BH_  (B_*H_)
#define ML_  (B_*L_)
#define NSPLIT 8
#define NP_  768           // padded QK-sample width: 16 heads * 48
#define CB_  4             // batches per chunk
#define CROWS_ (CB_*L_)    // 16384 rows per chunk
#define CAP_ 512           // candidate cap per (b,h)
#define DELTA_ 0.12f       // exact-recompute band (~9 sigma of bf16 GEMM err)

using f32x4   = __attribute__((ext_vector_type(4))) float;
using short8  = __attribute__((ext_vector_type(8))) short;
using ushort8 = __attribute__((ext_vector_type(8))) unsigned short;

__device__ __forceinline__ unsigned short f2bf(float f) {
  uint32_t u = __float_as_uint(f);
  u += 0x7fffu + ((u >> 16) & 1u);      // RNE; inputs finite
  return (unsigned short)(u >> 16);
}
__device__ __forceinline__ float bf2f(unsigned short h) {
  return __uint_as_float(((uint32_t)h) << 16);
}

__device__ __forceinline__ void gload16(const void* g, void* l) {
  __builtin_amdgcn_global_load_lds((const __attribute__((address_space(1))) void*)g,
                                   (__attribute__((address_space(3))) void*)l,
                                   16, 0, 0);
}

// ---------- split: q,k,v -> bf16 hi only ----------
__global__ __launch_bounds__(256) void split3h(const float* __restrict__ q,
    const float* __restrict__ k, const float* __restrict__ v,
    unsigned short* __restrict__ Xqh, unsigned short* __restrict__ Xkh,
    unsigned short* __restrict__ Xvh, int n4) {
  const int z = blockIdx.y;
  const float* __restrict__ X = (z == 0) ? q : ((z == 1) ? k : v);
  unsigned short* __restrict__ O = (z == 0) ? Xqh : ((z == 1) ? Xkh : Xvh);
  int i = blockIdx.x * 256 + threadIdx.x;
  const int stride = gridDim.x * 256;
  for (; i < n4; i += stride) {
    const float4 w = ((const float4*)X)[i];
    ushort4 hv;
    hv.x = f2bf(w.x); hv.y = f2bf(w.y); hv.z = f2bf(w.z); hv.w = f2bf(w.w);
    ((ushort4*)O)[i] = hv;
  }
}

// ---------- W (KxN) -> W^T bf16 (NxK) ----------
__global__ __launch_bounds__(256) void wT_single(const float* __restrict__ W,
                                                 unsigned short* __restrict__ WT) {
  const int idx = blockIdx.x * 256 + threadIdx.x;   // 1M threads
  const int n = idx >> 10, kk = idx & 1023;
  WT[idx] = f2bf(W[kk * 1024 + n]);
}

// ---------- plain bf16 GEMM, bf16 out: C = bf16(X*W + bias) ----------
__global__ __launch_bounds__(256) void gemm_plain(const unsigned short* __restrict__ Agh,
    const unsigned short* __restrict__ Bgh, const float* __restrict__ bias,
    unsigned short* __restrict__ C) {
  constexpr int K = 1024, N = 1024;
  __shared__ unsigned short sA[128 * 32];
  __shared__ unsigned short sB[128 * 32];
  const int tid = threadIdx.x, wid = tid >> 6, lane = tid & 63;
  const int m0 = blockIdx.y * 128, n0 = blockIdx.x * 128;
  const int wr = wid >> 1, wc = wid & 1;
  const int fr = lane & 15, fq = lane >> 4;
  const int srow = lane >> 2, scol = (lane & 3) * 8;
  f32x4 acc[4][4];
#pragma unroll
  for (int i = 0; i < 4; i++)
#pragma unroll
    for (int j = 0; j < 4; j++) acc[i][j] = f32x4{0.f, 0.f, 0.f, 0.f};

  for (int k0 = 0; k0 < K; k0 += 32) {
#pragma unroll
    for (int c = 0; c < 2; c++) {
      const int ch = wid * 2 + c;
      const int row = ch * 16 + srow;
      gload16(Agh + (size_t)(m0 + row) * K + (k0 + scol), &sA[ch * 512]);
      gload16(Bgh + (size_t)(n0 + row) * K + (k0 + scol), &sB[ch * 512]);
    }
    __syncthreads();
    short8 ah[4], bh[4];
#pragma unroll
    for (int i = 0; i < 4; i++) {
      ah[i] = *(const short8*)&sA[(wr * 64 + i * 16 + fr) * 32 + fq * 8];
      bh[i] = *(const short8*)&sB[(wc * 64 + i * 16 + fr) * 32 + fq * 8];
    }
#pragma unroll
    for (int i = 0; i < 4; i++)
#pragma unroll
      for (int j = 0; j < 4; j++)
        acc[i][j] = __builtin_amdgcn_mfma_f32_16x16x32_bf16(ah[i], bh[j], acc[i][j], 0, 0, 0);
    __syncthreads();
  }
#pragma unroll
  for (int j = 0; j < 4; j++) {
    const int col = n0 + wc * 64 + j * 16 + fr;
    const float bv = bias[col];
#pragma unroll
    for (int i = 0; i < 4; i++) {
      const int row = m0 + wr * 64 + i * 16 + fq * 4;
#pragma unroll
      for (int r = 0; r < 4; r++) C[(size_t)(row + r) * N + col] = f2bf(acc[i][j][r] + bv);
    }
  }
}

// ---------- plain bf16 GEMM, TRANSPOSED bf16 out: VT[(b*1024+col)][l] ----------
__global__ __launch_bounds__(256) void gemm_plainT(const unsigned short* __restrict__ Agh,
    const unsigned short* __restrict__ Bgh, const float* __restrict__ bias,
    unsigned short* __restrict__ VT, int rowbase) {
  constexpr int K = 1024;
  __shared__ unsigned short sA[128 * 32];
  __shared__ unsigned short sB[128 * 32];
  const int tid = threadIdx.x, wid = tid >> 6, lane = tid & 63;
  const int m0 = blockIdx.y * 128, n0 = blockIdx.x * 128;
  const int wr = wid >> 1, wc = wid & 1;
  const int fr = lane & 15, fq = lane >> 4;
  const int srow = lane >> 2, scol = (lane & 3) * 8;
  f32x4 acc[4][4];
#pragma unroll
  for (int i = 0; i < 4; i++)
#pragma unroll
    for (int j = 0; j < 4; j++) acc[i][j] = f32x4{0.f, 0.f, 0.f, 0.f};

  for (int k0 = 0; k0 < K; k0 += 32) {
#pragma unroll
    for (int c = 0; c < 2; c++) {
      const int ch = wid * 2 + c;
      const int row = ch * 16 + srow;
      gload16(Agh + (size_t)(m0 + row) * K + (k0 + scol), &sA[ch * 512]);
      gload16(Bgh + (size_t)(n0 + row) * K + (k0 + scol), &sB[ch * 512]);
    }
    __syncthreads();
    short8 ah[4], bh[4];
#pragma unroll
    for (int i = 0; i < 4; i++) {
      ah[i] = *(const short8*)&sA[(wr * 64 + i * 16 + fr) * 32 + fq * 8];
      bh[i] = *(const short8*)&sB[(wc * 64 + i * 16 + fr) * 32 + fq * 8];
    }
#pragma unroll
    for (int i = 0; i < 4; i++)
#pragma unroll
      for (int j = 0; j < 4; j++)
        acc[i][j] = __builtin_amdgcn_mfma_f32_16x16x32_bf16(ah[i], bh[j], acc[i][j], 0, 0, 0);
    __syncthreads();
  }
#pragma unroll
  for (int j = 0; j < 4; j++) {
    const int col = n0 + wc * 64 + j * 16 + fr;
    const float bv = bias[col];
#pragma unroll
    for (int i = 0; i < 4; i++) {
      const int grow = rowbase + m0 + wr * 64 + i * 16 + fq * 4;
      const int b = grow >> 12, l = grow & 4095;    // L_ = 4096
      ushort4 hv;
      hv.x = f2bf(acc[i][j][0] + bv);
      hv.y = f2bf(acc[i][j][1] + bv);
      hv.z = f2bf(acc[i][j][2] + bv);
      hv.w = f2bf(acc[i][j][3] + bv);
      *(ushort4*)&VT[((size_t)(b * 1024 + col)) * L_ + l] = hv;
    }
  }
}

// ---------- plain bf16 GEMM: QKs = Xq * P_b (fp32 out, N=768) ----------
__global__ __launch_bounds__(256) void gemm_qk1(const unsigned short* __restrict__ Agh,
    const unsigned short* __restrict__ Pall_h, float* __restrict__ C, int chunk) {
  constexpr int K = 1024;
  __shared__ unsigned short sA[128 * 32];
  __shared__ unsigned short sB[128 * 32];
  const int tid = threadIdx.x, wid = tid >> 6, lane = tid & 63;
  const int m0 = blockIdx.y * 128, n0 = blockIdx.x * 128;
  const int batch = chunk * CB_ + (blockIdx.y >> 5);
  const unsigned short* __restrict__ Bgh = Pall_h + (size_t)batch * NP_ * K;
  const int wr = wid >> 1, wc = wid & 1;
  const int fr = lane & 15, fq = lane >> 4;
  const int srow = lane >> 2, scol = (lane & 3) * 8;
  f32x4 acc[4][4];
#pragma unroll
  for (int i = 0; i < 4; i++)
#pragma unroll
    for (int j = 0; j < 4; j++) acc[i][j] = f32x4{0.f, 0.f, 0.f, 0.f};

  for (int k0 = 0; k0 < K; k0 += 32) {
#pragma unroll
    for (int c = 0; c < 2; c++) {
      const int ch = wid * 2 + c;
      const int row = ch * 16 + srow;
      gload16(Agh + (size_t)(m0 + row) * K + (k0 + scol), &sA[ch * 512]);
      gload16(Bgh + (size_t)(n0 + row) * K + (k0 + scol), &sB[ch * 512]);
    }
    __syncthreads();
    short8 ah[4], bh[4];
#pragma unroll
    for (int i = 0; i < 4; i++) {
      ah[i] = *(const short8*)&sA[(wr * 64 + i * 16 + fr) * 32 + fq * 8];
      bh[i] = *(const short8*)&sB[(wc * 64 + i * 16 + fr) * 32 + fq * 8];
    }
#pragma unroll
    for (int i = 0; i < 4; i++)
#pragma unroll
      for (int j = 0; j < 4; j++)
        acc[i][j] = __builtin_amdgcn_mfma_f32_16x16x32_bf16(ah[i], bh[j], acc[i][j], 0, 0, 0);
    __syncthreads();
  }
#pragma unroll
  for (int j = 0; j < 4; j++) {
    const int col = n0 + wc * 64 + j * 16 + fr;
#pragma unroll
    for (int i = 0; i < 4; i++) {
      const int row = m0 + wr * 64 + i * 16 + fq * 4;
#pragma unroll
      for (int r = 0; r < 4; r++) C[(size_t)(row + r) * NP_ + col] = acc[i][j][r];
    }
  }
}

// ---------- ksel3: exact fp32 sampled-K rows, split-K column-parallel ----------
__global__ __launch_bounds__(256) void ksel3(const float* __restrict__ X,
    const float* __restrict__ Wk, const int* __restrict__ sidx,
    float* __restrict__ kpart) {
  const int t = threadIdx.x;
  const int col = blockIdx.x * 256 + t;
  const int b = blockIdx.y;
  const int ug = blockIdx.z >> 2, kc = blockIdx.z & 3;
  __shared__ float Xs[15][256];
  __shared__ int rows[15];
  if (t < 15) rows[t] = sidx[ug * 15 + t];
  __syncthreads();
#pragma unroll
  for (int i = 0; i < 15; i++)
    Xs[i][t] = X[((size_t)b * L_ + rows[i]) * DM_ + kc * 256 + t];
  __syncthreads();
  float acc[15];
#pragma unroll
  for (int r = 0; r < 15; r++) acc[r] = 0.f;
  for (int k4 = 0; k4 < 64; k4++) {
    const int kb = kc * 256 + k4 * 4;
    const float w0 = Wk[(size_t)(kb + 0) * DM_ + col];
    const float w1 = Wk[(size_t)(kb + 1) * DM_ + col];
    const float w2 = Wk[(size_t)(kb + 2) * DM_ + col];
    const float w3 = Wk[(size_t)(kb + 3) * DM_ + col];
#pragma unroll
    for (int r = 0; r < 15; r++) {
      const float4 x = *(const float4*)&Xs[r][k4 * 4];
      acc[r] += x.x * w0 + x.y * w1 + x.z * w2 + x.w * w3;
    }
  }
  float* dst = kpart + (((size_t)kc * B_ + b) * U_ + ug * 15) * 1024 + col;
#pragma unroll
  for (int r = 0; r < 15; r++) dst[(size_t)r * 1024] = acc[r];
}

// combine: Ksamp = sum_kc kpart + bias (fixed order)
__global__ __launch_bounds__(256) void ksel_comb(const float* __restrict__ kpart,
    const float* __restrict__ bk, float* __restrict__ Ksamp) {
  const int idx = blockIdx.x * 256 + threadIdx.x;   // < 360*1024
  const int col = idx & 1023, ru = idx >> 10;
  const int b = ru / U_, u = ru - b * U_;
  const size_t o = ((size_t)b * U_ + u) * 1024 + col;
  const size_t stride = (size_t)B_ * U_ * 1024;
  float s = kpart[o] + kpart[o + stride] + kpart[o + 2 * stride] + kpart[o + 3 * stride]
          + bk[col];
  const int h = col >> 6, d = col & 63;
  Ksamp[((size_t)(b * 16 + h) * U_ + u) * 64 + d] = s;
}

// ---------- P^T[b][h*48+u][k] = sum_d Wq[k][h*64+d]*Ksamp (bf16 hi) ----------
__global__ __launch_bounds__(256) void pform_k(const float* __restrict__ Wq,
    const float* __restrict__ Ksamp, unsigned short* __restrict__ Ph) {
  const int bh = blockIdx.x, b = bh >> 4, h = bh & 15;
  __shared__ float Ks[U_][68];
  const int t = threadIdx.x;
  for (int e = t; e < U_ * 64; e += 256) {
    const int u = e >> 6, d = e & 63;
    Ks[u][d] = Ksamp[((size_t)bh * U_ + u) * 64 + d];
  }
  __syncthreads();
  for (int kc = 0; kc < 4; kc++) {
    const int k = kc * 256 + t;
    float wr[64];
#pragma unroll
    for (int dd = 0; dd < 16; dd++) {
      const float4 w4 = *(const float4*)&Wq[(size_t)k * DM_ + h * 64 + dd * 4];
      wr[dd * 4 + 0] = w4.x; wr[dd * 4 + 1] = w4.y;
      wr[dd * 4 + 2] = w4.z; wr[dd * 4 + 3] = w4.w;
    }
    for (int u = 0; u < 48; u++) {
      size_t o = ((size_t)b * NP_ + h * 48 + u) * 1024 + k;
      if (u < U_) {
        float acc = 0.f;
#pragma unroll
        for (int d = 0; d < 64; d++) acc += wr[d] * Ks[u][d];
        Ph[o] = f2bf(acc);
      } else {
        Ph[o] = 0;
      }
    }
  }
}

// ---------- M_approx = max - mean over u ----------
__global__ __launch_bounds__(256) void mpass_k(const float* __restrict__ QKs,
                                               float* __restrict__ Mbuf, int chunk) {
  const int idx = blockIdx.x * 256 + threadIdx.x;   // < CROWS_*16
  const int ll = idx >> 4, h = idx & 15;
  const float* row = QKs + (size_t)ll * NP_ + h * 48;
  float mx = row[0], sm = row[0];
#pragma unroll
  for (int u = 1; u < U_; u++) { const float v = row[u]; mx = fmaxf(mx, v); sm += v; }
  const int lg = chunk * CROWS_ + ll;
  const int b = lg >> 12, l = lg & 4095;
  Mbuf[((size_t)(b * 16 + h)) * L_ + l] = mx - sm * (1.f / (float)U_);
}

// ---------- select_a: approx top-45 -> thr; candidates = {M >= thr - DELTA} ----------
__global__ __launch_bounds__(256) void select_a(const float* __restrict__ Mbuf,
    int* __restrict__ list, int* __restrict__ cnt) {
  const int bh = blockIdx.x, t = threadIdx.x;
  __shared__ float vals[L_];
  __shared__ float rv[256];
  __shared__ int   ri[256];
  __shared__ int   scnt;
  __shared__ float sthr;
  if (t == 0) scnt = 0;
  for (int i = t; i < L_; i += 256) vals[i] = Mbuf[(size_t)bh * L_ + i];
  __syncthreads();
  for (int it = 0; it < U_; it++) {
    float bv = vals[t * 16]; int bi = t * 16;
#pragma unroll
    for (int jj = 1; jj < 16; jj++) {
      const float v = vals[t * 16 + jj];
      if (v > bv) { bv = v; bi = t * 16 + jj; }
    }
    rv[t] = bv; ri[t] = bi;
    __syncthreads();
    for (int s = 128; s > 0; s >>= 1) {
      if (t < s) {
        if (rv[t + s] > rv[t] || (rv[t + s] == rv[t] && ri[t + s] < ri[t])) {
          rv[t] = rv[t + s]; ri[t] = ri[t + s];
        }
      }
      __syncthreads();
    }
    if (t == 0) {
      list[(size_t)bh * CAP_ + it] = ri[0];
      vals[ri[0]] = -3.4e38f;
      if (it == U_ - 1) sthr = rv[0];
    }
    __syncthreads();
  }
  const float lim = sthr - DELTA_;
  for (int i = t; i < L_; i += 256) {
    if (vals[i] >= lim) {
      const int j = atomicAdd(&scnt, 1);
      if (U_ + j < CAP_) list[(size_t)bh * CAP_ + U_ + j] = i;
    }
  }
  __syncthreads();
  if (t == 0) cnt[bh] = min(U_ + scnt, CAP_);
}

// ---------- exactM2: fp32 recompute of M for candidates ----------
__global__ __launch_bounds__(256) void exactM2(const float* __restrict__ X,
    const float* __restrict__ Wq, const float* __restrict__ bq,
    const float* __restrict__ Ksamp, const int* __restrict__ list,
    const int* __restrict__ cnt, float* __restrict__ candM) {
  const int bh = blockIdx.x, g = blockIdx.y, b = bh >> 4, h = bh & 15;
  __shared__ float Ks[U_][68];
  __shared__ float Xs[8][256];
  __shared__ float red[4][8][64];
  __shared__ float qd[8][68];
  __shared__ float sc[8][45];
  __shared__ int rows[8];
  const int t = threadIdx.x, p = t >> 6, d = t & 63;
  for (int e = t; e < U_ * 64; e += 256) {
    const int u = e >> 6, dd = e & 63;
    Ks[u][dd] = Ksamp[((size_t)bh * U_ + u) * 64 + dd];
  }
  const int n = cnt[bh];
  const int stride = 8 * gridDim.y;
  for (int c0 = g * 8; c0 < n; c0 += stride) {
    const int nc = min(8, n - c0);
    __syncthreads();
    if (t < 8) rows[t] = list[(size_t)bh * CAP_ + c0 + min(t, nc - 1)];
    float acc[8];
#pragma unroll
    for (int r = 0; r < 8; r++) acc[r] = 0.f;
    for (int kc = 0; kc < 4; kc++) {
      __syncthreads();
#pragma unroll
      for (int i = 0; i < 8; i++)
        Xs[i][t] = X[((size_t)b * L_ + rows[i]) * DM_ + kc * 256 + t];
      __syncthreads();
#pragma unroll
      for (int k4 = 0; k4 < 16; k4++) {
        const int kb = kc * 256 + p * 64 + k4 * 4;
        const float w0 = Wq[(size_t)(kb + 0) * DM_ + h * 64 + d];
        const float w1 = Wq[(size_t)(kb + 1) * DM_ + h * 64 + d];
        const float w2 = Wq[(size_t)(kb + 2) * DM_ + h * 64 + d];
        const float w3 = Wq[(size_t)(kb + 3) * DM_ + h * 64 + d];
#pragma unroll
        for (int r = 0; r < 8; r++) {
          const float4 x = *(const float4*)&Xs[r][p * 64 + k4 * 4];
          acc[r] += x.x * w0 + x.y * w1 + x.z * w2 + x.w * w3;
        }
      }
    }
#pragma unroll
    for (int r = 0; r < 8; r++) red[p][r][d] = acc[r];
    __syncthreads();
    if (p == 0) {
#pragma unroll
      for (int r = 0; r < 8; r++)
        qd[r][d] = red[0][r][d] + red[1][r][d] + red[2][r][d] + red[3][r][d] + bq[h * 64 + d];
    }
    __syncthreads();
    for (int idx = t; idx < 8 * U_; idx += 256) {
      const int c = idx / U_, u = idx - c * U_;
      float s = 0.f;
#pragma unroll 8
      for (int dd = 0; dd < 64; dd++) s += qd[c][dd] * Ks[u][dd];
      sc[c][u] = s;
    }
    __syncthreads();
    if (t < nc) {
      float mx = sc[t][0], sm = sc[t][0];
      for (int u = 1; u < U_; u++) { mx = fmaxf(mx, sc[t][u]); sm += sc[t][u]; }
      candM[(size_t)bh * CAP_ + c0 + t] = mx - sm * (1.f / (float)U_);
    }
  }
}

// ---------- select_b: final top-45 over candidates (exact M, idx tie-break) ----------
__global__ __launch_bounds__(256) void select_b(const float* __restrict__ candM,
    const int* __restrict__ list, const int* __restrict__ cnt, int* __restrict__ topidx) {
  const int bh = blockIdx.x, t = threadIdx.x;
  __shared__ float mv[CAP_];
  __shared__ int   ml[CAP_];
  __shared__ float rv[256];
  __shared__ int   ri[256];
  const int n = cnt[bh];
  for (int i = t; i < CAP_; i += 256) {
    mv[i] = (i < n) ? candM[(size_t)bh * CAP_ + i] : -3.4e38f;
    ml[i] = (i < n) ? list[(size_t)bh * CAP_ + i] : 0x7fffffff;
  }
  __syncthreads();
  for (int it = 0; it < U_; it++) {
    float bv = mv[t]; int bi = ml[t]; int bj = t;
    {
      const float v = mv[t + 256]; const int l2 = ml[t + 256];
      if (v > bv || (v == bv && l2 < bi)) { bv = v; bi = l2; bj = t + 256; }
    }
    rv[t] = bv; ri[t] = bj;
    __syncthreads();
    for (int s = 128; s > 0; s >>= 1) {
      if (t < s) {
        const float v2 = rv[t + s];
        const int slot2 = ri[t + s];
        if (v2 > rv[t] || (v2 == rv[t] && ml[slot2] < ml[ri[t]])) {
          rv[t] = v2; ri[t] = slot2;
        }
      }
      __syncthreads();
    }
    if (t == 0) {
      topidx[bh * U_ + it] = ml[ri[0]];
      mv[ri[0]] = -3.4e38f;
    }
    __syncthreads();
  }
}

// ---------- qsel3: exact selected Q rows, split-K partials ----------
__global__ __launch_bounds__(256) void qsel3(const float* __restrict__ X,
    const float* __restrict__ Wq, const int* __restrict__ topidx,
    float* __restrict__ qpart) {
  const int bh = blockIdx.x;
  const int ug = blockIdx.y >> 2, kc = blockIdx.y & 3;
  const int b = bh >> 4, h = bh & 15;
  __shared__ float Xs[15][256];
  __shared__ int rows[15];
  const int t = threadIdx.x, p = t >> 6, d = t & 63;
  if (t < 15) rows[t] = topidx[bh * U_ + ug * 15 + t];
  __syncthreads();
#pragma unroll
  for (int i = 0; i < 15; i++)
    Xs[i][t] = X[((size_t)b * L_ + rows[i]) * DM_ + kc * 256 + t];
  __syncthreads();
  float acc[15];
#pragma unroll
  for (int r = 0; r < 15; r++) acc[r] = 0.f;
#pragma unroll
  for (int k4 = 0; k4 < 16; k4++) {
    const int kb = kc * 256 + p * 64 + k4 * 4;
    const float w0 = Wq[(size_t)(kb + 0) * DM_ + h * 64 + d];
    const float w1 = Wq[(size_t)(kb + 1) * DM_ + h * 64 + d];
    const float w2 = Wq[(size_t)(kb + 2) * DM_ + h * 64 + d];
    const float w3 = Wq[(size_t)(kb + 3) * DM_ + h * 64 + d];
#pragma unroll
    for (int r = 0; r < 15; r++) {
      const float4 x = *(const float4*)&Xs[r][p * 64 + k4 * 4];
      acc[r] += x.x * w0 + x.y * w1 + x.z * w2 + x.w * w3;
    }
  }
  const int p16 = kc * 4 + p;       // partial slot 0..15
  float* dst = qpart + (((size_t)p16 * BH_ + bh) * 48 + ug * 15) * 64 + d;
#pragma unroll
  for (int r = 0; r < 15; r++) dst[(size_t)r * 64] = acc[r];
}

// combine 16 partials (fixed order) + bias -> bf16 Qbf; zero pad rows
__global__ __launch_bounds__(256) void qsel_comb(const float* __restrict__ qpart,
    const float* __restrict__ bq, unsigned short* __restrict__ Qbf) {
  const int idx = blockIdx.x * 256 + threadIdx.x;   // < BH_*48*64
  const int d = idx & 63, u48 = (idx >> 6) % 48, bh = idx / (48 * 64);
  const int h = bh & 15;
  if (u48 < U_) {
    const size_t o = (((size_t)bh) * 48 + u48) * 64 + d;
    const size_t stride = (size_t)BH_ * 48 * 64;
    float s = bq[h * 64 + d];
#pragma unroll
    for (int p16 = 0; p16 < 16; p16++) s += qpart[o + (size_t)p16 * stride];
    Qbf[o] = f2bf(s);
  } else {
    Qbf[(((size_t)bh) * 48 + u48) * 64 + d] = 0;
  }
}

// ---------- V mean from V^T rows (contiguous, deterministic) ----------
__global__ __launch_bounds__(256) void vmean_vt(const unsigned short* __restrict__ VT,
                                                float* __restrict__ Vm) {
  const int row = blockIdx.x * 4 + (threadIdx.x >> 6);   // 8192 rows total
  const int lane = threadIdx.x & 63;
  const unsigned short* src = VT + (size_t)row * L_ + lane * 64;
  float s = 0.f;
#pragma unroll
  for (int c = 0; c < 8; c++) {
    const ushort8 v = *(const ushort8*)&src[c * 8];
#pragma unroll
    for (int x = 0; x < 8; x++) s += bf2f(v[x]);
  }
  for (int off = 32; off > 0; off >>= 1) s += __shfl_xor(s, off);
  if (lane == 0) Vm[row] = s * (1.f / (float)L_);
}

// ---------- stage1: MFMA QK^T + MFMA PV over bf16 P; no-max softmax ----------
__global__ __launch_bounds__(256) void attn_stage1(const unsigned short* __restrict__ Qbf,
    const unsigned short* __restrict__ Kbf, const unsigned short* __restrict__ VT,
    float* __restrict__ part) {
  const int bh = blockIdx.x, split = blockIdx.y;
  const int b = bh >> 4, h = bh & 15;
  __shared__ unsigned short sQ[48][72];
  __shared__ unsigned short sK[64][72];
  __shared__ unsigned short sVT[64][72];   // [d][key]
  __shared__ unsigned short esb[48][68];   // P bf16 [q][key]
  __shared__ float sS[4][48];
  __shared__ float S_total[48];
  const int tid = threadIdx.x, wid = tid >> 6, lane = tid & 63;
  const int fr = lane & 15, fq = lane >> 4;
  for (int e = tid; e < 48 * 8; e += 256) {
    const int r = e >> 3, c8 = (e & 7) * 8;
    *(ushort8*)&sQ[r][c8] = *(const ushort8*)&Qbf[((size_t)bh * 48 + r) * 64 + c8];
  }
  if (tid < 48) S_total[tid] = 0.f;
  __syncthreads();
  short8 qf[3][2];
#pragma unroll
  for (int nt = 0; nt < 3; nt++)
#pragma unroll
    for (int kh = 0; kh < 2; kh++)
      qf[nt][kh] = *(const short8*)&sQ[nt * 16 + fr][kh * 32 + fq * 8];

  f32x4 acc[3];
#pragma unroll
  for (int mt = 0; mt < 3; mt++) acc[mt] = f32x4{0.f, 0.f, 0.f, 0.f};

  for (int t = 0; t < 8; t++) {
    const int k0 = split * 512 + t * 64;
    if (t) __syncthreads();               // barrier A: prev PV + S_total add done
    for (int e = tid; e < 64 * 8; e += 256) {
      const int r = e >> 3, c8 = (e & 7) * 8;
      *(ushort8*)&sK[r][c8] =
          *(const ushort8*)&Kbf[((size_t)b * L_ + k0 + r) * DM_ + h * 64 + c8];
      *(ushort8*)&sVT[r][c8] =
          *(const ushort8*)&VT[((size_t)(b * 1024 + h * 64 + r)) * L_ + k0 + c8];
    }
    __syncthreads();                      // barrier B
    // QK^T: wave wid owns keys wid*16..+15 (m), all 48 q (n)
    const short8 kf0 = *(const short8*)&sK[wid * 16 + fr][fq * 8];
    const short8 kf1 = *(const short8*)&sK[wid * 16 + fr][32 + fq * 8];
    f32x4 accq[3];
#pragma unroll
    for (int nt = 0; nt < 3; nt++) {
      accq[nt] = f32x4{0.f, 0.f, 0.f, 0.f};
      accq[nt] = __builtin_amdgcn_mfma_f32_16x16x32_bf16(kf0, qf[nt][0], accq[nt], 0, 0, 0);
      accq[nt] = __builtin_amdgcn_mfma_f32_16x16x32_bf16(kf1, qf[nt][1], accq[nt], 0, 0, 0);
    }
    // exp -> bf16 P stored [q][key]; per-lane S partials reduced via shfl
#pragma unroll
    for (int nt = 0; nt < 3; nt++) {
      float sp = 0.f;
#pragma unroll
      for (int r = 0; r < 4; r++) {
        const float e = expf(accq[nt][r] * 0.125f);   // |score| bounded: no max
        sp += e;
        esb[nt * 16 + fr][wid * 16 + fq * 4 + r] = f2bf(e);
      }
      sp += __shfl_xor(sp, 16);
      sp += __shfl_xor(sp, 32);
      if (fq == 0) sS[wid][nt * 16 + fr] = sp;
    }
    __syncthreads();                      // barrier C
    if (tid < 48) S_total[tid] += sS[0][tid] + sS[1][tid] + sS[2][tid] + sS[3][tid];
    // PV: wave wid owns d-cols wid*16..+15 (n), all 48 q (m), K=64 keys
    const short8 vb0 = *(const short8*)&sVT[wid * 16 + fr][fq * 8];
    const short8 vb1 = *(const short8*)&sVT[wid * 16 + fr][32 + fq * 8];
#pragma unroll
    for (int mt = 0; mt < 3; mt++) {
      const short8 pa0 = *(const short8*)&esb[mt * 16 + fr][fq * 8];
      const short8 pa1 = *(const short8*)&esb[mt * 16 + fr][32 + fq * 8];
      acc[mt] = __builtin_amdgcn_mfma_f32_16x16x32_bf16(pa0, vb0, acc[mt], 0, 0, 0);
      acc[mt] = __builtin_amdgcn_mfma_f32_16x16x32_bf16(pa1, vb1, acc[mt], 0, 0, 0);
    }
  }
  __syncthreads();
  // ctx[q][d]: q = mt*16 + fq*4 + r, d = wid*16 + fr
#pragma unroll
  for (int u = 0; u < U_; u++) {
    const int mt = u >> 4, fqq = (u >> 2) & 3, r = u & 3;
    float* pb = part + ((size_t)(bh * NSPLIT + split) * U_ + u) * 65;
    if (fq == fqq) pb[1 + wid * 16 + fr] = acc[mt][r];
    if (tid == fqq * 16) pb[0] = S_total[u];
  }
}

// ---------- combine splits; dctx = ctx/S - Vmean ----------
__global__ __launch_bounds__(256) void attn_stage2(const float* __restrict__ part,
    const float* __restrict__ Vm, float* __restrict__ dctx) {
  const int bh = blockIdx.x;
  const int wid = threadIdx.x >> 6, lane = threadIdx.x & 63;
  for (int u = wid; u < U_; u += 4) {
    float S = 0.f, c = 0.f;
#pragma unroll
    for (int sp = 0; sp < NSPLIT; sp++) {
      const float* pb = part + ((size_t)(bh * NSPLIT + sp) * U_ + u) * 65;
      S += pb[0];
      c += pb[1 + lane];
    }
    dctx[((size_t)bh * U_ + u) * 64 + lane] = c / S - Vm[bh * 64 + lane];
  }
}

// ---------- base[b][:] = concat_h(Vmean) @ Wo + bo ----------
__global__ __launch_bounds__(256) void base_k(const float* __restrict__ Vm,
    const float* __restrict__ Wo, const float* __restrict__ bo, float* __restrict__ base) {
  const int b = blockIdx.y;
  const int j = blockIdx.x * 256 + threadIdx.x;
  float acc = bo[j];
#pragma unroll 8
  for (int i = 0; i < DM_; i++) acc += Vm[b * DM_ + i] * Wo[(size_t)i * DM_ + j];
  base[b * DM_ + j] = acc;
}

// ---------- out[b,l,:] = base[b,:] ----------
__global__ __launch_bounds__(256) void fill_out(const float* __restrict__ base,
                                                float* __restrict__ out) {
  const size_t g = ((size_t)blockIdx.x * 256 + threadIdx.x) * 4;
  const int b = (int)(g >> 22), j = (int)(g & 1023);
  *(float4*)&out[g] = *(const float4*)&base[(b << 10) + j];
}

// ---------- gemm_upd: rowupd[bh][u][:] = dctx[bh] @ Wo_h ----------
__global__ __launch_bounds__(256) void gemm_upd(const float* __restrict__ dctx,
    const float* __restrict__ Wo, float* __restrict__ rowupd) {
  const int bh = blockIdx.y, h = bh & 15;
  const int col = blockIdx.x * 256 + threadIdx.x;
  __shared__ float dc[U_][68];
  for (int e = threadIdx.x; e < U_ * 64; e += 256) {
    const int u = e >> 6, d = e & 63;
    dc[u][d] = dctx[(size_t)bh * U_ * 64 + e];
  }
  __syncthreads();
  float acc[U_];
#pragma unroll
  for (int u = 0; u < U_; u++) acc[u] = 0.f;
  for (int d = 0; d < 64; d++) {
    const float w = Wo[(size_t)(h * 64 + d) * DM_ + col];
#pragma unroll
    for (int u = 0; u < U_; u++) acc[u] += dc[u][d] * w;   // dc broadcast read
  }
#pragma unroll
  for (int u = 0; u < U_; u++)
    rowupd[((size_t)bh * U_ + u) * DM_ + col] = acc[u];
}

// ---------- build_list: per selected row, head-mask + slot; unique-row list ----------
__global__ __launch_bounds__(256) void build_list(const int* __restrict__ topidx,
    int* __restrict__ rowmask, unsigned char* __restrict__ slotU,
    int* __restrict__ uniq, int* __restrict__ uniqCnt) {
  const int i = blockIdx.x * 256 + threadIdx.x;
  if (i >= BH_ * U_) return;
  const int bh = i / U_, u = i - bh * U_;
  const int b = bh >> 4, h = bh & 15;
  const int key = b * L_ + topidx[i];
  slotU[key * 16 + h] = (unsigned char)u;
  const int old = atomicOr(&rowmask[key], 1 << h);
  if (old == 0) {
    const int q = atomicAdd(uniqCnt, 1);
    uniq[q] = key;
  }
}

// ---------- scatter3: one block per unique row; fixed h-order sum; plain write ----------
__global__ __launch_bounds__(256) void scatter3(const float* __restrict__ rowupd,
    const float* __restrict__ base, const int* __restrict__ rowmask,
    const unsigned char* __restrict__ slotU, const int* __restrict__ uniq,
    const int* __restrict__ uniqCnt, float* __restrict__ out) {
  const int idx = blockIdx.x;
  if (idx >= *uniqCnt) return;
  const int key = uniq[idx];
  const int b = key >> 12;                       // L_ = 4096
  const int mask = rowmask[key];
  const int j4 = threadIdx.x * 4;
  float4 a = *(const float4*)&base[b * DM_ + j4];
#pragma unroll
  for (int h = 0; h < 16; h++) {
    if (mask & (1 << h)) {
      const int u = slotU[key * 16 + h];
      const float4 r = *(const float4*)&rowupd[((size_t)(b * 16 + h) * U_ + u) * DM_ + j4];
      a.x += r.x; a.y += r.y; a.z += r.z; a.w += r.w;
    }
  }
  *(float4*)&out[(size_t)key * DM_ + j4] = a;
}

extern "C" void kernel_launch(void* const* d_in, const int* in_sizes, int n_in,
                              void* d_out, int out_size, void* d_ws, size_t ws_size,
                              hipStream_t stream) {
  const float* queries = (const float*)d_in[0];
  const float* keys    = (const float*)d_in[1];
  const float* values  = (const float*)d_in[2];
  const float* Wq = (const float*)d_in[3]; const float* bq = (const float*)d_in[4];
  const float* Wk = (const float*)d_in[5]; const float* bk = (const float*)d_in[6];
  const float* Wv = (const float*)d_in[7]; const float* bv = (const float*)d_in[8];
  const float* Wo = (const float*)d_in[9]; const float* bo = (const float*)d_in[10];
  const int* sidx = (const int*)d_in[11];

  // K (row-major) and V^T live as bf16 in d_out until the epilogue
  unsigned short* Kbf = (unsigned short*)d_out;
  unsigned short* VT  = Kbf + (size_t)ML_ * DM_;

  uint8_t* p = (uint8_t*)d_ws;
  auto carve = [&](size_t bytes) { uint8_t* r = p; p += (bytes + 255) & ~(size_t)255; return r; };
  unsigned short* Xqh = (unsigned short*)carve((size_t)CROWS_ * DM_ * 2);   // 33.6 MB
  unsigned short* Xkh = (unsigned short*)carve((size_t)CROWS_ * DM_ * 2);
  unsigned short* Xvh = (unsigned short*)carve((size_t)CROWS_ * DM_ * 2);
  float* QKs = (float*)carve((size_t)CROWS_ * NP_ * 4);                     // 50.3 MB
  unsigned short* Ph = (unsigned short*)carve((size_t)B_ * NP_ * DM_ * 2);  // 12.6 MB
  unsigned short* WkT = (unsigned short*)carve((size_t)DM_ * DM_ * 2);
  unsigned short* WvT = (unsigned short*)carve((size_t)DM_ * DM_ * 2);
  float* Mbuf  = (float*)carve((size_t)BH_ * L_ * 4);                       // 2.1 MB
  float* Ksamp = (float*)carve((size_t)BH_ * U_ * 64 * 4);                  // 1.5 MB
  float* kpart = (float*)carve((size_t)4 * B_ * U_ * 1024 * 4);             // 5.9 MB
  float* qpart = (float*)carve((size_t)16 * BH_ * 48 * 64 * 4);             // 25.2 MB
  int*   list  = (int*)carve((size_t)BH_ * CAP_ * 4);                       // 256 KB
  float* candM = (float*)carve((size_t)BH_ * CAP_ * 4);                     // 256 KB
  int*   cntb  = (int*)carve((size_t)BH_ * 4);
  int*   topidx = (int*)carve((size_t)BH_ * U_ * 4);
  float* Vm    = (float*)carve((size_t)BH_ * 64 * 4);
  unsigned short* Qbf = (unsigned short*)carve((size_t)BH_ * 48 * 64 * 2);  // 786 KB
  int*   rowmask = (int*)carve((size_t)B_ * L_ * 4);                        // 128 KB (memset)
  int*   uniqCnt = (int*)carve(256);                                        // (memset)
  unsigned char* slotU = (unsigned char*)carve((size_t)B_ * L_ * 16);       // 512 KB
  int*   uniq  = (int*)carve((size_t)BH_ * U_ * 4);                         // 23 KB
  const size_t need = (size_t)(p - (uint8_t*)d_ws);
  if (ws_size < need)
    fprintf(stderr, "ATHENA_WS: need %zu have %zu (WILL FAULT)\n", need, ws_size);

  // late-phase buffers alias QKs (dead after mpass)
  uint8_t* ap = (uint8_t*)QKs;
  auto acarve = [&](size_t bytes) { uint8_t* r = ap; ap += (bytes + 255) & ~(size_t)255; return r; };
  float* part  = (float*)acarve((size_t)BH_ * NSPLIT * U_ * 65 * 4);        // 12 MB
  float* dctx  = (float*)acarve((size_t)BH_ * U_ * 64 * 4);
  float* base  = (float*)acarve((size_t)B_ * DM_ * 4);
  float* rowupd = (float*)acarve((size_t)BH_ * U_ * DM_ * 4);               // 23.6 MB

  ksel3<<<dim3(4, B_, 12), 256, 0, stream>>>(keys, Wk, sidx, kpart);
  ksel_comb<<<(B_ * U_ * 1024) / 256, 256, 0, stream>>>(kpart, bk, Ksamp);
  pform_k<<<BH_, 256, 0, stream>>>(Wq, Ksamp, Ph);
  wT_single<<<4096, 256, 0, stream>>>(Wk, WkT);
  wT_single<<<4096, 256, 0, stream>>>(Wv, WvT);

  const int n4 = (int)((size_t)CROWS_ * DM_ / 4);
  for (int c = 0; c < 2; c++) {
    const size_t off = (size_t)c * CROWS_ * DM_;
    split3h<<<dim3(2048, 3), 256, 0, stream>>>(queries + off, keys + off, values + off,
                                               Xqh, Xkh, Xvh, n4);
    gemm_plain<<<dim3(8, 128), 256, 0, stream>>>(Xkh, WkT, bk, Kbf + off);
    gemm_plainT<<<dim3(8, 128), 256, 0, stream>>>(Xvh, WvT, bv, VT, c * CROWS_);
    gemm_qk1<<<dim3(6, 128), 256, 0, stream>>>(Xqh, Ph, QKs, c);
    mpass_k<<<(CROWS_ * 16) / 256, 256, 0, stream>>>(QKs, Mbuf, c);
  }

  select_a<<<BH_, 256, 0, stream>>>(Mbuf, list, cntb);
  exactM2<<<dim3(BH_, 16), 256, 0, stream>>>(queries, Wq, bq, Ksamp, list, cntb, candM);
  select_b<<<BH_, 256, 0, stream>>>(candM, list, cntb, topidx);
  qsel3<<<dim3(BH_, 12), 256, 0, stream>>>(queries, Wq, topidx, qpart);
  qsel_comb<<<(BH_ * 48 * 64) / 256, 256, 0, stream>>>(qpart, bq, Qbf);
  vmean_vt<<<(BH_ * 64) / 4, 256, 0, stream>>>(VT, Vm);
  attn_stage1<<<dim3(BH_, NSPLIT), 256, 0, stream>>>(Qbf, Kbf, VT, part);
  attn_stage2<<<BH_, 256, 0, stream>>>(part, Vm, dctx);
  base_k<<<dim3(DM_ / 256, B_), 256, 0, stream>>>(Vm, Wo, bo, base);

  // epilogue: deterministic, atomic-free
  hipMemsetAsync(rowmask, 0, (size_t)B_ * L_ * 4 + 256, stream);  // rowmask + uniqCnt
  gemm_upd<<<dim3(4, BH_), 256, 0, stream>>>(dctx, Wo, rowupd);
  build_list<<<(BH_ * U_ + 255) / 256, 256, 0, stream>>>(topidx, rowmask, slotU, uniq, uniqCnt);
  fill_out<<<(int)((size_t)ML_ * DM_ / 4 / 256), 256, 0, stream>>>(base, (float*)d_out);
  scatter3<<<BH_ * U_, 256, 0, stream>>>(rowupd, base, rowmask, slotU, uniq, uniqCnt,
                                         (float*)d_out);
}

// Round 12
// 1108.020 us; speedup vs baseline: 1.0098x; 1.0098x over previous
//
#include <hip/hip_runtime.h>
#include <cstdint>
#include <cstdio>

#define B_   8
#define L_   4096
#define DM_  1024
#define H_   16
#define D_   64
#define U_   45
#define BH_  (B_*H_)
#define ML_  (B_*L_)
#define NSPLIT 8
#define NP_  768           // padded QK-sample width: 16 heads * 48
#define CB_  4             // batches per chunk
#define CROWS_ (CB_*L_)    // 16384 rows per chunk
#define CAP_ 512           // candidate cap per (b,h)
#define DELTA_ 0.12f       // exact-recompute band (~9 sigma of bf16 GEMM err)

using f32x4   = __attribute__((ext_vector_type(4))) float;
using short8  = __attribute__((ext_vector_type(8))) short;
using ushort8 = __attribute__((ext_vector_type(8))) unsigned short;

__device__ __forceinline__ unsigned short f2bf(float f) {
  uint32_t u = __float_as_uint(f);
  u += 0x7fffu + ((u >> 16) & 1u);      // RNE; inputs finite
  return (unsigned short)(u >> 16);
}
__device__ __forceinline__ float bf2f(unsigned short h) {
  return __uint_as_float(((uint32_t)h) << 16);
}

__device__ __forceinline__ void gload16(const void* g, void* l) {
  __builtin_amdgcn_global_load_lds((const __attribute__((address_space(1))) void*)g,
                                   (__attribute__((address_space(3))) void*)l,
                                   16, 0, 0);
}

// ---------- split: q,k,v -> bf16 hi only (8 floats/thread/iter) ----------
__global__ __launch_bounds__(256) void split3h(const float* __restrict__ q,
    const float* __restrict__ k, const float* __restrict__ v,
    unsigned short* __restrict__ Xqh, unsigned short* __restrict__ Xkh,
    unsigned short* __restrict__ Xvh, int n8) {
  const int z = blockIdx.y;
  const float* __restrict__ X = (z == 0) ? q : ((z == 1) ? k : v);
  unsigned short* __restrict__ O = (z == 0) ? Xqh : ((z == 1) ? Xkh : Xvh);
  int i = blockIdx.x * 256 + threadIdx.x;
  const int stride = gridDim.x * 256;
  for (; i < n8; i += stride) {
    const float4 a = ((const float4*)X)[2 * i];
    const float4 b = ((const float4*)X)[2 * i + 1];
    ushort8 hv;
    hv[0] = f2bf(a.x); hv[1] = f2bf(a.y); hv[2] = f2bf(a.z); hv[3] = f2bf(a.w);
    hv[4] = f2bf(b.x); hv[5] = f2bf(b.y); hv[6] = f2bf(b.z); hv[7] = f2bf(b.w);
    ((ushort8*)O)[i] = hv;
  }
}

// ---------- W (KxN) -> W^T bf16 (NxK) ----------
__global__ __launch_bounds__(256) void wT_single(const float* __restrict__ W,
                                                 unsigned short* __restrict__ WT) {
  const int idx = blockIdx.x * 256 + threadIdx.x;   // 1M threads
  const int n = idx >> 10, kk = idx & 1023;
  WT[idx] = f2bf(W[kk * 1024 + n]);
}

// ---------- plain bf16 GEMM, bf16 out: C = bf16(X*W + bias) ----------
__global__ __launch_bounds__(256) void gemm_plain(const unsigned short* __restrict__ Agh,
    const unsigned short* __restrict__ Bgh, const float* __restrict__ bias,
    unsigned short* __restrict__ C) {
  constexpr int K = 1024, N = 1024;
  __shared__ unsigned short sA[128 * 32];
  __shared__ unsigned short sB[128 * 32];
  const int tid = threadIdx.x, wid = tid >> 6, lane = tid & 63;
  const int m0 = blockIdx.y * 128, n0 = blockIdx.x * 128;
  const int wr = wid >> 1, wc = wid & 1;
  const int fr = lane & 15, fq = lane >> 4;
  const int srow = lane >> 2, scol = (lane & 3) * 8;
  f32x4 acc[4][4];
#pragma unroll
  for (int i = 0; i < 4; i++)
#pragma unroll
    for (int j = 0; j < 4; j++) acc[i][j] = f32x4{0.f, 0.f, 0.f, 0.f};

  for (int k0 = 0; k0 < K; k0 += 32) {
#pragma unroll
    for (int c = 0; c < 2; c++) {
      const int ch = wid * 2 + c;
      const int row = ch * 16 + srow;
      gload16(Agh + (size_t)(m0 + row) * K + (k0 + scol), &sA[ch * 512]);
      gload16(Bgh + (size_t)(n0 + row) * K + (k0 + scol), &sB[ch * 512]);
    }
    __syncthreads();
    short8 ah[4], bh[4];
#pragma unroll
    for (int i = 0; i < 4; i++) {
      ah[i] = *(const short8*)&sA[(wr * 64 + i * 16 + fr) * 32 + fq * 8];
      bh[i] = *(const short8*)&sB[(wc * 64 + i * 16 + fr) * 32 + fq * 8];
    }
#pragma unroll
    for (int i = 0; i < 4; i++)
#pragma unroll
      for (int j = 0; j < 4; j++)
        acc[i][j] = __builtin_amdgcn_mfma_f32_16x16x32_bf16(ah[i], bh[j], acc[i][j], 0, 0, 0);
    __syncthreads();
  }
#pragma unroll
  for (int j = 0; j < 4; j++) {
    const int col = n0 + wc * 64 + j * 16 + fr;
    const float bv = bias[col];
#pragma unroll
    for (int i = 0; i < 4; i++) {
      const int row = m0 + wr * 64 + i * 16 + fq * 4;
#pragma unroll
      for (int r = 0; r < 4; r++) C[(size_t)(row + r) * N + col] = f2bf(acc[i][j][r] + bv);
    }
  }
}

// ---------- bf16 GEMM with transposed output via LDS: VT[(b*1024+col)][l], coalesced ---
__global__ __launch_bounds__(256) void gemm_plainT(const unsigned short* __restrict__ Agh,
    const unsigned short* __restrict__ Bgh, const float* __restrict__ bias,
    unsigned short* __restrict__ VT, int rowbase) {
  constexpr int K = 1024;
  __shared__ unsigned short sA[128 * 32];
  __shared__ unsigned short sB[128 * 32];
  __shared__ unsigned short sC[128][132];   // [d-col][l-in-tile]
  const int tid = threadIdx.x, wid = tid >> 6, lane = tid & 63;
  const int m0 = blockIdx.y * 128, n0 = blockIdx.x * 128;
  const int wr = wid >> 1, wc = wid & 1;
  const int fr = lane & 15, fq = lane >> 4;
  const int srow = lane >> 2, scol = (lane & 3) * 8;
  f32x4 acc[4][4];
#pragma unroll
  for (int i = 0; i < 4; i++)
#pragma unroll
    for (int j = 0; j < 4; j++) acc[i][j] = f32x4{0.f, 0.f, 0.f, 0.f};

  for (int k0 = 0; k0 < K; k0 += 32) {
#pragma unroll
    for (int c = 0; c < 2; c++) {
      const int ch = wid * 2 + c;
      const int row = ch * 16 + srow;
      gload16(Agh + (size_t)(m0 + row) * K + (k0 + scol), &sA[ch * 512]);
      gload16(Bgh + (size_t)(n0 + row) * K + (k0 + scol), &sB[ch * 512]);
    }
    __syncthreads();
    short8 ah[4], bh[4];
#pragma unroll
    for (int i = 0; i < 4; i++) {
      ah[i] = *(const short8*)&sA[(wr * 64 + i * 16 + fr) * 32 + fq * 8];
      bh[i] = *(const short8*)&sB[(wc * 64 + i * 16 + fr) * 32 + fq * 8];
    }
#pragma unroll
    for (int i = 0; i < 4; i++)
#pragma unroll
      for (int j = 0; j < 4; j++)
        acc[i][j] = __builtin_amdgcn_mfma_f32_16x16x32_bf16(ah[i], bh[j], acc[i][j], 0, 0, 0);
    __syncthreads();
  }
  // stage tile transposed in LDS
#pragma unroll
  for (int j = 0; j < 4; j++) {
    const int col = wc * 64 + j * 16 + fr;             // d within tile
    const float bv = bias[n0 + col];
#pragma unroll
    for (int i = 0; i < 4; i++) {
      const int lrow = wr * 64 + i * 16 + fq * 4;      // l within tile
#pragma unroll
      for (int r = 0; r < 4; r++) sC[col][lrow + r] = f2bf(acc[i][j][r] + bv);
    }
  }
  __syncthreads();
  // coalesced write: 16 rows/iter, 16 threads x ushort8 = 256 B contiguous per row
  const int grow0 = rowbase + m0;
  const int b = grow0 >> 12, l0 = grow0 & 4095;        // tile within one batch
#pragma unroll
  for (int it = 0; it < 8; it++) {
    const int row = it * 16 + (tid >> 4);              // d within tile
    const int seg = (tid & 15) * 8;                    // l offset
    const ushort8 v = *(const ushort8*)&sC[row][seg];
    *(ushort8*)&VT[((size_t)(b * 1024 + n0 + row)) * L_ + l0 + seg] = v;
  }
}

// ---------- plain bf16 GEMM: QKs = Xq * P_b (fp32 out, N=768) ----------
__global__ __launch_bounds__(256) void gemm_qk1(const unsigned short* __restrict__ Agh,
    const unsigned short* __restrict__ Pall_h, float* __restrict__ C, int chunk) {
  constexpr int K = 1024;
  __shared__ unsigned short sA[128 * 32];
  __shared__ unsigned short sB[128 * 32];
  const int tid = threadIdx.x, wid = tid >> 6, lane = tid & 63;
  const int m0 = blockIdx.y * 128, n0 = blockIdx.x * 128;
  const int batch = chunk * CB_ + (blockIdx.y >> 5);
  const unsigned short* __restrict__ Bgh = Pall_h + (size_t)batch * NP_ * K;
  const int wr = wid >> 1, wc = wid & 1;
  const int fr = lane & 15, fq = lane >> 4;
  const int srow = lane >> 2, scol = (lane & 3) * 8;
  f32x4 acc[4][4];
#pragma unroll
  for (int i = 0; i < 4; i++)
#pragma unroll
    for (int j = 0; j < 4; j++) acc[i][j] = f32x4{0.f, 0.f, 0.f, 0.f};

  for (int k0 = 0; k0 < K; k0 += 32) {
#pragma unroll
    for (int c = 0; c < 2; c++) {
      const int ch = wid * 2 + c;
      const int row = ch * 16 + srow;
      gload16(Agh + (size_t)(m0 + row) * K + (k0 + scol), &sA[ch * 512]);
      gload16(Bgh + (size_t)(n0 + row) * K + (k0 + scol), &sB[ch * 512]);
    }
    __syncthreads();
    short8 ah[4], bh[4];
#pragma unroll
    for (int i = 0; i < 4; i++) {
      ah[i] = *(const short8*)&sA[(wr * 64 + i * 16 + fr) * 32 + fq * 8];
      bh[i] = *(const short8*)&sB[(wc * 64 + i * 16 + fr) * 32 + fq * 8];
    }
#pragma unroll
    for (int i = 0; i < 4; i++)
#pragma unroll
      for (int j = 0; j < 4; j++)
        acc[i][j] = __builtin_amdgcn_mfma_f32_16x16x32_bf16(ah[i], bh[j], acc[i][j], 0, 0, 0);
    __syncthreads();
  }
#pragma unroll
  for (int j = 0; j < 4; j++) {
    const int col = n0 + wc * 64 + j * 16 + fr;
#pragma unroll
    for (int i = 0; i < 4; i++) {
      const int row = m0 + wr * 64 + i * 16 + fq * 4;
#pragma unroll
      for (int r = 0; r < 4; r++) C[(size_t)(row + r) * NP_ + col] = acc[i][j][r];
    }
  }
}

// ---------- ksel3: exact fp32 sampled-K rows, split-K column-parallel ----------
__global__ __launch_bounds__(256) void ksel3(const float* __restrict__ X,
    const float* __restrict__ Wk, const int* __restrict__ sidx,
    float* __restrict__ kpart) {
  const int t = threadIdx.x;
  const int col = blockIdx.x * 256 + t;
  const int b = blockIdx.y;
  const int ug = blockIdx.z >> 2, kc = blockIdx.z & 3;
  __shared__ float Xs[15][256];
  __shared__ int rows[15];
  if (t < 15) rows[t] = sidx[ug * 15 + t];
  __syncthreads();
#pragma unroll
  for (int i = 0; i < 15; i++)
    Xs[i][t] = X[((size_t)b * L_ + rows[i]) * DM_ + kc * 256 + t];
  __syncthreads();
  float acc[15];
#pragma unroll
  for (int r = 0; r < 15; r++) acc[r] = 0.f;
  for (int k4 = 0; k4 < 64; k4++) {
    const int kb = kc * 256 + k4 * 4;
    const float w0 = Wk[(size_t)(kb + 0) * DM_ + col];
    const float w1 = Wk[(size_t)(kb + 1) * DM_ + col];
    const float w2 = Wk[(size_t)(kb + 2) * DM_ + col];
    const float w3 = Wk[(size_t)(kb + 3) * DM_ + col];
#pragma unroll
    for (int r = 0; r < 15; r++) {
      const float4 x = *(const float4*)&Xs[r][k4 * 4];
      acc[r] += x.x * w0 + x.y * w1 + x.z * w2 + x.w * w3;
    }
  }
  float* dst = kpart + (((size_t)kc * B_ + b) * U_ + ug * 15) * 1024 + col;
#pragma unroll
  for (int r = 0; r < 15; r++) dst[(size_t)r * 1024] = acc[r];
}

// combine: Ksamp = sum_kc kpart + bias (fixed order)
__global__ __launch_bounds__(256) void ksel_comb(const float* __restrict__ kpart,
    const float* __restrict__ bk, float* __restrict__ Ksamp) {
  const int idx = blockIdx.x * 256 + threadIdx.x;   // < 360*1024
  const int col = idx & 1023, ru = idx >> 10;
  const int b = ru / U_, u = ru - b * U_;
  const size_t o = ((size_t)b * U_ + u) * 1024 + col;
  const size_t stride = (size_t)B_ * U_ * 1024;
  float s = kpart[o] + kpart[o + stride] + kpart[o + 2 * stride] + kpart[o + 3 * stride]
          + bk[col];
  const int h = col >> 6, d = col & 63;
  Ksamp[((size_t)(b * 16 + h) * U_ + u) * 64 + d] = s;
}

// ---------- P^T[b][h*48+u][k] = sum_d Wq[k][h*64+d]*Ksamp (bf16 hi) ----------
__global__ __launch_bounds__(256) void pform_k(const float* __restrict__ Wq,
    const float* __restrict__ Ksamp, unsigned short* __restrict__ Ph) {
  const int bh = blockIdx.x, b = bh >> 4, h = bh & 15;
  __shared__ float Ks[U_][68];
  const int t = threadIdx.x;
  for (int e = t; e < U_ * 64; e += 256) {
    const int u = e >> 6, d = e & 63;
    Ks[u][d] = Ksamp[((size_t)bh * U_ + u) * 64 + d];
  }
  __syncthreads();
  for (int kc = 0; kc < 4; kc++) {
    const int k = kc * 256 + t;
    float wr[64];
#pragma unroll
    for (int dd = 0; dd < 16; dd++) {
      const float4 w4 = *(const float4*)&Wq[(size_t)k * DM_ + h * 64 + dd * 4];
      wr[dd * 4 + 0] = w4.x; wr[dd * 4 + 1] = w4.y;
      wr[dd * 4 + 2] = w4.z; wr[dd * 4 + 3] = w4.w;
    }
    for (int u = 0; u < 48; u++) {
      size_t o = ((size_t)b * NP_ + h * 48 + u) * 1024 + k;
      if (u < U_) {
        float acc = 0.f;
#pragma unroll
        for (int d = 0; d < 64; d++) acc += wr[d] * Ks[u][d];
        Ph[o] = f2bf(acc);
      } else {
        Ph[o] = 0;
      }
    }
  }
}

// ---------- M_approx = max - mean over u ----------
__global__ __launch_bounds__(256) void mpass_k(const float* __restrict__ QKs,
                                               float* __restrict__ Mbuf, int chunk) {
  const int idx = blockIdx.x * 256 + threadIdx.x;   // < CROWS_*16
  const int ll = idx >> 4, h = idx & 15;
  const float* row = QKs + (size_t)ll * NP_ + h * 48;
  float mx = row[0], sm = row[0];
#pragma unroll
  for (int u = 1; u < U_; u++) { const float v = row[u]; mx = fmaxf(mx, v); sm += v; }
  const int lg = chunk * CROWS_ + ll;
  const int b = lg >> 12, l = lg & 4095;
  Mbuf[((size_t)(b * 16 + h)) * L_ + l] = mx - sm * (1.f / (float)U_);
}

// ---------- select_a: approx top-45 -> thr; candidates = {M >= thr - DELTA} ----------
__global__ __launch_bounds__(256) void select_a(const float* __restrict__ Mbuf,
    int* __restrict__ list, int* __restrict__ cnt) {
  const int bh = blockIdx.x, t = threadIdx.x;
  __shared__ float vals[L_];
  __shared__ float rv[256];
  __shared__ int   ri[256];
  __shared__ int   scnt;
  __shared__ float sthr;
  if (t == 0) scnt = 0;
  for (int i = t; i < L_; i += 256) vals[i] = Mbuf[(size_t)bh * L_ + i];
  __syncthreads();
  for (int it = 0; it < U_; it++) {
    float bv = vals[t * 16]; int bi = t * 16;
#pragma unroll
    for (int jj = 1; jj < 16; jj++) {
      const float v = vals[t * 16 + jj];
      if (v > bv) { bv = v; bi = t * 16 + jj; }
    }
    rv[t] = bv; ri[t] = bi;
    __syncthreads();
    for (int s = 128; s > 0; s >>= 1) {
      if (t < s) {
        if (rv[t + s] > rv[t] || (rv[t + s] == rv[t] && ri[t + s] < ri[t])) {
          rv[t] = rv[t + s]; ri[t] = ri[t + s];
        }
      }
      __syncthreads();
    }
    if (t == 0) {
      list[(size_t)bh * CAP_ + it] = ri[0];
      vals[ri[0]] = -3.4e38f;
      if (it == U_ - 1) sthr = rv[0];
    }
    __syncthreads();
  }
  const float lim = sthr - DELTA_;
  for (int i = t; i < L_; i += 256) {
    if (vals[i] >= lim) {
      const int j = atomicAdd(&scnt, 1);
      if (U_ + j < CAP_) list[(size_t)bh * CAP_ + U_ + j] = i;
    }
  }
  __syncthreads();
  if (t == 0) cnt[bh] = min(U_ + scnt, CAP_);
}

// ---------- exactM2: fp32 recompute of M for candidates ----------
__global__ __launch_bounds__(256) void exactM2(const float* __restrict__ X,
    const float* __restrict__ Wq, const float* __restrict__ bq,
    const float* __restrict__ Ksamp, const int* __restrict__ list,
    const int* __restrict__ cnt, float* __restrict__ candM) {
  const int bh = blockIdx.x, g = blockIdx.y, b = bh >> 4, h = bh & 15;
  __shared__ float Ks[U_][68];
  __shared__ float Xs[8][256];
  __shared__ float red[4][8][64];
  __shared__ float qd[8][68];
  __shared__ float sc[8][45];
  __shared__ int rows[8];
  const int t = threadIdx.x, p = t >> 6, d = t & 63;
  for (int e = t; e < U_ * 64; e += 256) {
    const int u = e >> 6, dd = e & 63;
    Ks[u][dd] = Ksamp[((size_t)bh * U_ + u) * 64 + dd];
  }
  const int n = cnt[bh];
  const int stride = 8 * gridDim.y;
  for (int c0 = g * 8; c0 < n; c0 += stride) {
    const int nc = min(8, n - c0);
    __syncthreads();
    if (t < 8) rows[t] = list[(size_t)bh * CAP_ + c0 + min(t, nc - 1)];
    float acc[8];
#pragma unroll
    for (int r = 0; r < 8; r++) acc[r] = 0.f;
    for (int kc = 0; kc < 4; kc++) {
      __syncthreads();
#pragma unroll
      for (int i = 0; i < 8; i++)
        Xs[i][t] = X[((size_t)b * L_ + rows[i]) * DM_ + kc * 256 + t];
      __syncthreads();
#pragma unroll
      for (int k4 = 0; k4 < 16; k4++) {
        const int kb = kc * 256 + p * 64 + k4 * 4;
        const float w0 = Wq[(size_t)(kb + 0) * DM_ + h * 64 + d];
        const float w1 = Wq[(size_t)(kb + 1) * DM_ + h * 64 + d];
        const float w2 = Wq[(size_t)(kb + 2) * DM_ + h * 64 + d];
        const float w3 = Wq[(size_t)(kb + 3) * DM_ + h * 64 + d];
#pragma unroll
        for (int r = 0; r < 8; r++) {
          const float4 x = *(const float4*)&Xs[r][p * 64 + k4 * 4];
          acc[r] += x.x * w0 + x.y * w1 + x.z * w2 + x.w * w3;
        }
      }
    }
#pragma unroll
    for (int r = 0; r < 8; r++) red[p][r][d] = acc[r];
    __syncthreads();
    if (p == 0) {
#pragma unroll
      for (int r = 0; r < 8; r++)
        qd[r][d] = red[0][r][d] + red[1][r][d] + red[2][r][d] + red[3][r][d] + bq[h * 64 + d];
    }
    __syncthreads();
    for (int idx = t; idx < 8 * U_; idx += 256) {
      const int c = idx / U_, u = idx - c * U_;
      float s = 0.f;
#pragma unroll 8
      for (int dd = 0; dd < 64; dd++) s += qd[c][dd] * Ks[u][dd];
      sc[c][u] = s;
    }
    __syncthreads();
    if (t < nc) {
      float mx = sc[t][0], sm = sc[t][0];
      for (int u = 1; u < U_; u++) { mx = fmaxf(mx, sc[t][u]); sm += sc[t][u]; }
      candM[(size_t)bh * CAP_ + c0 + t] = mx - sm * (1.f / (float)U_);
    }
  }
}

// ---------- select_b: final top-45 over candidates (exact M, idx tie-break) ----------
__global__ __launch_bounds__(256) void select_b(const float* __restrict__ candM,
    const int* __restrict__ list, const int* __restrict__ cnt, int* __restrict__ topidx) {
  const int bh = blockIdx.x, t = threadIdx.x;
  __shared__ float mv[CAP_];
  __shared__ int   ml[CAP_];
  __shared__ float rv[256];
  __shared__ int   ri[256];
  const int n = cnt[bh];
  for (int i = t; i < CAP_; i += 256) {
    mv[i] = (i < n) ? candM[(size_t)bh * CAP_ + i] : -3.4e38f;
    ml[i] = (i < n) ? list[(size_t)bh * CAP_ + i] : 0x7fffffff;
  }
  __syncthreads();
  for (int it = 0; it < U_; it++) {
    float bv = mv[t]; int bi = ml[t]; int bj = t;
    {
      const float v = mv[t + 256]; const int l2 = ml[t + 256];
      if (v > bv || (v == bv && l2 < bi)) { bv = v; bi = l2; bj = t + 256; }
    }
    rv[t] = bv; ri[t] = bj;
    __syncthreads();
    for (int s = 128; s > 0; s >>= 1) {
      if (t < s) {
        const float v2 = rv[t + s];
        const int slot2 = ri[t + s];
        if (v2 > rv[t] || (v2 == rv[t] && ml[slot2] < ml[ri[t]])) {
          rv[t] = v2; ri[t] = slot2;
        }
      }
      __syncthreads();
    }
    if (t == 0) {
      topidx[bh * U_ + it] = ml[ri[0]];
      mv[ri[0]] = -3.4e38f;
    }
    __syncthreads();
  }
}

// ---------- qsel3: exact selected Q rows, split-K partials ----------
__global__ __launch_bounds__(256) void qsel3(const float* __restrict__ X,
    const float* __restrict__ Wq, const int* __restrict__ topidx,
    float* __restrict__ qpart) {
  const int bh = blockIdx.x;
  const int ug = blockIdx.y >> 2, kc = blockIdx.y & 3;
  const int b = bh >> 4, h = bh & 15;
  __shared__ float Xs[15][256];
  __shared__ int rows[15];
  const int t = threadIdx.x, p = t >> 6, d = t & 63;
  if (t < 15) rows[t] = topidx[bh * U_ + ug * 15 + t];
  __syncthreads();
#pragma unroll
  for (int i = 0; i < 15; i++)
    Xs[i][t] = X[((size_t)b * L_ + rows[i]) * DM_ + kc * 256 + t];
  __syncthreads();
  float acc[15];
#pragma unroll
  for (int r = 0; r < 15; r++) acc[r] = 0.f;
#pragma unroll
  for (int k4 = 0; k4 < 16; k4++) {
    const int kb = kc * 256 + p * 64 + k4 * 4;
    const float w0 = Wq[(size_t)(kb + 0) * DM_ + h * 64 + d];
    const float w1 = Wq[(size_t)(kb + 1) * DM_ + h * 64 + d];
    const float w2 = Wq[(size_t)(kb + 2) * DM_ + h * 64 + d];
    const float w3 = Wq[(size_t)(kb + 3) * DM_ + h * 64 + d];
#pragma unroll
    for (int r = 0; r < 15; r++) {
      const float4 x = *(const float4*)&Xs[r][p * 64 + k4 * 4];
      acc[r] += x.x * w0 + x.y * w1 + x.z * w2 + x.w * w3;
    }
  }
  const int p16 = kc * 4 + p;       // partial slot 0..15
  float* dst = qpart + (((size_t)p16 * BH_ + bh) * 48 + ug * 15) * 64 + d;
#pragma unroll
  for (int r = 0; r < 15; r++) dst[(size_t)r * 64] = acc[r];
}

// combine 16 partials (fixed order) + bias -> bf16 Qbf; zero pad rows
__global__ __launch_bounds__(256) void qsel_comb(const float* __restrict__ qpart,
    const float* __restrict__ bq, unsigned short* __restrict__ Qbf) {
  const int idx = blockIdx.x * 256 + threadIdx.x;   // < BH_*48*64
  const int d = idx & 63, u48 = (idx >> 6) % 48, bh = idx / (48 * 64);
  const int h = bh & 15;
  if (u48 < U_) {
    const size_t o = (((size_t)bh) * 48 + u48) * 64 + d;
    const size_t stride = (size_t)BH_ * 48 * 64;
    float s = bq[h * 64 + d];
#pragma unroll
    for (int p16 = 0; p16 < 16; p16++) s += qpart[o + (size_t)p16 * stride];
    Qbf[o] = f2bf(s);
  } else {
    Qbf[(((size_t)bh) * 48 + u48) * 64 + d] = 0;
  }
}

// ---------- V mean from V^T rows (contiguous, deterministic) ----------
__global__ __launch_bounds__(256) void vmean_vt(const unsigned short* __restrict__ VT,
                                                float* __restrict__ Vm) {
  const int row = blockIdx.x * 4 + (threadIdx.x >> 6);   // 8192 rows total
  const int lane = threadIdx.x & 63;
  const unsigned short* src = VT + (size_t)row * L_ + lane * 64;
  float s = 0.f;
#pragma unroll
  for (int c = 0; c < 8; c++) {
    const ushort8 v = *(const ushort8*)&src[c * 8];
#pragma unroll
    for (int x = 0; x < 8; x++) s += bf2f(v[x]);
  }
  for (int off = 32; off > 0; off >>= 1) s += __shfl_xor(s, off);
  if (lane == 0) Vm[row] = s * (1.f / (float)L_);
}

// ---------- stage1: MFMA QK^T + MFMA PV over bf16 P; no-max softmax ----------
__global__ __launch_bounds__(256) void attn_stage1(const unsigned short* __restrict__ Qbf,
    const unsigned short* __restrict__ Kbf, const unsigned short* __restrict__ VT,
    float* __restrict__ part) {
  const int bh = blockIdx.x, split = blockIdx.y;
  const int b = bh >> 4, h = bh & 15;
  __shared__ unsigned short sQ[48][72];
  __shared__ unsigned short sK[64][72];
  __shared__ unsigned short sVT[64][72];   // [d][key]
  __shared__ unsigned short esb[48][68];   // P bf16 [q][key]
  __shared__ float sS[4][48];
  __shared__ float S_total[48];
  const int tid = threadIdx.x, wid = tid >> 6, lane = tid & 63;
  const int fr = lane & 15, fq = lane >> 4;
  for (int e = tid; e < 48 * 8; e += 256) {
    const int r = e >> 3, c8 = (e & 7) * 8;
    *(ushort8*)&sQ[r][c8] = *(const ushort8*)&Qbf[((size_t)bh * 48 + r) * 64 + c8];
  }
  if (tid < 48) S_total[tid] = 0.f;
  __syncthreads();
  short8 qf[3][2];
#pragma unroll
  for (int nt = 0; nt < 3; nt++)
#pragma unroll
    for (int kh = 0; kh < 2; kh++)
      qf[nt][kh] = *(const short8*)&sQ[nt * 16 + fr][kh * 32 + fq * 8];

  f32x4 acc[3];
#pragma unroll
  for (int mt = 0; mt < 3; mt++) acc[mt] = f32x4{0.f, 0.f, 0.f, 0.f};

  for (int t = 0; t < 8; t++) {
    const int k0 = split * 512 + t * 64;
    if (t) __syncthreads();               // barrier A: prev PV + S_total add done
    for (int e = tid; e < 64 * 8; e += 256) {
      const int r = e >> 3, c8 = (e & 7) * 8;
      *(ushort8*)&sK[r][c8] =
          *(const ushort8*)&Kbf[((size_t)b * L_ + k0 + r) * DM_ + h * 64 + c8];
      *(ushort8*)&sVT[r][c8] =
          *(const ushort8*)&VT[((size_t)(b * 1024 + h * 64 + r)) * L_ + k0 + c8];
    }
    __syncthreads();                      // barrier B
    const short8 kf0 = *(const short8*)&sK[wid * 16 + fr][fq * 8];
    const short8 kf1 = *(const short8*)&sK[wid * 16 + fr][32 + fq * 8];
    f32x4 accq[3];
#pragma unroll
    for (int nt = 0; nt < 3; nt++) {
      accq[nt] = f32x4{0.f, 0.f, 0.f, 0.f};
      accq[nt] = __builtin_amdgcn_mfma_f32_16x16x32_bf16(kf0, qf[nt][0], accq[nt], 0, 0, 0);
      accq[nt] = __builtin_amdgcn_mfma_f32_16x16x32_bf16(kf1, qf[nt][1], accq[nt], 0, 0, 0);
    }
#pragma unroll
    for (int nt = 0; nt < 3; nt++) {
      float sp = 0.f;
#pragma unroll
      for (int r = 0; r < 4; r++) {
        const float e = expf(accq[nt][r] * 0.125f);   // |score| bounded: no max
        sp += e;
        esb[nt * 16 + fr][wid * 16 + fq * 4 + r] = f2bf(e);
      }
      sp += __shfl_xor(sp, 16);
      sp += __shfl_xor(sp, 32);
      if (fq == 0) sS[wid][nt * 16 + fr] = sp;
    }
    __syncthreads();                      // barrier C
    if (tid < 48) S_total[tid] += sS[0][tid] + sS[1][tid] + sS[2][tid] + sS[3][tid];
    const short8 vb0 = *(const short8*)&sVT[wid * 16 + fr][fq * 8];
    const short8 vb1 = *(const short8*)&sVT[wid * 16 + fr][32 + fq * 8];
#pragma unroll
    for (int mt = 0; mt < 3; mt++) {
      const short8 pa0 = *(const short8*)&esb[mt * 16 + fr][fq * 8];
      const short8 pa1 = *(const short8*)&esb[mt * 16 + fr][32 + fq * 8];
      acc[mt] = __builtin_amdgcn_mfma_f32_16x16x32_bf16(pa0, vb0, acc[mt], 0, 0, 0);
      acc[mt] = __builtin_amdgcn_mfma_f32_16x16x32_bf16(pa1, vb1, acc[mt], 0, 0, 0);
    }
  }
  __syncthreads();
#pragma unroll
  for (int u = 0; u < U_; u++) {
    const int mt = u >> 4, fqq = (u >> 2) & 3, r = u & 3;
    float* pb = part + ((size_t)(bh * NSPLIT + split) * U_ + u) * 65;
    if (fq == fqq) pb[1 + wid * 16 + fr] = acc[mt][r];
    if (tid == fqq * 16) pb[0] = S_total[u];
  }
}

// ---------- combine splits; dctx = ctx/S - Vmean ----------
__global__ __launch_bounds__(256) void attn_stage2(const float* __restrict__ part,
    const float* __restrict__ Vm, float* __restrict__ dctx) {
  const int bh = blockIdx.x;
  const int wid = threadIdx.x >> 6, lane = threadIdx.x & 63;
  for (int u = wid; u < U_; u += 4) {
    float S = 0.f, c = 0.f;
#pragma unroll
    for (int sp = 0; sp < NSPLIT; sp++) {
      const float* pb = part + ((size_t)(bh * NSPLIT + sp) * U_ + u) * 65;
      S += pb[0];
      c += pb[1 + lane];
    }
    dctx[((size_t)bh * U_ + u) * 64 + lane] = c / S - Vm[bh * 64 + lane];
  }
}

// ---------- base[b][:] = concat_h(Vmean) @ Wo + bo ----------
__global__ __launch_bounds__(256) void base_k(const float* __restrict__ Vm,
    const float* __restrict__ Wo, const float* __restrict__ bo, float* __restrict__ base) {
  const int b = blockIdx.y;
  const int j = blockIdx.x * 256 + threadIdx.x;
  float acc = bo[j];
#pragma unroll 8
  for (int i = 0; i < DM_; i++) acc += Vm[b * DM_ + i] * Wo[(size_t)i * DM_ + j];
  base[b * DM_ + j] = acc;
}

// ---------- out[b,l,:] = base[b,:] ----------
__global__ __launch_bounds__(256) void fill_out(const float* __restrict__ base,
                                                float* __restrict__ out) {
  const size_t g = ((size_t)blockIdx.x * 256 + threadIdx.x) * 4;
  const int b = (int)(g >> 22), j = (int)(g & 1023);
  *(float4*)&out[g] = *(const float4*)&base[(b << 10) + j];
}

// ---------- gemm_upd: rowupd[bh][u][:] = dctx[bh] @ Wo_h ----------
__global__ __launch_bounds__(256) void gemm_upd(const float* __restrict__ dctx,
    const float* __restrict__ Wo, float* __restrict__ rowupd) {
  const int bh = blockIdx.y, h = bh & 15;
  const int col = blockIdx.x * 256 + threadIdx.x;
  __shared__ float dc[U_][68];
  for (int e = threadIdx.x; e < U_ * 64; e += 256) {
    const int u = e >> 6, d = e & 63;
    dc[u][d] = dctx[(size_t)bh * U_ * 64 + e];
  }
  __syncthreads();
  float acc[U_];
#pragma unroll
  for (int u = 0; u < U_; u++) acc[u] = 0.f;
  for (int d = 0; d < 64; d++) {
    const float w = Wo[(size_t)(h * 64 + d) * DM_ + col];
#pragma unroll
    for (int u = 0; u < U_; u++) acc[u] += dc[u][d] * w;   // dc broadcast read
  }
#pragma unroll
  for (int u = 0; u < U_; u++)
    rowupd[((size_t)bh * U_ + u) * DM_ + col] = acc[u];
}

// ---------- build_list: per selected row, head-mask + slot; unique-row list ----------
__global__ __launch_bounds__(256) void build_list(const int* __restrict__ topidx,
    int* __restrict__ rowmask, unsigned char* __restrict__ slotU,
    int* __restrict__ uniq, int* __restrict__ uniqCnt) {
  const int i = blockIdx.x * 256 + threadIdx.x;
  if (i >= BH_ * U_) return;
  const int bh = i / U_, u = i - bh * U_;
  const int b = bh >> 4, h = bh & 15;
  const int key = b * L_ + topidx[i];
  slotU[key * 16 + h] = (unsigned char)u;
  const int old = atomicOr(&rowmask[key], 1 << h);
  if (old == 0) {
    const int q = atomicAdd(uniqCnt, 1);
    uniq[q] = key;
  }
}

// ---------- scatter3: one block per unique row; fixed h-order sum; plain write ----------
__global__ __launch_bounds__(256) void scatter3(const float* __restrict__ rowupd,
    const float* __restrict__ base, const int* __restrict__ rowmask,
    const unsigned char* __restrict__ slotU, const int* __restrict__ uniq,
    const int* __restrict__ uniqCnt, float* __restrict__ out) {
  const int idx = blockIdx.x;
  if (idx >= *uniqCnt) return;
  const int key = uniq[idx];
  const int b = key >> 12;                       // L_ = 4096
  const int mask = rowmask[key];
  const int j4 = threadIdx.x * 4;
  float4 a = *(const float4*)&base[b * DM_ + j4];
#pragma unroll
  for (int h = 0; h < 16; h++) {
    if (mask & (1 << h)) {
      const int u = slotU[key * 16 + h];
      const float4 r = *(const float4*)&rowupd[((size_t)(b * 16 + h) * U_ + u) * DM_ + j4];
      a.x += r.x; a.y += r.y; a.z += r.z; a.w += r.w;
    }
  }
  *(float4*)&out[(size_t)key * DM_ + j4] = a;
}

extern "C" void kernel_launch(void* const* d_in, const int* in_sizes, int n_in,
                              void* d_out, int out_size, void* d_ws, size_t ws_size,
                              hipStream_t stream) {
  const float* queries = (const float*)d_in[0];
  const float* keys    = (const float*)d_in[1];
  const float* values  = (const float*)d_in[2];
  const float* Wq = (const float*)d_in[3]; const float* bq = (const float*)d_in[4];
  const float* Wk = (const float*)d_in[5]; const float* bk = (const float*)d_in[6];
  const float* Wv = (const float*)d_in[7]; const float* bv = (const float*)d_in[8];
  const float* Wo = (const float*)d_in[9]; const float* bo = (const float*)d_in[10];
  const int* sidx = (const int*)d_in[11];

  // K (row-major) and V^T live as bf16 in d_out until the epilogue
  unsigned short* Kbf = (unsigned short*)d_out;
  unsigned short* VT  = Kbf + (size_t)ML_ * DM_;

  uint8_t* p = (uint8_t*)d_ws;
  auto carve = [&](size_t bytes) { uint8_t* r = p; p += (bytes + 255) & ~(size_t)255; return r; };
  unsigned short* Xqh = (unsigned short*)carve((size_t)CROWS_ * DM_ * 2);   // 33.6 MB
  unsigned short* Xkh = (unsigned short*)carve((size_t)CROWS_ * DM_ * 2);
  unsigned short* Xvh = (unsigned short*)carve((size_t)CROWS_ * DM_ * 2);
  float* QKs = (float*)carve((size_t)CROWS_ * NP_ * 4);                     // 50.3 MB
  unsigned short* Ph = (unsigned short*)carve((size_t)B_ * NP_ * DM_ * 2);  // 12.6 MB
  unsigned short* WkT = (unsigned short*)carve((size_t)DM_ * DM_ * 2);
  unsigned short* WvT = (unsigned short*)carve((size_t)DM_ * DM_ * 2);
  float* Mbuf  = (float*)carve((size_t)BH_ * L_ * 4);                       // 2.1 MB
  float* Ksamp = (float*)carve((size_t)BH_ * U_ * 64 * 4);                  // 1.5 MB
  float* kpart = (float*)carve((size_t)4 * B_ * U_ * 1024 * 4);             // 5.9 MB
  float* qpart = (float*)carve((size_t)16 * BH_ * 48 * 64 * 4);             // 25.2 MB
  int*   list  = (int*)carve((size_t)BH_ * CAP_ * 4);                       // 256 KB
  float* candM = (float*)carve((size_t)BH_ * CAP_ * 4);                     // 256 KB
  int*   cntb  = (int*)carve((size_t)BH_ * 4);
  int*   topidx = (int*)carve((size_t)BH_ * U_ * 4);
  float* Vm    = (float*)carve((size_t)BH_ * 64 * 4);
  unsigned short* Qbf = (unsigned short*)carve((size_t)BH_ * 48 * 64 * 2);  // 786 KB
  int*   rowmask = (int*)carve((size_t)B_ * L_ * 4);                        // 128 KB (memset)
  int*   uniqCnt = (int*)carve(256);                                        // (memset)
  unsigned char* slotU = (unsigned char*)carve((size_t)B_ * L_ * 16);       // 512 KB
  int*   uniq  = (int*)carve((size_t)BH_ * U_ * 4);                         // 23 KB
  const size_t need = (size_t)(p - (uint8_t*)d_ws);
  if (ws_size < need)
    fprintf(stderr, "ATHENA_WS: need %zu have %zu (WILL FAULT)\n", need, ws_size);

  // late-phase buffers alias QKs (dead after mpass)
  uint8_t* ap = (uint8_t*)QKs;
  auto acarve = [&](size_t bytes) { uint8_t* r = ap; ap += (bytes + 255) & ~(size_t)255; return r; };
  float* part  = (float*)acarve((size_t)BH_ * NSPLIT * U_ * 65 * 4);        // 12 MB
  float* dctx  = (float*)acarve((size_t)BH_ * U_ * 64 * 4);
  float* base  = (float*)acarve((size_t)B_ * DM_ * 4);
  float* rowupd = (float*)acarve((size_t)BH_ * U_ * DM_ * 4);               // 23.6 MB

  ksel3<<<dim3(4, B_, 12), 256, 0, stream>>>(keys, Wk, sidx, kpart);
  ksel_comb<<<(B_ * U_ * 1024) / 256, 256, 0, stream>>>(kpart, bk, Ksamp);
  pform_k<<<BH_, 256, 0, stream>>>(Wq, Ksamp, Ph);
  wT_single<<<4096, 256, 0, stream>>>(Wk, WkT);
  wT_single<<<4096, 256, 0, stream>>>(Wv, WvT);

  const int n8 = (int)((size_t)CROWS_ * DM_ / 8);
  for (int c = 0; c < 2; c++) {
    const size_t off = (size_t)c * CROWS_ * DM_;
    split3h<<<dim3(2048, 3), 256, 0, stream>>>(queries + off, keys + off, values + off,
                                               Xqh, Xkh, Xvh, n8);
    gemm_plain<<<dim3(8, 128), 256, 0, stream>>>(Xkh, WkT, bk, Kbf + off);
    gemm_plainT<<<dim3(8, 128), 256, 0, stream>>>(Xvh, WvT, bv, VT, c * CROWS_);
    gemm_qk1<<<dim3(6, 128), 256, 0, stream>>>(Xqh, Ph, QKs, c);
    mpass_k<<<(CROWS_ * 16) / 256, 256, 0, stream>>>(QKs, Mbuf, c);
  }

  select_a<<<BH_, 256, 0, stream>>>(Mbuf, list, cntb);
  exactM2<<<dim3(BH_, 16), 256, 0, stream>>>(queries, Wq, bq, Ksamp, list, cntb, candM);
  select_b<<<BH_, 256, 0, stream>>>(candM, list, cntb, topidx);
  qsel3<<<dim3(BH_, 12), 256, 0, stream>>>(queries, Wq, topidx, qpart);
  qsel_comb<<<(BH_ * 48 * 64) / 256, 256, 0, stream>>>(qpart, bq, Qbf);
  vmean_vt<<<(BH_ * 64) / 4, 256, 0, stream>>>(VT, Vm);
  attn_stage1<<<dim3(BH_, NSPLIT), 256, 0, stream>>>(Qbf, Kbf, VT, part);
  attn_stage2<<<BH_, 256, 0, stream>>>(part, Vm, dctx);
  base_k<<<dim3(DM_ / 256, B_), 256, 0, stream>>>(Vm, Wo, bo, base);

  // epilogue: deterministic, atomic-free
  hipMemsetAsync(rowmask, 0, (size_t)B_ * L_ * 4 + 256, stream);  // rowmask + uniqCnt
  gemm_upd<<<dim3(4, BH_), 256, 0, stream>>>(dctx, Wo, rowupd);
  build_list<<<(BH_ * U_ + 255) / 256, 256, 0, stream>>>(topidx, rowmask, slotU, uniq, uniqCnt);
  fill_out<<<(int)((size_t)ML_ * DM_ / 4 / 256), 256, 0, stream>>>(base, (float*)d_out);
  scatter3<<<BH_ * U_, 256, 0, stream>>>(rowupd, base, rowmask, slotU, uniq, uniqCnt,
                                         (float*)d_out);
}

// Round 13
// 1105.112 us; speedup vs baseline: 1.0124x; 1.0026x over previous
//
#include <hip/hip_runtime.h>
#include <cstdint>
#include <cstdio>

#define B_   8
#define L_   4096
#define DM_  1024
#define H_   16
#define D_   64
#define U_   45
#define BH_  (B_*H_)
#define ML_  (B_*L_)
#define NSPLIT 8
#define NP_  768           // padded QK-sample width: 16 heads * 48
#define CB_  4             // batches per chunk
#define CROWS_ (CB_*L_)    // 16384 rows per chunk
#define CAP_ 512           // candidate cap per (b,h)
#define DELTA_ 0.12f       // exact-recompute band (~9 sigma of bf16 GEMM err)

using f32x4   = __attribute__((ext_vector_type(4))) float;
using short8  = __attribute__((ext_vector_type(8))) short;
using ushort8 = __attribute__((ext_vector_type(8))) unsigned short;

__device__ __forceinline__ unsigned short f2bf(float f) {
  uint32_t u = __float_as_uint(f);
  u += 0x7fffu + ((u >> 16) & 1u);      // RNE; inputs finite
  return (unsigned short)(u >> 16);
}
__device__ __forceinline__ float bf2f(unsigned short h) {
  return __uint_as_float(((uint32_t)h) << 16);
}

__device__ __forceinline__ void gload16(const void* g, void* l) {
  __builtin_amdgcn_global_load_lds((const __attribute__((address_space(1))) void*)g,
                                   (__attribute__((address_space(3))) void*)l,
                                   16, 0, 0);
}

// ---------- W (KxN) -> W^T bf16 (NxK) ----------
__global__ __launch_bounds__(256) void wT_single(const float* __restrict__ W,
                                                 unsigned short* __restrict__ WT) {
  const int idx = blockIdx.x * 256 + threadIdx.x;   // 1M threads
  const int n = idx >> 10, kk = idx & 1023;
  WT[idx] = f2bf(W[kk * 1024 + n]);
}

// ---------- fused-convert bf16 GEMM: A = fp32 X (converted in-flight), B = bf16 W^T ---
// MODE 0: bf16 row-major C (stride 1024) + bias
// MODE 1: bf16 transposed-out VT[(b*1024+col)][l] via LDS + bias   (V projection)
// MODE 2: fp32 C (stride NP_), per-batch B = Ph                    (QK-sample)
// Chunked-XCD swizzle: same-XCD blocks share the A m-tile (L2-local fp32 re-reads).
template <int MODE>
__global__ __launch_bounds__(256) void gemm_f(const float* __restrict__ Af,
    const unsigned short* __restrict__ Bg, const float* __restrict__ bias,
    void* __restrict__ Cout, int rowbase, int chunk) {
  constexpr int K = 1024;
  constexpr int NX = (MODE == 2) ? 6 : 8;
  constexpr int NWG = NX * 128;
  __shared__ unsigned short sA[128 * 32];
  __shared__ unsigned short sB[128 * 32];
  const int tid = threadIdx.x, wid = tid >> 6, lane = tid & 63;
  const int orig = blockIdx.y * NX + blockIdx.x;
  const int g = (orig & 7) * (NWG / 8) + (orig >> 3);   // bijective (NWG % 8 == 0)
  const int by = g / NX, bx = g % NX;
  const int m0 = by * 128, n0 = bx * 128;
  const unsigned short* __restrict__ Bgh =
      (MODE == 2) ? Bg + (size_t)(chunk * CB_ + (by >> 5)) * NP_ * K : Bg;
  const int wr = wid >> 1, wc = wid & 1;
  const int fr = lane & 15, fq = lane >> 4;
  const int srow = lane >> 2, scol = (lane & 3) * 8;
  const int arow = tid >> 3, acol = (tid & 7) * 4;
  f32x4 acc[4][4];
#pragma unroll
  for (int i = 0; i < 4; i++)
#pragma unroll
    for (int j = 0; j < 4; j++) acc[i][j] = f32x4{0.f, 0.f, 0.f, 0.f};

  for (int k0 = 0; k0 < K; k0 += 32) {
    // B: async global->LDS (bf16)
#pragma unroll
    for (int c = 0; c < 2; c++) {
      const int ch = wid * 2 + c;
      const int row = ch * 16 + srow;
      gload16(Bgh + (size_t)(n0 + row) * K + (k0 + scol), &sB[ch * 512]);
    }
    // A: fp32 load -> bf16 convert -> LDS (4 passes of 32 rows)
#pragma unroll
    for (int pq = 0; pq < 4; pq++) {
      const int row = pq * 32 + arow;
      const float4 x = *(const float4*)&Af[(size_t)(m0 + row) * K + k0 + acol];
      ushort4 hv;
      hv.x = f2bf(x.x); hv.y = f2bf(x.y); hv.z = f2bf(x.z); hv.w = f2bf(x.w);
      *(ushort4*)&sA[row * 32 + acol] = hv;
    }
    __syncthreads();
    short8 ah[4], bh[4];
#pragma unroll
    for (int i = 0; i < 4; i++) {
      ah[i] = *(const short8*)&sA[(wr * 64 + i * 16 + fr) * 32 + fq * 8];
      bh[i] = *(const short8*)&sB[(wc * 64 + i * 16 + fr) * 32 + fq * 8];
    }
#pragma unroll
    for (int i = 0; i < 4; i++)
#pragma unroll
      for (int j = 0; j < 4; j++)
        acc[i][j] = __builtin_amdgcn_mfma_f32_16x16x32_bf16(ah[i], bh[j], acc[i][j], 0, 0, 0);
    __syncthreads();
  }

  if (MODE == 0) {
    unsigned short* C = (unsigned short*)Cout;
#pragma unroll
    for (int j = 0; j < 4; j++) {
      const int col = n0 + wc * 64 + j * 16 + fr;
      const float bv = bias[col];
#pragma unroll
      for (int i = 0; i < 4; i++) {
        const int row = m0 + wr * 64 + i * 16 + fq * 4;
#pragma unroll
        for (int r = 0; r < 4; r++)
          C[(size_t)(row + r) * 1024 + col] = f2bf(acc[i][j][r] + bv);
      }
    }
  } else if (MODE == 2) {
    float* C = (float*)Cout;
#pragma unroll
    for (int j = 0; j < 4; j++) {
      const int col = n0 + wc * 64 + j * 16 + fr;
#pragma unroll
      for (int i = 0; i < 4; i++) {
        const int row = m0 + wr * 64 + i * 16 + fq * 4;
#pragma unroll
        for (int r = 0; r < 4; r++) C[(size_t)(row + r) * NP_ + col] = acc[i][j][r];
      }
    }
  } else {
    // MODE 1: transpose tile in LDS, then coalesced V^T write
    __shared__ unsigned short sC[128][132];
#pragma unroll
    for (int j = 0; j < 4; j++) {
      const int col = wc * 64 + j * 16 + fr;           // d within tile
      const float bv = bias[n0 + col];
#pragma unroll
      for (int i = 0; i < 4; i++) {
        const int lrow = wr * 64 + i * 16 + fq * 4;    // l within tile
#pragma unroll
        for (int r = 0; r < 4; r++) sC[col][lrow + r] = f2bf(acc[i][j][r] + bv);
      }
    }
    __syncthreads();
    unsigned short* VT = (unsigned short*)Cout;
    const int grow0 = rowbase + m0;
    const int b = grow0 >> 12, l0 = grow0 & 4095;      // L_ = 4096
#pragma unroll
    for (int it = 0; it < 8; it++) {
      const int row = it * 16 + (tid >> 4);
      const int seg = (tid & 15) * 8;
      const ushort8 v = *(const ushort8*)&sC[row][seg];
      *(ushort8*)&VT[((size_t)(b * 1024 + n0 + row)) * L_ + l0 + seg] = v;
    }
  }
}

// ---------- ksel3: exact fp32 sampled-K rows, split-K column-parallel ----------
__global__ __launch_bounds__(256) void ksel3(const float* __restrict__ X,
    const float* __restrict__ Wk, const int* __restrict__ sidx,
    float* __restrict__ kpart) {
  const int t = threadIdx.x;
  const int col = blockIdx.x * 256 + t;
  const int b = blockIdx.y;
  const int ug = blockIdx.z >> 2, kc = blockIdx.z & 3;
  __shared__ float Xs[15][256];
  __shared__ int rows[15];
  if (t < 15) rows[t] = sidx[ug * 15 + t];
  __syncthreads();
#pragma unroll
  for (int i = 0; i < 15; i++)
    Xs[i][t] = X[((size_t)b * L_ + rows[i]) * DM_ + kc * 256 + t];
  __syncthreads();
  float acc[15];
#pragma unroll
  for (int r = 0; r < 15; r++) acc[r] = 0.f;
  for (int k4 = 0; k4 < 64; k4++) {
    const int kb = kc * 256 + k4 * 4;
    const float w0 = Wk[(size_t)(kb + 0) * DM_ + col];
    const float w1 = Wk[(size_t)(kb + 1) * DM_ + col];
    const float w2 = Wk[(size_t)(kb + 2) * DM_ + col];
    const float w3 = Wk[(size_t)(kb + 3) * DM_ + col];
#pragma unroll
    for (int r = 0; r < 15; r++) {
      const float4 x = *(const float4*)&Xs[r][k4 * 4];
      acc[r] += x.x * w0 + x.y * w1 + x.z * w2 + x.w * w3;
    }
  }
  float* dst = kpart + (((size_t)kc * B_ + b) * U_ + ug * 15) * 1024 + col;
#pragma unroll
  for (int r = 0; r < 15; r++) dst[(size_t)r * 1024] = acc[r];
}

// combine: Ksamp = sum_kc kpart + bias (fixed order)
__global__ __launch_bounds__(256) void ksel_comb(const float* __restrict__ kpart,
    const float* __restrict__ bk, float* __restrict__ Ksamp) {
  const int idx = blockIdx.x * 256 + threadIdx.x;   // < 360*1024
  const int col = idx & 1023, ru = idx >> 10;
  const int b = ru / U_, u = ru - b * U_;
  const size_t o = ((size_t)b * U_ + u) * 1024 + col;
  const size_t stride = (size_t)B_ * U_ * 1024;
  float s = kpart[o] + kpart[o + stride] + kpart[o + 2 * stride] + kpart[o + 3 * stride]
          + bk[col];
  const int h = col >> 6, d = col & 63;
  Ksamp[((size_t)(b * 16 + h) * U_ + u) * 64 + d] = s;
}

// ---------- P^T[b][h*48+u][k] = sum_d Wq[k][h*64+d]*Ksamp (bf16 hi) ----------
__global__ __launch_bounds__(256) void pform_k(const float* __restrict__ Wq,
    const float* __restrict__ Ksamp, unsigned short* __restrict__ Ph) {
  const int bh = blockIdx.x, b = bh >> 4, h = bh & 15;
  __shared__ float Ks[U_][68];
  const int t = threadIdx.x;
  for (int e = t; e < U_ * 64; e += 256) {
    const int u = e >> 6, d = e & 63;
    Ks[u][d] = Ksamp[((size_t)bh * U_ + u) * 64 + d];
  }
  __syncthreads();
  for (int kc = 0; kc < 4; kc++) {
    const int k = kc * 256 + t;
    float wr[64];
#pragma unroll
    for (int dd = 0; dd < 16; dd++) {
      const float4 w4 = *(const float4*)&Wq[(size_t)k * DM_ + h * 64 + dd * 4];
      wr[dd * 4 + 0] = w4.x; wr[dd * 4 + 1] = w4.y;
      wr[dd * 4 + 2] = w4.z; wr[dd * 4 + 3] = w4.w;
    }
    for (int u = 0; u < 48; u++) {
      size_t o = ((size_t)b * NP_ + h * 48 + u) * 1024 + k;
      if (u < U_) {
        float acc = 0.f;
#pragma unroll
        for (int d = 0; d < 64; d++) acc += wr[d] * Ks[u][d];
        Ph[o] = f2bf(acc);
      } else {
        Ph[o] = 0;
      }
    }
  }
}

// ---------- M_approx = max - mean over u ----------
__global__ __launch_bounds__(256) void mpass_k(const float* __restrict__ QKs,
                                               float* __restrict__ Mbuf, int chunk) {
  const int idx = blockIdx.x * 256 + threadIdx.x;   // < CROWS_*16
  const int ll = idx >> 4, h = idx & 15;
  const float* row = QKs + (size_t)ll * NP_ + h * 48;
  float mx = row[0], sm = row[0];
#pragma unroll
  for (int u = 1; u < U_; u++) { const float v = row[u]; mx = fmaxf(mx, v); sm += v; }
  const int lg = chunk * CROWS_ + ll;
  const int b = lg >> 12, l = lg & 4095;
  Mbuf[((size_t)(b * 16 + h)) * L_ + l] = mx - sm * (1.f / (float)U_);
}

// ---------- select_a: approx top-45 -> thr; candidates = {M >= thr - DELTA} ----------
__global__ __launch_bounds__(256) void select_a(const float* __restrict__ Mbuf,
    int* __restrict__ list, int* __restrict__ cnt) {
  const int bh = blockIdx.x, t = threadIdx.x;
  __shared__ float vals[L_];
  __shared__ float rv[256];
  __shared__ int   ri[256];
  __shared__ int   scnt;
  __shared__ float sthr;
  if (t == 0) scnt = 0;
  for (int i = t; i < L_; i += 256) vals[i] = Mbuf[(size_t)bh * L_ + i];
  __syncthreads();
  for (int it = 0; it < U_; it++) {
    float bv = vals[t * 16]; int bi = t * 16;
#pragma unroll
    for (int jj = 1; jj < 16; jj++) {
      const float v = vals[t * 16 + jj];
      if (v > bv) { bv = v; bi = t * 16 + jj; }
    }
    rv[t] = bv; ri[t] = bi;
    __syncthreads();
    for (int s = 128; s > 0; s >>= 1) {
      if (t < s) {
        if (rv[t + s] > rv[t] || (rv[t + s] == rv[t] && ri[t + s] < ri[t])) {
          rv[t] = rv[t + s]; ri[t] = ri[t + s];
        }
      }
      __syncthreads();
    }
    if (t == 0) {
      list[(size_t)bh * CAP_ + it] = ri[0];
      vals[ri[0]] = -3.4e38f;
      if (it == U_ - 1) sthr = rv[0];
    }
    __syncthreads();
  }
  const float lim = sthr - DELTA_;
  for (int i = t; i < L_; i += 256) {
    if (vals[i] >= lim) {
      const int j = atomicAdd(&scnt, 1);
      if (U_ + j < CAP_) list[(size_t)bh * CAP_ + U_ + j] = i;
    }
  }
  __syncthreads();
  if (t == 0) cnt[bh] = min(U_ + scnt, CAP_);
}

// ---------- exactM2: fp32 recompute of M for candidates ----------
__global__ __launch_bounds__(256) void exactM2(const float* __restrict__ X,
    const float* __restrict__ Wq, const float* __restrict__ bq,
    const float* __restrict__ Ksamp, const int* __restrict__ list,
    const int* __restrict__ cnt, float* __restrict__ candM) {
  const int bh = blockIdx.x, g = blockIdx.y, b = bh >> 4, h = bh & 15;
  __shared__ float Ks[U_][68];
  __shared__ float Xs[8][256];
  __shared__ float red[4][8][64];
  __shared__ float qd[8][68];
  __shared__ float sc[8][45];
  __shared__ int rows[8];
  const int t = threadIdx.x, p = t >> 6, d = t & 63;
  for (int e = t; e < U_ * 64; e += 256) {
    const int u = e >> 6, dd = e & 63;
    Ks[u][dd] = Ksamp[((size_t)bh * U_ + u) * 64 + dd];
  }
  const int n = cnt[bh];
  const int stride = 8 * gridDim.y;
  for (int c0 = g * 8; c0 < n; c0 += stride) {
    const int nc = min(8, n - c0);
    __syncthreads();
    if (t < 8) rows[t] = list[(size_t)bh * CAP_ + c0 + min(t, nc - 1)];
    float acc[8];
#pragma unroll
    for (int r = 0; r < 8; r++) acc[r] = 0.f;
    for (int kc = 0; kc < 4; kc++) {
      __syncthreads();
#pragma unroll
      for (int i = 0; i < 8; i++)
        Xs[i][t] = X[((size_t)b * L_ + rows[i]) * DM_ + kc * 256 + t];
      __syncthreads();
#pragma unroll
      for (int k4 = 0; k4 < 16; k4++) {
        const int kb = kc * 256 + p * 64 + k4 * 4;
        const float w0 = Wq[(size_t)(kb + 0) * DM_ + h * 64 + d];
        const float w1 = Wq[(size_t)(kb + 1) * DM_ + h * 64 + d];
        const float w2 = Wq[(size_t)(kb + 2) * DM_ + h * 64 + d];
        const float w3 = Wq[(size_t)(kb + 3) * DM_ + h * 64 + d];
#pragma unroll
        for (int r = 0; r < 8; r++) {
          const float4 x = *(const float4*)&Xs[r][p * 64 + k4 * 4];
          acc[r] += x.x * w0 + x.y * w1 + x.z * w2 + x.w * w3;
        }
      }
    }
#pragma unroll
    for (int r = 0; r < 8; r++) red[p][r][d] = acc[r];
    __syncthreads();
    if (p == 0) {
#pragma unroll
      for (int r = 0; r < 8; r++)
        qd[r][d] = red[0][r][d] + red[1][r][d] + red[2][r][d] + red[3][r][d] + bq[h * 64 + d];
    }
    __syncthreads();
    for (int idx = t; idx < 8 * U_; idx += 256) {
      const int c = idx / U_, u = idx - c * U_;
      float s = 0.f;
#pragma unroll 8
      for (int dd = 0; dd < 64; dd++) s += qd[c][dd] * Ks[u][dd];
      sc[c][u] = s;
    }
    __syncthreads();
    if (t < nc) {
      float mx = sc[t][0], sm = sc[t][0];
      for (int u = 1; u < U_; u++) { mx = fmaxf(mx, sc[t][u]); sm += sc[t][u]; }
      candM[(size_t)bh * CAP_ + c0 + t] = mx - sm * (1.f / (float)U_);
    }
  }
}

// ---------- select_b: final top-45 over candidates (exact M, idx tie-break) ----------
__global__ __launch_bounds__(256) void select_b(const float* __restrict__ candM,
    const int* __restrict__ list, const int* __restrict__ cnt, int* __restrict__ topidx) {
  const int bh = blockIdx.x, t = threadIdx.x;
  __shared__ float mv[CAP_];
  __shared__ int   ml[CAP_];
  __shared__ float rv[256];
  __shared__ int   ri[256];
  const int n = cnt[bh];
  for (int i = t; i < CAP_; i += 256) {
    mv[i] = (i < n) ? candM[(size_t)bh * CAP_ + i] : -3.4e38f;
    ml[i] = (i < n) ? list[(size_t)bh * CAP_ + i] : 0x7fffffff;
  }
  __syncthreads();
  for (int it = 0; it < U_; it++) {
    float bv = mv[t]; int bi = ml[t]; int bj = t;
    {
      const float v = mv[t + 256]; const int l2 = ml[t + 256];
      if (v > bv || (v == bv && l2 < bi)) { bv = v; bi = l2; bj = t + 256; }
    }
    rv[t] = bv; ri[t] = bj;
    __syncthreads();
    for (int s = 128; s > 0; s >>= 1) {
      if (t < s) {
        const float v2 = rv[t + s];
        const int slot2 = ri[t + s];
        if (v2 > rv[t] || (v2 == rv[t] && ml[slot2] < ml[ri[t]])) {
          rv[t] = v2; ri[t] = slot2;
        }
      }
      __syncthreads();
    }
    if (t == 0) {
      topidx[bh * U_ + it] = ml[ri[0]];
      mv[ri[0]] = -3.4e38f;
    }
    __syncthreads();
  }
}

// ---------- qsel3: exact selected Q rows, split-K partials ----------
__global__ __launch_bounds__(256) void qsel3(const float* __restrict__ X,
    const float* __restrict__ Wq, const int* __restrict__ topidx,
    float* __restrict__ qpart) {
  const int bh = blockIdx.x;
  const int ug = blockIdx.y >> 2, kc = blockIdx.y & 3;
  const int b = bh >> 4, h = bh & 15;
  __shared__ float Xs[15][256];
  __shared__ int rows[15];
  const int t = threadIdx.x, p = t >> 6, d = t & 63;
  if (t < 15) rows[t] = topidx[bh * U_ + ug * 15 + t];
  __syncthreads();
#pragma unroll
  for (int i = 0; i < 15; i++)
    Xs[i][t] = X[((size_t)b * L_ + rows[i]) * DM_ + kc * 256 + t];
  __syncthreads();
  float acc[15];
#pragma unroll
  for (int r = 0; r < 15; r++) acc[r] = 0.f;
#pragma unroll
  for (int k4 = 0; k4 < 16; k4++) {
    const int kb = kc * 256 + p * 64 + k4 * 4;
    const float w0 = Wq[(size_t)(kb + 0) * DM_ + h * 64 + d];
    const float w1 = Wq[(size_t)(kb + 1) * DM_ + h * 64 + d];
    const float w2 = Wq[(size_t)(kb + 2) * DM_ + h * 64 + d];
    const float w3 = Wq[(size_t)(kb + 3) * DM_ + h * 64 + d];
#pragma unroll
    for (int r = 0; r < 15; r++) {
      const float4 x = *(const float4*)&Xs[r][p * 64 + k4 * 4];
      acc[r] += x.x * w0 + x.y * w1 + x.z * w2 + x.w * w3;
    }
  }
  const int p16 = kc * 4 + p;       // partial slot 0..15
  float* dst = qpart + (((size_t)p16 * BH_ + bh) * 48 + ug * 15) * 64 + d;
#pragma unroll
  for (int r = 0; r < 15; r++) dst[(size_t)r * 64] = acc[r];
}

// combine 16 partials (fixed order) + bias -> bf16 Qbf; zero pad rows
__global__ __launch_bounds__(256) void qsel_comb(const float* __restrict__ qpart,
    const float* __restrict__ bq, unsigned short* __restrict__ Qbf) {
  const int idx = blockIdx.x * 256 + threadIdx.x;   // < BH_*48*64
  const int d = idx & 63, u48 = (idx >> 6) % 48, bh = idx / (48 * 64);
  const int h = bh & 15;
  if (u48 < U_) {
    const size_t o = (((size_t)bh) * 48 + u48) * 64 + d;
    const size_t stride = (size_t)BH_ * 48 * 64;
    float s = bq[h * 64 + d];
#pragma unroll
    for (int p16 = 0; p16 < 16; p16++) s += qpart[o + (size_t)p16 * stride];
    Qbf[o] = f2bf(s);
  } else {
    Qbf[(((size_t)bh) * 48 + u48) * 64 + d] = 0;
  }
}

// ---------- V mean from V^T rows (contiguous, deterministic) ----------
__global__ __launch_bounds__(256) void vmean_vt(const unsigned short* __restrict__ VT,
                                                float* __restrict__ Vm) {
  const int row = blockIdx.x * 4 + (threadIdx.x >> 6);   // 8192 rows total
  const int lane = threadIdx.x & 63;
  const unsigned short* src = VT + (size_t)row * L_ + lane * 64;
  float s = 0.f;
#pragma unroll
  for (int c = 0; c < 8; c++) {
    const ushort8 v = *(const ushort8*)&src[c * 8];
#pragma unroll
    for (int x = 0; x < 8; x++) s += bf2f(v[x]);
  }
  for (int off = 32; off > 0; off >>= 1) s += __shfl_xor(s, off);
  if (lane == 0) Vm[row] = s * (1.f / (float)L_);
}

// ---------- stage1: MFMA QK^T + MFMA PV over bf16 P; no-max softmax ----------
__global__ __launch_bounds__(256) void attn_stage1(const unsigned short* __restrict__ Qbf,
    const unsigned short* __restrict__ Kbf, const unsigned short* __restrict__ VT,
    float* __restrict__ part) {
  const int bh = blockIdx.x, split = blockIdx.y;
  const int b = bh >> 4, h = bh & 15;
  __shared__ unsigned short sQ[48][72];
  __shared__ unsigned short sK[64][72];
  __shared__ unsigned short sVT[64][72];   // [d][key]
  __shared__ unsigned short esb[48][68];   // P bf16 [q][key]
  __shared__ float sS[4][48];
  __shared__ float S_total[48];
  const int tid = threadIdx.x, wid = tid >> 6, lane = tid & 63;
  const int fr = lane & 15, fq = lane >> 4;
  for (int e = tid; e < 48 * 8; e += 256) {
    const int r = e >> 3, c8 = (e & 7) * 8;
    *(ushort8*)&sQ[r][c8] = *(const ushort8*)&Qbf[((size_t)bh * 48 + r) * 64 + c8];
  }
  if (tid < 48) S_total[tid] = 0.f;
  __syncthreads();
  short8 qf[3][2];
#pragma unroll
  for (int nt = 0; nt < 3; nt++)
#pragma unroll
    for (int kh = 0; kh < 2; kh++)
      qf[nt][kh] = *(const short8*)&sQ[nt * 16 + fr][kh * 32 + fq * 8];

  f32x4 acc[3];
#pragma unroll
  for (int mt = 0; mt < 3; mt++) acc[mt] = f32x4{0.f, 0.f, 0.f, 0.f};

  for (int t = 0; t < 8; t++) {
    const int k0 = split * 512 + t * 64;
    if (t) __syncthreads();               // barrier A: prev PV + S_total add done
    for (int e = tid; e < 64 * 8; e += 256) {
      const int r = e >> 3, c8 = (e & 7) * 8;
      *(ushort8*)&sK[r][c8] =
          *(const ushort8*)&Kbf[((size_t)b * L_ + k0 + r) * DM_ + h * 64 + c8];
      *(ushort8*)&sVT[r][c8] =
          *(const ushort8*)&VT[((size_t)(b * 1024 + h * 64 + r)) * L_ + k0 + c8];
    }
    __syncthreads();                      // barrier B
    const short8 kf0 = *(const short8*)&sK[wid * 16 + fr][fq * 8];
    const short8 kf1 = *(const short8*)&sK[wid * 16 + fr][32 + fq * 8];
    f32x4 accq[3];
#pragma unroll
    for (int nt = 0; nt < 3; nt++) {
      accq[nt] = f32x4{0.f, 0.f, 0.f, 0.f};
      accq[nt] = __builtin_amdgcn_mfma_f32_16x16x32_bf16(kf0, qf[nt][0], accq[nt], 0, 0, 0);
      accq[nt] = __builtin_amdgcn_mfma_f32_16x16x32_bf16(kf1, qf[nt][1], accq[nt], 0, 0, 0);
    }
#pragma unroll
    for (int nt = 0; nt < 3; nt++) {
      float sp = 0.f;
#pragma unroll
      for (int r = 0; r < 4; r++) {
        const float e = expf(accq[nt][r] * 0.125f);   // |score| bounded: no max
        sp += e;
        esb[nt * 16 + fr][wid * 16 + fq * 4 + r] = f2bf(e);
      }
      sp += __shfl_xor(sp, 16);
      sp += __shfl_xor(sp, 32);
      if (fq == 0) sS[wid][nt * 16 + fr] = sp;
    }
    __syncthreads();                      // barrier C
    if (tid < 48) S_total[tid] += sS[0][tid] + sS[1][tid] + sS[2][tid] + sS[3][tid];
    const short8 vb0 = *(const short8*)&sVT[wid * 16 + fr][fq * 8];
    const short8 vb1 = *(const short8*)&sVT[wid * 16 + fr][32 + fq * 8];
#pragma unroll
    for (int mt = 0; mt < 3; mt++) {
      const short8 pa0 = *(const short8*)&esb[mt * 16 + fr][fq * 8];
      const short8 pa1 = *(const short8*)&esb[mt * 16 + fr][32 + fq * 8];
      acc[mt] = __builtin_amdgcn_mfma_f32_16x16x32_bf16(pa0, vb0, acc[mt], 0, 0, 0);
      acc[mt] = __builtin_amdgcn_mfma_f32_16x16x32_bf16(pa1, vb1, acc[mt], 0, 0, 0);
    }
  }
  __syncthreads();
#pragma unroll
  for (int u = 0; u < U_; u++) {
    const int mt = u >> 4, fqq = (u >> 2) & 3, r = u & 3;
    float* pb = part + ((size_t)(bh * NSPLIT + split) * U_ + u) * 65;
    if (fq == fqq) pb[1 + wid * 16 + fr] = acc[mt][r];
    if (tid == fqq * 16) pb[0] = S_total[u];
  }
}

// ---------- combine splits; dctx = ctx/S - Vmean ----------
__global__ __launch_bounds__(256) void attn_stage2(const float* __restrict__ part,
    const float* __restrict__ Vm, float* __restrict__ dctx) {
  const int bh = blockIdx.x;
  const int wid = threadIdx.x >> 6, lane = threadIdx.x & 63;
  for (int u = wid; u < U_; u += 4) {
    float S = 0.f, c = 0.f;
#pragma unroll
    for (int sp = 0; sp < NSPLIT; sp++) {
      const float* pb = part + ((size_t)(bh * NSPLIT + sp) * U_ + u) * 65;
      S += pb[0];
      c += pb[1 + lane];
    }
    dctx[((size_t)bh * U_ + u) * 64 + lane] = c / S - Vm[bh * 64 + lane];
  }
}

// ---------- base[b][:] = concat_h(Vmean) @ Wo + bo ----------
__global__ __launch_bounds__(256) void base_k(const float* __restrict__ Vm,
    const float* __restrict__ Wo, const float* __restrict__ bo, float* __restrict__ base) {
  const int b = blockIdx.y;
  const int j = blockIdx.x * 256 + threadIdx.x;
  float acc = bo[j];
#pragma unroll 8
  for (int i = 0; i < DM_; i++) acc += Vm[b * DM_ + i] * Wo[(size_t)i * DM_ + j];
  base[b * DM_ + j] = acc;
}

// ---------- gemm_upd: rowupd[bh][u][:] = dctx[bh] @ Wo_h ----------
__global__ __launch_bounds__(256) void gemm_upd(const float* __restrict__ dctx,
    const float* __restrict__ Wo, float* __restrict__ rowupd) {
  const int bh = blockIdx.y, h = bh & 15;
  const int col = blockIdx.x * 256 + threadIdx.x;
  __shared__ float dc[U_][68];
  for (int e = threadIdx.x; e < U_ * 64; e += 256) {
    const int u = e >> 6, d = e & 63;
    dc[u][d] = dctx[(size_t)bh * U_ * 64 + e];
  }
  __syncthreads();
  float acc[U_];
#pragma unroll
  for (int u = 0; u < U_; u++) acc[u] = 0.f;
  for (int d = 0; d < 64; d++) {
    const float w = Wo[(size_t)(h * 64 + d) * DM_ + col];
#pragma unroll
    for (int u = 0; u < U_; u++) acc[u] += dc[u][d] * w;   // dc broadcast read
  }
#pragma unroll
  for (int u = 0; u < U_; u++)
    rowupd[((size_t)bh * U_ + u) * DM_ + col] = acc[u];
}

// ---------- build_list: per selected row, head-mask + slot ----------
__global__ __launch_bounds__(256) void build_list(const int* __restrict__ topidx,
    int* __restrict__ rowmask, unsigned char* __restrict__ slotU) {
  const int i = blockIdx.x * 256 + threadIdx.x;
  if (i >= BH_ * U_) return;
  const int bh = i / U_, u = i - bh * U_;
  const int b = bh >> 4, h = bh & 15;
  const int key = b * L_ + topidx[i];
  slotU[key * 16 + h] = (unsigned char)u;
  atomicOr(&rowmask[key], 1 << h);
}

// ---------- fill2: out[row] = base[b] (+ fixed-h-order sum of head updates) ----------
__global__ __launch_bounds__(256) void fill2(const float* __restrict__ rowupd,
    const float* __restrict__ base, const int* __restrict__ rowmask,
    const unsigned char* __restrict__ slotU, float* __restrict__ out) {
  const int key = blockIdx.x;                    // 0..ML_-1
  const int b = key >> 12;                       // L_ = 4096
  const int mask = rowmask[key];
  const int j4 = threadIdx.x * 4;
  float4 a = *(const float4*)&base[b * DM_ + j4];
  if (mask) {
#pragma unroll
    for (int h = 0; h < 16; h++) {
      if (mask & (1 << h)) {
        const int u = slotU[key * 16 + h];
        const float4 r = *(const float4*)&rowupd[((size_t)(b * 16 + h) * U_ + u) * DM_ + j4];
        a.x += r.x; a.y += r.y; a.z += r.z; a.w += r.w;
      }
    }
  }
  *(float4*)&out[(size_t)key * DM_ + j4] = a;
}

extern "C" void kernel_launch(void* const* d_in, const int* in_sizes, int n_in,
                              void* d_out, int out_size, void* d_ws, size_t ws_size,
                              hipStream_t stream) {
  const float* queries = (const float*)d_in[0];
  const float* keys    = (const float*)d_in[1];
  const float* values  = (const float*)d_in[2];
  const float* Wq = (const float*)d_in[3]; const float* bq = (const float*)d_in[4];
  const float* Wk = (const float*)d_in[5]; const float* bk = (const float*)d_in[6];
  const float* Wv = (const float*)d_in[7]; const float* bv = (const float*)d_in[8];
  const float* Wo = (const float*)d_in[9]; const float* bo = (const float*)d_in[10];
  const int* sidx = (const int*)d_in[11];

  // K (row-major) and V^T live as bf16 in d_out until the epilogue
  unsigned short* Kbf = (unsigned short*)d_out;
  unsigned short* VT  = Kbf + (size_t)ML_ * DM_;

  uint8_t* p = (uint8_t*)d_ws;
  auto carve = [&](size_t bytes) { uint8_t* r = p; p += (bytes + 255) & ~(size_t)255; return r; };
  float* QKs = (float*)carve((size_t)CROWS_ * NP_ * 4);                     // 50.3 MB
  unsigned short* Ph = (unsigned short*)carve((size_t)B_ * NP_ * DM_ * 2);  // 12.6 MB
  unsigned short* WkT = (unsigned short*)carve((size_t)DM_ * DM_ * 2);
  unsigned short* WvT = (unsigned short*)carve((size_t)DM_ * DM_ * 2);
  float* Mbuf  = (float*)carve((size_t)BH_ * L_ * 4);                       // 2.1 MB
  float* Ksamp = (float*)carve((size_t)BH_ * U_ * 64 * 4);                  // 1.5 MB
  float* kpart = (float*)carve((size_t)4 * B_ * U_ * 1024 * 4);             // 5.9 MB
  float* qpart = (float*)carve((size_t)16 * BH_ * 48 * 64 * 4);             // 25.2 MB
  int*   list  = (int*)carve((size_t)BH_ * CAP_ * 4);                       // 256 KB
  float* candM = (float*)carve((size_t)BH_ * CAP_ * 4);                     // 256 KB
  int*   cntb  = (int*)carve((size_t)BH_ * 4);
  int*   topidx = (int*)carve((size_t)BH_ * U_ * 4);
  float* Vm    = (float*)carve((size_t)BH_ * 64 * 4);
  unsigned short* Qbf = (unsigned short*)carve((size_t)BH_ * 48 * 64 * 2);  // 786 KB
  int*   rowmask = (int*)carve((size_t)B_ * L_ * 4);                        // 128 KB (memset)
  unsigned char* slotU = (unsigned char*)carve((size_t)B_ * L_ * 16);       // 512 KB
  const size_t need = (size_t)(p - (uint8_t*)d_ws);
  if (ws_size < need)
    fprintf(stderr, "ATHENA_WS: need %zu have %zu (WILL FAULT)\n", need, ws_size);

  // late-phase buffers alias QKs (dead after mpass)
  uint8_t* ap = (uint8_t*)QKs;
  auto acarve = [&](size_t bytes) { uint8_t* r = ap; ap += (bytes + 255) & ~(size_t)255; return r; };
  float* part  = (float*)acarve((size_t)BH_ * NSPLIT * U_ * 65 * 4);        // 12 MB
  float* dctx  = (float*)acarve((size_t)BH_ * U_ * 64 * 4);
  float* base  = (float*)acarve((size_t)B_ * DM_ * 4);
  float* rowupd = (float*)acarve((size_t)BH_ * U_ * DM_ * 4);               // 23.6 MB

  ksel3<<<dim3(4, B_, 12), 256, 0, stream>>>(keys, Wk, sidx, kpart);
  ksel_comb<<<(B_ * U_ * 1024) / 256, 256, 0, stream>>>(kpart, bk, Ksamp);
  pform_k<<<BH_, 256, 0, stream>>>(Wq, Ksamp, Ph);
  wT_single<<<4096, 256, 0, stream>>>(Wk, WkT);
  wT_single<<<4096, 256, 0, stream>>>(Wv, WvT);

  for (int c = 0; c < 2; c++) {
    const size_t off = (size_t)c * CROWS_ * DM_;
    gemm_f<0><<<dim3(8, 128), 256, 0, stream>>>(keys + off, WkT, bk, Kbf + off, 0, 0);
    gemm_f<1><<<dim3(8, 128), 256, 0, stream>>>(values + off, WvT, bv, VT, c * CROWS_, 0);
    gemm_f<2><<<dim3(6, 128), 256, 0, stream>>>(queries + off, Ph, bq, QKs, 0, c);
    mpass_k<<<(CROWS_ * 16) / 256, 256, 0, stream>>>(QKs, Mbuf, c);
  }

  select_a<<<BH_, 256, 0, stream>>>(Mbuf, list, cntb);
  exactM2<<<dim3(BH_, 16), 256, 0, stream>>>(queries, Wq, bq, Ksamp, list, cntb, candM);
  select_b<<<BH_, 256, 0, stream>>>(candM, list, cntb, topidx);
  qsel3<<<dim3(BH_, 12), 256, 0, stream>>>(queries, Wq, topidx, qpart);
  qsel_comb<<<(BH_ * 48 * 64) / 256, 256, 0, stream>>>(qpart, bq, Qbf);
  vmean_vt<<<(BH_ * 64) / 4, 256, 0, stream>>>(VT, Vm);
  attn_stage1<<<dim3(BH_, NSPLIT), 256, 0, stream>>>(Qbf, Kbf, VT, part);
  attn_stage2<<<BH_, 256, 0, stream>>>(part, Vm, dctx);
  base_k<<<dim3(DM_ / 256, B_), 256, 0, stream>>>(Vm, Wo, bo, base);

  // epilogue: deterministic
  hipMemsetAsync(rowmask, 0, (size_t)B_ * L_ * 4, stream);
  gemm_upd<<<dim3(4, BH_), 256, 0, stream>>>(dctx, Wo, rowupd);
  build_list<<<(BH_ * U_ + 255) / 256, 256, 0, stream>>>(topidx, rowmask, slotU);
  fill2<<<ML_, 256, 0, stream>>>(rowupd, base, rowmask, slotU, (float*)d_out);
}

// Round 14
// 1063.906 us; speedup vs baseline: 1.0516x; 1.0387x over previous
//
#include <hip/hip_runtime.h>
#include <cstdint>
#include <cstdio>

#define B_   8
#define L_   4096
#define DM_  1024
#define H_   16
#define D_   64
#define U_   45
#define BH_  (B_*H_)
#define ML_  (B_*L_)
#define NSPLIT 8
#define NP_  768           // padded QK-sample width: 16 heads * 48
#define CB_  4             // batches per chunk
#define CROWS_ (CB_*L_)    // 16384 rows per chunk
#define CAP_ 512           // candidate cap per (b,h)
#define DELTA_ 0.12f       // exact-recompute band (~9 sigma of bf16 GEMM err)

using f32x4   = __attribute__((ext_vector_type(4))) float;
using short8  = __attribute__((ext_vector_type(8))) short;
using ushort8 = __attribute__((ext_vector_type(8))) unsigned short;

__device__ __forceinline__ unsigned short f2bf(float f) {
  uint32_t u = __float_as_uint(f);
  u += 0x7fffu + ((u >> 16) & 1u);      // RNE; inputs finite
  return (unsigned short)(u >> 16);
}
__device__ __forceinline__ float bf2f(unsigned short h) {
  return __uint_as_float(((uint32_t)h) << 16);
}

__device__ __forceinline__ void gload16(const void* g, void* l) {
  __builtin_amdgcn_global_load_lds((const __attribute__((address_space(1))) void*)g,
                                   (__attribute__((address_space(3))) void*)l,
                                   16, 0, 0);
}

// ---------- W (KxN) -> W^T bf16 (NxK) ----------
__global__ __launch_bounds__(256) void wT_single(const float* __restrict__ W,
                                                 unsigned short* __restrict__ WT) {
  const int idx = blockIdx.x * 256 + threadIdx.x;   // 1M threads
  const int n = idx >> 10, kk = idx & 1023;
  WT[idx] = f2bf(W[kk * 1024 + n]);
}

// ---------- fused-convert bf16 GEMM, BK=64 2-deep pipelined A-staging ----------
// A = fp32 X (reg-staged, converted in-flight), B = bf16 W^T via global_load_lds.
// MODE 0: bf16 row-major C (stride 1024) + bias
// MODE 1: bf16 transposed-out VT[(b*1024+col)][l] via LDS half-passes + bias
// MODE 2: fp32 C (stride NP_), per-batch B = Ph
template <int MODE>
__global__ __launch_bounds__(256) void gemm_f(const float* __restrict__ Af,
    const unsigned short* __restrict__ Bg, const float* __restrict__ bias,
    void* __restrict__ Cout, int rowbase, int chunk) {
  constexpr int K = 1024;
  constexpr int NX = (MODE == 2) ? 6 : 8;
  constexpr int NWG = NX * 128;
  __shared__ unsigned short sA[2][128 * 32];
  __shared__ unsigned short sB[2][128 * 32];
  const int tid = threadIdx.x, wid = tid >> 6, lane = tid & 63;
  const int orig = blockIdx.y * NX + blockIdx.x;
  const int g = (orig & 7) * (NWG / 8) + (orig >> 3);   // bijective (NWG % 8 == 0)
  const int by = g / NX, bx = g % NX;
  const int m0 = by * 128, n0 = bx * 128;
  const unsigned short* __restrict__ Bgh =
      (MODE == 2) ? Bg + (size_t)(chunk * CB_ + (by >> 5)) * NP_ * K : Bg;
  const int wr = wid >> 1, wc = wid & 1;
  const int fr = lane & 15, fq = lane >> 4;
  const int srow = lane >> 2, scol = (lane & 3) * 8;
  const int arow = tid >> 3, acol = (tid & 7) * 4;
  f32x4 acc[4][4];
#pragma unroll
  for (int i = 0; i < 4; i++)
#pragma unroll
    for (int j = 0; j < 4; j++) acc[i][j] = f32x4{0.f, 0.f, 0.f, 0.f};

  float4 xr[2][4];
#pragma unroll
  for (int s = 0; s < 2; s++)
#pragma unroll
    for (int pq = 0; pq < 4; pq++)
      xr[s][pq] = *(const float4*)&Af[(size_t)(m0 + pq * 32 + arow) * K + s * 32 + acol];

  for (int k0 = 0; k0 < K; k0 += 64) {
    // B: async global->LDS for both halves
#pragma unroll
    for (int s = 0; s < 2; s++)
#pragma unroll
      for (int c = 0; c < 2; c++) {
        const int ch = wid * 2 + c;
        const int row = ch * 16 + srow;
        gload16(Bgh + (size_t)(n0 + row) * K + (k0 + s * 32 + scol), &sB[s][ch * 512]);
      }
    // A: write previously-staged regs (no wait), convert in-flight
#pragma unroll
    for (int s = 0; s < 2; s++)
#pragma unroll
      for (int pq = 0; pq < 4; pq++) {
        const int row = pq * 32 + arow;
        ushort4 hv;
        hv.x = f2bf(xr[s][pq].x); hv.y = f2bf(xr[s][pq].y);
        hv.z = f2bf(xr[s][pq].z); hv.w = f2bf(xr[s][pq].w);
        *(ushort4*)&sA[s][row * 32 + acol] = hv;
      }
    // prefetch next BK=64 block (latency hides under MFMAs + barrier drain)
    if (k0 + 64 < K) {
#pragma unroll
      for (int s = 0; s < 2; s++)
#pragma unroll
        for (int pq = 0; pq < 4; pq++)
          xr[s][pq] = *(const float4*)&Af[(size_t)(m0 + pq * 32 + arow) * K +
                                          (k0 + 64 + s * 32) + acol];
    }
    __syncthreads();
#pragma unroll
    for (int s = 0; s < 2; s++) {
      short8 ah[4], bh[4];
#pragma unroll
      for (int i = 0; i < 4; i++) {
        ah[i] = *(const short8*)&sA[s][(wr * 64 + i * 16 + fr) * 32 + fq * 8];
        bh[i] = *(const short8*)&sB[s][(wc * 64 + i * 16 + fr) * 32 + fq * 8];
      }
#pragma unroll
      for (int i = 0; i < 4; i++)
#pragma unroll
        for (int j = 0; j < 4; j++)
          acc[i][j] = __builtin_amdgcn_mfma_f32_16x16x32_bf16(ah[i], bh[j], acc[i][j], 0, 0, 0);
    }
    __syncthreads();
  }

  if (MODE == 0) {
    unsigned short* C = (unsigned short*)Cout;
#pragma unroll
    for (int j = 0; j < 4; j++) {
      const int col = n0 + wc * 64 + j * 16 + fr;
      const float bv = bias[col];
#pragma unroll
      for (int i = 0; i < 4; i++) {
        const int row = m0 + wr * 64 + i * 16 + fq * 4;
#pragma unroll
        for (int r = 0; r < 4; r++)
          C[(size_t)(row + r) * 1024 + col] = f2bf(acc[i][j][r] + bv);
      }
    }
  } else if (MODE == 2) {
    float* C = (float*)Cout;
#pragma unroll
    for (int j = 0; j < 4; j++) {
      const int col = n0 + wc * 64 + j * 16 + fr;
#pragma unroll
      for (int i = 0; i < 4; i++) {
        const int row = m0 + wr * 64 + i * 16 + fq * 4;
#pragma unroll
        for (int r = 0; r < 4; r++) C[(size_t)(row + r) * NP_ + col] = acc[i][j][r];
      }
    }
  } else {
    // MODE 1: transpose via LDS in two 64-l half-passes, coalesced V^T writes
    __shared__ unsigned short sC[128][68];
    unsigned short* VT = (unsigned short*)Cout;
    const int grow0 = rowbase + m0;
    const int b = grow0 >> 12, l0 = grow0 & 4095;      // L_ = 4096
#pragma unroll
    for (int pass = 0; pass < 2; pass++) {
      if (pass) __syncthreads();
      if (wr == pass) {
#pragma unroll
        for (int j = 0; j < 4; j++) {
          const int col = wc * 64 + j * 16 + fr;       // d within tile
          const float bv = bias[n0 + col];
#pragma unroll
          for (int i = 0; i < 4; i++) {
            const int lrow = i * 16 + fq * 4;          // l within half
#pragma unroll
            for (int r = 0; r < 4; r++) sC[col][lrow + r] = f2bf(acc[i][j][r] + bv);
          }
        }
      }
      __syncthreads();
#pragma unroll
      for (int it = 0; it < 8; it++) {
        const int row = it * 16 + (tid >> 4);
        const int seg = (tid & 15) * 4;
        const ushort4 v = *(const ushort4*)&sC[row][seg];
        *(ushort4*)&VT[((size_t)(b * 1024 + n0 + row)) * L_ + l0 + pass * 64 + seg] = v;
      }
    }
  }
}

// ---------- ksel3: exact fp32 sampled-K rows, split-K column-parallel ----------
__global__ __launch_bounds__(256) void ksel3(const float* __restrict__ X,
    const float* __restrict__ Wk, const int* __restrict__ sidx,
    float* __restrict__ kpart) {
  const int t = threadIdx.x;
  const int col = blockIdx.x * 256 + t;
  const int b = blockIdx.y;
  const int ug = blockIdx.z >> 2, kc = blockIdx.z & 3;
  __shared__ float Xs[15][256];
  __shared__ int rows[15];
  if (t < 15) rows[t] = sidx[ug * 15 + t];
  __syncthreads();
#pragma unroll
  for (int i = 0; i < 15; i++)
    Xs[i][t] = X[((size_t)b * L_ + rows[i]) * DM_ + kc * 256 + t];
  __syncthreads();
  float acc[15];
#pragma unroll
  for (int r = 0; r < 15; r++) acc[r] = 0.f;
  for (int k4 = 0; k4 < 64; k4++) {
    const int kb = kc * 256 + k4 * 4;
    const float w0 = Wk[(size_t)(kb + 0) * DM_ + col];
    const float w1 = Wk[(size_t)(kb + 1) * DM_ + col];
    const float w2 = Wk[(size_t)(kb + 2) * DM_ + col];
    const float w3 = Wk[(size_t)(kb + 3) * DM_ + col];
#pragma unroll
    for (int r = 0; r < 15; r++) {
      const float4 x = *(const float4*)&Xs[r][k4 * 4];
      acc[r] += x.x * w0 + x.y * w1 + x.z * w2 + x.w * w3;
    }
  }
  float* dst = kpart + (((size_t)kc * B_ + b) * U_ + ug * 15) * 1024 + col;
#pragma unroll
  for (int r = 0; r < 15; r++) dst[(size_t)r * 1024] = acc[r];
}

// combine: Ksamp = sum_kc kpart + bias (fixed order)
__global__ __launch_bounds__(256) void ksel_comb(const float* __restrict__ kpart,
    const float* __restrict__ bk, float* __restrict__ Ksamp) {
  const int idx = blockIdx.x * 256 + threadIdx.x;   // < 360*1024
  const int col = idx & 1023, ru = idx >> 10;
  const int b = ru / U_, u = ru - b * U_;
  const size_t o = ((size_t)b * U_ + u) * 1024 + col;
  const size_t stride = (size_t)B_ * U_ * 1024;
  float s = kpart[o] + kpart[o + stride] + kpart[o + 2 * stride] + kpart[o + 3 * stride]
          + bk[col];
  const int h = col >> 6, d = col & 63;
  Ksamp[((size_t)(b * 16 + h) * U_ + u) * 64 + d] = s;
}

// ---------- P^T[b][h*48+u][k] = sum_d Wq[k][h*64+d]*Ksamp (bf16 hi) ----------
__global__ __launch_bounds__(256) void pform_k(const float* __restrict__ Wq,
    const float* __restrict__ Ksamp, unsigned short* __restrict__ Ph) {
  const int bh = blockIdx.x, b = bh >> 4, h = bh & 15;
  __shared__ float Ks[U_][68];
  const int t = threadIdx.x;
  for (int e = t; e < U_ * 64; e += 256) {
    const int u = e >> 6, d = e & 63;
    Ks[u][d] = Ksamp[((size_t)bh * U_ + u) * 64 + d];
  }
  __syncthreads();
  for (int kc = 0; kc < 4; kc++) {
    const int k = kc * 256 + t;
    float wr[64];
#pragma unroll
    for (int dd = 0; dd < 16; dd++) {
      const float4 w4 = *(const float4*)&Wq[(size_t)k * DM_ + h * 64 + dd * 4];
      wr[dd * 4 + 0] = w4.x; wr[dd * 4 + 1] = w4.y;
      wr[dd * 4 + 2] = w4.z; wr[dd * 4 + 3] = w4.w;
    }
    for (int u = 0; u < 48; u++) {
      size_t o = ((size_t)b * NP_ + h * 48 + u) * 1024 + k;
      if (u < U_) {
        float acc = 0.f;
#pragma unroll
        for (int d = 0; d < 64; d++) acc += wr[d] * Ks[u][d];
        Ph[o] = f2bf(acc);
      } else {
        Ph[o] = 0;
      }
    }
  }
}

// ---------- M_approx = max - mean over u ----------
__global__ __launch_bounds__(256) void mpass_k(const float* __restrict__ QKs,
                                               float* __restrict__ Mbuf, int chunk) {
  const int idx = blockIdx.x * 256 + threadIdx.x;   // < CROWS_*16
  const int ll = idx >> 4, h = idx & 15;
  const float* row = QKs + (size_t)ll * NP_ + h * 48;
  float mx = row[0], sm = row[0];
#pragma unroll
  for (int u = 1; u < U_; u++) { const float v = row[u]; mx = fmaxf(mx, v); sm += v; }
  const int lg = chunk * CROWS_ + ll;
  const int b = lg >> 12, l = lg & 4095;
  Mbuf[((size_t)(b * 16 + h)) * L_ + l] = mx - sm * (1.f / (float)U_);
}

// ---------- select_a: approx top-45 -> thr; candidates = {M >= thr - DELTA} ----------
__global__ __launch_bounds__(256) void select_a(const float* __restrict__ Mbuf,
    int* __restrict__ list, int* __restrict__ cnt) {
  const int bh = blockIdx.x, t = threadIdx.x;
  __shared__ float vals[L_];
  __shared__ float rv[256];
  __shared__ int   ri[256];
  __shared__ int   scnt;
  __shared__ float sthr;
  if (t == 0) scnt = 0;
  for (int i = t; i < L_; i += 256) vals[i] = Mbuf[(size_t)bh * L_ + i];
  __syncthreads();
  for (int it = 0; it < U_; it++) {
    float bv = vals[t * 16]; int bi = t * 16;
#pragma unroll
    for (int jj = 1; jj < 16; jj++) {
      const float v = vals[t * 16 + jj];
      if (v > bv) { bv = v; bi = t * 16 + jj; }
    }
    rv[t] = bv; ri[t] = bi;
    __syncthreads();
    for (int s = 128; s > 0; s >>= 1) {
      if (t < s) {
        if (rv[t + s] > rv[t] || (rv[t + s] == rv[t] && ri[t + s] < ri[t])) {
          rv[t] = rv[t + s]; ri[t] = ri[t + s];
        }
      }
      __syncthreads();
    }
    if (t == 0) {
      list[(size_t)bh * CAP_ + it] = ri[0];
      vals[ri[0]] = -3.4e38f;
      if (it == U_ - 1) sthr = rv[0];
    }
    __syncthreads();
  }
  const float lim = sthr - DELTA_;
  for (int i = t; i < L_; i += 256) {
    if (vals[i] >= lim) {
      const int j = atomicAdd(&scnt, 1);
      if (U_ + j < CAP_) list[(size_t)bh * CAP_ + U_ + j] = i;
    }
  }
  __syncthreads();
  if (t == 0) cnt[bh] = min(U_ + scnt, CAP_);
}

// ---------- exactM2: fp32 recompute of M for candidates ----------
__global__ __launch_bounds__(256) void exactM2(const float* __restrict__ X,
    const float* __restrict__ Wq, const float* __restrict__ bq,
    const float* __restrict__ Ksamp, const int* __restrict__ list,
    const int* __restrict__ cnt, float* __restrict__ candM) {
  const int bh = blockIdx.x, g = blockIdx.y, b = bh >> 4, h = bh & 15;
  __shared__ float Ks[U_][68];
  __shared__ float Xs[8][256];
  __shared__ float red[4][8][64];
  __shared__ float qd[8][68];
  __shared__ float sc[8][45];
  __shared__ int rows[8];
  const int t = threadIdx.x, p = t >> 6, d = t & 63;
  for (int e = t; e < U_ * 64; e += 256) {
    const int u = e >> 6, dd = e & 63;
    Ks[u][dd] = Ksamp[((size_t)bh * U_ + u) * 64 + dd];
  }
  const int n = cnt[bh];
  const int stride = 8 * gridDim.y;
  for (int c0 = g * 8; c0 < n; c0 += stride) {
    const int nc = min(8, n - c0);
    __syncthreads();
    if (t < 8) rows[t] = list[(size_t)bh * CAP_ + c0 + min(t, nc - 1)];
    float acc[8];
#pragma unroll
    for (int r = 0; r < 8; r++) acc[r] = 0.f;
    for (int kc = 0; kc < 4; kc++) {
      __syncthreads();
#pragma unroll
      for (int i = 0; i < 8; i++)
        Xs[i][t] = X[((size_t)b * L_ + rows[i]) * DM_ + kc * 256 + t];
      __syncthreads();
#pragma unroll
      for (int k4 = 0; k4 < 16; k4++) {
        const int kb = kc * 256 + p * 64 + k4 * 4;
        const float w0 = Wq[(size_t)(kb + 0) * DM_ + h * 64 + d];
        const float w1 = Wq[(size_t)(kb + 1) * DM_ + h * 64 + d];
        const float w2 = Wq[(size_t)(kb + 2) * DM_ + h * 64 + d];
        const float w3 = Wq[(size_t)(kb + 3) * DM_ + h * 64 + d];
#pragma unroll
        for (int r = 0; r < 8; r++) {
          const float4 x = *(const float4*)&Xs[r][p * 64 + k4 * 4];
          acc[r] += x.x * w0 + x.y * w1 + x.z * w2 + x.w * w3;
        }
      }
    }
#pragma unroll
    for (int r = 0; r < 8; r++) red[p][r][d] = acc[r];
    __syncthreads();
    if (p == 0) {
#pragma unroll
      for (int r = 0; r < 8; r++)
        qd[r][d] = red[0][r][d] + red[1][r][d] + red[2][r][d] + red[3][r][d] + bq[h * 64 + d];
    }
    __syncthreads();
    for (int idx = t; idx < 8 * U_; idx += 256) {
      const int c = idx / U_, u = idx - c * U_;
      float s = 0.f;
#pragma unroll 8
      for (int dd = 0; dd < 64; dd++) s += qd[c][dd] * Ks[u][dd];
      sc[c][u] = s;
    }
    __syncthreads();
    if (t < nc) {
      float mx = sc[t][0], sm = sc[t][0];
      for (int u = 1; u < U_; u++) { mx = fmaxf(mx, sc[t][u]); sm += sc[t][u]; }
      candM[(size_t)bh * CAP_ + c0 + t] = mx - sm * (1.f / (float)U_);
    }
  }
}

// ---------- select_b: final top-45 over candidates (exact M, idx tie-break) ----------
__global__ __launch_bounds__(256) void select_b(const float* __restrict__ candM,
    const int* __restrict__ list, const int* __restrict__ cnt, int* __restrict__ topidx) {
  const int bh = blockIdx.x, t = threadIdx.x;
  __shared__ float mv[CAP_];
  __shared__ int   ml[CAP_];
  __shared__ float rv[256];
  __shared__ int   ri[256];
  const int n = cnt[bh];
  for (int i = t; i < CAP_; i += 256) {
    mv[i] = (i < n) ? candM[(size_t)bh * CAP_ + i] : -3.4e38f;
    ml[i] = (i < n) ? list[(size_t)bh * CAP_ + i] : 0x7fffffff;
  }
  __syncthreads();
  for (int it = 0; it < U_; it++) {
    float bv = mv[t]; int bi = ml[t]; int bj = t;
    {
      const float v = mv[t + 256]; const int l2 = ml[t + 256];
      if (v > bv || (v == bv && l2 < bi)) { bv = v; bi = l2; bj = t + 256; }
    }
    rv[t] = bv; ri[t] = bj;
    __syncthreads();
    for (int s = 128; s > 0; s >>= 1) {
      if (t < s) {
        const float v2 = rv[t + s];
        const int slot2 = ri[t + s];
        if (v2 > rv[t] || (v2 == rv[t] && ml[slot2] < ml[ri[t]])) {
          rv[t] = v2; ri[t] = slot2;
        }
      }
      __syncthreads();
    }
    if (t == 0) {
      topidx[bh * U_ + it] = ml[ri[0]];
      mv[ri[0]] = -3.4e38f;
    }
    __syncthreads();
  }
}

// ---------- qsel3: exact selected Q rows, split-K partials ----------
__global__ __launch_bounds__(256) void qsel3(const float* __restrict__ X,
    const float* __restrict__ Wq, const int* __restrict__ topidx,
    float* __restrict__ qpart) {
  const int bh = blockIdx.x;
  const int ug = blockIdx.y >> 2, kc = blockIdx.y & 3;
  const int b = bh >> 4, h = bh & 15;
  __shared__ float Xs[15][256];
  __shared__ int rows[15];
  const int t = threadIdx.x, p = t >> 6, d = t & 63;
  if (t < 15) rows[t] = topidx[bh * U_ + ug * 15 + t];
  __syncthreads();
#pragma unroll
  for (int i = 0; i < 15; i++)
    Xs[i][t] = X[((size_t)b * L_ + rows[i]) * DM_ + kc * 256 + t];
  __syncthreads();
  float acc[15];
#pragma unroll
  for (int r = 0; r < 15; r++) acc[r] = 0.f;
#pragma unroll
  for (int k4 = 0; k4 < 16; k4++) {
    const int kb = kc * 256 + p * 64 + k4 * 4;
    const float w0 = Wq[(size_t)(kb + 0) * DM_ + h * 64 + d];
    const float w1 = Wq[(size_t)(kb + 1) * DM_ + h * 64 + d];
    const float w2 = Wq[(size_t)(kb + 2) * DM_ + h * 64 + d];
    const float w3 = Wq[(size_t)(kb + 3) * DM_ + h * 64 + d];
#pragma unroll
    for (int r = 0; r < 15; r++) {
      const float4 x = *(const float4*)&Xs[r][p * 64 + k4 * 4];
      acc[r] += x.x * w0 + x.y * w1 + x.z * w2 + x.w * w3;
    }
  }
  const int p16 = kc * 4 + p;       // partial slot 0..15
  float* dst = qpart + (((size_t)p16 * BH_ + bh) * 48 + ug * 15) * 64 + d;
#pragma unroll
  for (int r = 0; r < 15; r++) dst[(size_t)r * 64] = acc[r];
}

// combine 16 partials (fixed order) + bias -> bf16 Qbf; zero pad rows
__global__ __launch_bounds__(256) void qsel_comb(const float* __restrict__ qpart,
    const float* __restrict__ bq, unsigned short* __restrict__ Qbf) {
  const int idx = blockIdx.x * 256 + threadIdx.x;   // < BH_*48*64
  const int d = idx & 63, u48 = (idx >> 6) % 48, bh = idx / (48 * 64);
  const int h = bh & 15;
  if (u48 < U_) {
    const size_t o = (((size_t)bh) * 48 + u48) * 64 + d;
    const size_t stride = (size_t)BH_ * 48 * 64;
    float s = bq[h * 64 + d];
#pragma unroll
    for (int p16 = 0; p16 < 16; p16++) s += qpart[o + (size_t)p16 * stride];
    Qbf[o] = f2bf(s);
  } else {
    Qbf[(((size_t)bh) * 48 + u48) * 64 + d] = 0;
  }
}

// ---------- V mean from V^T rows (contiguous, deterministic) ----------
__global__ __launch_bounds__(256) void vmean_vt(const unsigned short* __restrict__ VT,
                                                float* __restrict__ Vm) {
  const int row = blockIdx.x * 4 + (threadIdx.x >> 6);   // 8192 rows total
  const int lane = threadIdx.x & 63;
  const unsigned short* src = VT + (size_t)row * L_ + lane * 64;
  float s = 0.f;
#pragma unroll
  for (int c = 0; c < 8; c++) {
    const ushort8 v = *(const ushort8*)&src[c * 8];
#pragma unroll
    for (int x = 0; x < 8; x++) s += bf2f(v[x]);
  }
  for (int off = 32; off > 0; off >>= 1) s += __shfl_xor(s, off);
  if (lane == 0) Vm[row] = s * (1.f / (float)L_);
}

// ---------- stage1: MFMA QK^T + MFMA PV over bf16 P; no-max softmax ----------
__global__ __launch_bounds__(256) void attn_stage1(const unsigned short* __restrict__ Qbf,
    const unsigned short* __restrict__ Kbf, const unsigned short* __restrict__ VT,
    float* __restrict__ part) {
  const int bh = blockIdx.x, split = blockIdx.y;
  const int b = bh >> 4, h = bh & 15;
  __shared__ unsigned short sQ[48][72];
  __shared__ unsigned short sK[64][72];
  __shared__ unsigned short sVT[64][72];   // [d][key]
  __shared__ unsigned short esb[48][68];   // P bf16 [q][key]
  __shared__ float sS[4][48];
  __shared__ float S_total[48];
  const int tid = threadIdx.x, wid = tid >> 6, lane = tid & 63;
  const int fr = lane & 15, fq = lane >> 4;
  for (int e = tid; e < 48 * 8; e += 256) {
    const int r = e >> 3, c8 = (e & 7) * 8;
    *(ushort8*)&sQ[r][c8] = *(const ushort8*)&Qbf[((size_t)bh * 48 + r) * 64 + c8];
  }
  if (tid < 48) S_total[tid] = 0.f;
  __syncthreads();
  short8 qf[3][2];
#pragma unroll
  for (int nt = 0; nt < 3; nt++)
#pragma unroll
    for (int kh = 0; kh < 2; kh++)
      qf[nt][kh] = *(const short8*)&sQ[nt * 16 + fr][kh * 32 + fq * 8];

  f32x4 acc[3];
#pragma unroll
  for (int mt = 0; mt < 3; mt++) acc[mt] = f32x4{0.f, 0.f, 0.f, 0.f};

  for (int t = 0; t < 8; t++) {
    const int k0 = split * 512 + t * 64;
    if (t) __syncthreads();               // barrier A: prev PV + S_total add done
    for (int e = tid; e < 64 * 8; e += 256) {
      const int r = e >> 3, c8 = (e & 7) * 8;
      *(ushort8*)&sK[r][c8] =
          *(const ushort8*)&Kbf[((size_t)b * L_ + k0 + r) * DM_ + h * 64 + c8];
      *(ushort8*)&sVT[r][c8] =
          *(const ushort8*)&VT[((size_t)(b * 1024 + h * 64 + r)) * L_ + k0 + c8];
    }
    __syncthreads();                      // barrier B
    const short8 kf0 = *(const short8*)&sK[wid * 16 + fr][fq * 8];
    const short8 kf1 = *(const short8*)&sK[wid * 16 + fr][32 + fq * 8];
    f32x4 accq[3];
#pragma unroll
    for (int nt = 0; nt < 3; nt++) {
      accq[nt] = f32x4{0.f, 0.f, 0.f, 0.f};
      accq[nt] = __builtin_amdgcn_mfma_f32_16x16x32_bf16(kf0, qf[nt][0], accq[nt], 0, 0, 0);
      accq[nt] = __builtin_amdgcn_mfma_f32_16x16x32_bf16(kf1, qf[nt][1], accq[nt], 0, 0, 0);
    }
#pragma unroll
    for (int nt = 0; nt < 3; nt++) {
      float sp = 0.f;
#pragma unroll
      for (int r = 0; r < 4; r++) {
        const float e = expf(accq[nt][r] * 0.125f);   // |score| bounded: no max
        sp += e;
        esb[nt * 16 + fr][wid * 16 + fq * 4 + r] = f2bf(e);
      }
      sp += __shfl_xor(sp, 16);
      sp += __shfl_xor(sp, 32);
      if (fq == 0) sS[wid][nt * 16 + fr] = sp;
    }
    __syncthreads();                      // barrier C
    if (tid < 48) S_total[tid] += sS[0][tid] + sS[1][tid] + sS[2][tid] + sS[3][tid];
    const short8 vb0 = *(const short8*)&sVT[wid * 16 + fr][fq * 8];
    const short8 vb1 = *(const short8*)&sVT[wid * 16 + fr][32 + fq * 8];
#pragma unroll
    for (int mt = 0; mt < 3; mt++) {
      const short8 pa0 = *(const short8*)&esb[mt * 16 + fr][fq * 8];
      const short8 pa1 = *(const short8*)&esb[mt * 16 + fr][32 + fq * 8];
      acc[mt] = __builtin_amdgcn_mfma_f32_16x16x32_bf16(pa0, vb0, acc[mt], 0, 0, 0);
      acc[mt] = __builtin_amdgcn_mfma_f32_16x16x32_bf16(pa1, vb1, acc[mt], 0, 0, 0);
    }
  }
  __syncthreads();
#pragma unroll
  for (int u = 0; u < U_; u++) {
    const int mt = u >> 4, fqq = (u >> 2) & 3, r = u & 3;
    float* pb = part + ((size_t)(bh * NSPLIT + split) * U_ + u) * 65;
    if (fq == fqq) pb[1 + wid * 16 + fr] = acc[mt][r];
    if (tid == fqq * 16) pb[0] = S_total[u];
  }
}

// ---------- combine splits; dctx = ctx/S - Vmean ----------
__global__ __launch_bounds__(256) void attn_stage2(const float* __restrict__ part,
    const float* __restrict__ Vm, float* __restrict__ dctx) {
  const int bh = blockIdx.x;
  const int wid = threadIdx.x >> 6, lane = threadIdx.x & 63;
  for (int u = wid; u < U_; u += 4) {
    float S = 0.f, c = 0.f;
#pragma unroll
    for (int sp = 0; sp < NSPLIT; sp++) {
      const float* pb = part + ((size_t)(bh * NSPLIT + sp) * U_ + u) * 65;
      S += pb[0];
      c += pb[1 + lane];
    }
    dctx[((size_t)bh * U_ + u) * 64 + lane] = c / S - Vm[bh * 64 + lane];
  }
}

// ---------- base[b][:] = concat_h(Vmean) @ Wo + bo ----------
__global__ __launch_bounds__(256) void base_k(const float* __restrict__ Vm,
    const float* __restrict__ Wo, const float* __restrict__ bo, float* __restrict__ base) {
  const int b = blockIdx.y;
  const int j = blockIdx.x * 256 + threadIdx.x;
  float acc = bo[j];
#pragma unroll 8
  for (int i = 0; i < DM_; i++) acc += Vm[b * DM_ + i] * Wo[(size_t)i * DM_ + j];
  base[b * DM_ + j] = acc;
}

// ---------- gemm_upd: rowupd[bh][u][:] = dctx[bh] @ Wo_h ----------
__global__ __launch_bounds__(256) void gemm_upd(const float* __restrict__ dctx,
    const float* __restrict__ Wo, float* __restrict__ rowupd) {
  const int bh = blockIdx.y, h = bh & 15;
  const int col = blockIdx.x * 256 + threadIdx.x;
  __shared__ float dc[U_][68];
  for (int e = threadIdx.x; e < U_ * 64; e += 256) {
    const int u = e >> 6, d = e & 63;
    dc[u][d] = dctx[(size_t)bh * U_ * 64 + e];
  }
  __syncthreads();
  float acc[U_];
#pragma unroll
  for (int u = 0; u < U_; u++) acc[u] = 0.f;
  for (int d = 0; d < 64; d++) {
    const float w = Wo[(size_t)(h * 64 + d) * DM_ + col];
#pragma unroll
    for (int u = 0; u < U_; u++) acc[u] += dc[u][d] * w;   // dc broadcast read
  }
#pragma unroll
  for (int u = 0; u < U_; u++)
    rowupd[((size_t)bh * U_ + u) * DM_ + col] = acc[u];
}

// ---------- build_list: per selected row, head-mask + slot ----------
__global__ __launch_bounds__(256) void build_list(const int* __restrict__ topidx,
    int* __restrict__ rowmask, unsigned char* __restrict__ slotU) {
  const int i = blockIdx.x * 256 + threadIdx.x;
  if (i >= BH_ * U_) return;
  const int bh = i / U_, u = i - bh * U_;
  const int b = bh >> 4, h = bh & 15;
  const int key = b * L_ + topidx[i];
  slotU[key * 16 + h] = (unsigned char)u;
  atomicOr(&rowmask[key], 1 << h);
}

// ---------- fill2: out[row] = base[b] (+ fixed-h-order sum of head updates) ----------
__global__ __launch_bounds__(256) void fill2(const float* __restrict__ rowupd,
    const float* __restrict__ base, const int* __restrict__ rowmask,
    const unsigned char* __restrict__ slotU, float* __restrict__ out) {
  const int key = blockIdx.x;                    // 0..ML_-1
  const int b = key >> 12;                       // L_ = 4096
  const int mask = rowmask[key];
  const int j4 = threadIdx.x * 4;
  float4 a = *(const float4*)&base[b * DM_ + j4];
  if (mask) {
#pragma unroll
    for (int h = 0; h < 16; h++) {
      if (mask & (1 << h)) {
        const int u = slotU[key * 16 + h];
        const float4 r = *(const float4*)&rowupd[((size_t)(b * 16 + h) * U_ + u) * DM_ + j4];
        a.x += r.x; a.y += r.y; a.z += r.z; a.w += r.w;
      }
    }
  }
  *(float4*)&out[(size_t)key * DM_ + j4] = a;
}

extern "C" void kernel_launch(void* const* d_in, const int* in_sizes, int n_in,
                              void* d_out, int out_size, void* d_ws, size_t ws_size,
                              hipStream_t stream) {
  const float* queries = (const float*)d_in[0];
  const float* keys    = (const float*)d_in[1];
  const float* values  = (const float*)d_in[2];
  const float* Wq = (const float*)d_in[3]; const float* bq = (const float*)d_in[4];
  const float* Wk = (const float*)d_in[5]; const float* bk = (const float*)d_in[6];
  const float* Wv = (const float*)d_in[7]; const float* bv = (const float*)d_in[8];
  const float* Wo = (const float*)d_in[9]; const float* bo = (const float*)d_in[10];
  const int* sidx = (const int*)d_in[11];

  // K (row-major) and V^T live as bf16 in d_out until the epilogue
  unsigned short* Kbf = (unsigned short*)d_out;
  unsigned short* VT  = Kbf + (size_t)ML_ * DM_;

  uint8_t* p = (uint8_t*)d_ws;
  auto carve = [&](size_t bytes) { uint8_t* r = p; p += (bytes + 255) & ~(size_t)255; return r; };
  float* QKs = (float*)carve((size_t)CROWS_ * NP_ * 4);                     // 50.3 MB
  unsigned short* Ph = (unsigned short*)carve((size_t)B_ * NP_ * DM_ * 2);  // 12.6 MB
  unsigned short* WkT = (unsigned short*)carve((size_t)DM_ * DM_ * 2);
  unsigned short* WvT = (unsigned short*)carve((size_t)DM_ * DM_ * 2);
  float* Mbuf  = (float*)carve((size_t)BH_ * L_ * 4);                       // 2.1 MB
  float* Ksamp = (float*)carve((size_t)BH_ * U_ * 64 * 4);                  // 1.5 MB
  float* kpart = (float*)carve((size_t)4 * B_ * U_ * 1024 * 4);             // 5.9 MB
  float* qpart = (float*)carve((size_t)16 * BH_ * 48 * 64 * 4);             // 25.2 MB
  int*   list  = (int*)carve((size_t)BH_ * CAP_ * 4);                       // 256 KB
  float* candM = (float*)carve((size_t)BH_ * CAP_ * 4);                     // 256 KB
  int*   cntb  = (int*)carve((size_t)BH_ * 4);
  int*   topidx = (int*)carve((size_t)BH_ * U_ * 4);
  float* Vm    = (float*)carve((size_t)BH_ * 64 * 4);
  unsigned short* Qbf = (unsigned short*)carve((size_t)BH_ * 48 * 64 * 2);  // 786 KB
  int*   rowmask = (int*)carve((size_t)B_ * L_ * 4);                        // 128 KB (memset)
  unsigned char* slotU = (unsigned char*)carve((size_t)B_ * L_ * 16);       // 512 KB
  const size_t need = (size_t)(p - (uint8_t*)d_ws);
  if (ws_size < need)
    fprintf(stderr, "ATHENA_WS: need %zu have %zu (WILL FAULT)\n", need, ws_size);

  // late-phase buffers alias QKs (dead after mpass)
  uint8_t* ap = (uint8_t*)QKs;
  auto acarve = [&](size_t bytes) { uint8_t* r = ap; ap += (bytes + 255) & ~(size_t)255; return r; };
  float* part  = (float*)acarve((size_t)BH_ * NSPLIT * U_ * 65 * 4);        // 12 MB
  float* dctx  = (float*)acarve((size_t)BH_ * U_ * 64 * 4);
  float* base  = (float*)acarve((size_t)B_ * DM_ * 4);
  float* rowupd = (float*)acarve((size_t)BH_ * U_ * DM_ * 4);               // 23.6 MB

  ksel3<<<dim3(4, B_, 12), 256, 0, stream>>>(keys, Wk, sidx, kpart);
  ksel_comb<<<(B_ * U_ * 1024) / 256, 256, 0, stream>>>(kpart, bk, Ksamp);
  pform_k<<<BH_, 256, 0, stream>>>(Wq, Ksamp, Ph);
  wT_single<<<4096, 256, 0, stream>>>(Wk, WkT);
  wT_single<<<4096, 256, 0, stream>>>(Wv, WvT);

  for (int c = 0; c < 2; c++) {
    const size_t off = (size_t)c * CROWS_ * DM_;
    gemm_f<0><<<dim3(8, 128), 256, 0, stream>>>(keys + off, WkT, bk, Kbf + off, 0, 0);
    gemm_f<1><<<dim3(8, 128), 256, 0, stream>>>(values + off, WvT, bv, VT, c * CROWS_, 0);
    gemm_f<2><<<dim3(6, 128), 256, 0, stream>>>(queries + off, Ph, bq, QKs, 0, c);
    mpass_k<<<(CROWS_ * 16) / 256, 256, 0, stream>>>(QKs, Mbuf, c);
  }

  select_a<<<BH_, 256, 0, stream>>>(Mbuf, list, cntb);
  exactM2<<<dim3(BH_, 16), 256, 0, stream>>>(queries, Wq, bq, Ksamp, list, cntb, candM);
  select_b<<<BH_, 256, 0, stream>>>(candM, list, cntb, topidx);
  qsel3<<<dim3(BH_, 12), 256, 0, stream>>>(queries, Wq, topidx, qpart);
  qsel_comb<<<(BH_ * 48 * 64) / 256, 256, 0, stream>>>(qpart, bq, Qbf);
  vmean_vt<<<(BH_ * 64) / 4, 256, 0, stream>>>(VT, Vm);
  attn_stage1<<<dim3(BH_, NSPLIT), 256, 0, stream>>>(Qbf, Kbf, VT, part);
  attn_stage2<<<BH_, 256, 0, stream>>>(part, Vm, dctx);
  base_k<<<dim3(DM_ / 256, B_), 256, 0, stream>>>(Vm, Wo, bo, base);

  // epilogue: deterministic
  hipMemsetAsync(rowmask, 0, (size_t)B_ * L_ * 4, stream);
  gemm_upd<<<dim3(4, BH_), 256, 0, stream>>>(dctx, Wo, rowupd);
  build_list<<<(BH_ * U_ + 255) / 256, 256, 0, stream>>>(topidx, rowmask, slotU);
  fill2<<<ML_, 256, 0, stream>>>(rowupd, base, rowmask, slotU, (float*)d_out);
}

// Round 15
// 987.190 us; speedup vs baseline: 1.1334x; 1.0777x over previous
//
#include <hip/hip_runtime.h>
#include <cstdint>
#include <cstdio>

#define B_   8
#define L_   4096
#define DM_  1024
#define H_   16
#define D_   64
#define U_   45
#define BH_  (B_*H_)
#define ML_  (B_*L_)
#define NSPLIT 8
#define NP_  768           // padded QK-sample width: 16 heads * 48
#define CAP_ 512           // candidate cap per (b,h)
#define DELTA_ 0.12f       // exact-recompute band (~9 sigma of bf16 GEMM err)
#define ASTR 40            // padded sA row stride (shorts); 80 B rows -> 8-bank spread

using f32x4   = __attribute__((ext_vector_type(4))) float;
using short8  = __attribute__((ext_vector_type(8))) short;
using ushort8 = __attribute__((ext_vector_type(8))) unsigned short;

__device__ __forceinline__ unsigned short f2bf(float f) {
  uint32_t u = __float_as_uint(f);
  u += 0x7fffu + ((u >> 16) & 1u);      // RNE; inputs finite
  return (unsigned short)(u >> 16);
}
__device__ __forceinline__ float bf2f(unsigned short h) {
  return __uint_as_float(((uint32_t)h) << 16);
}

__device__ __forceinline__ void gload16(const void* g, void* l) {
  __builtin_amdgcn_global_load_lds((const __attribute__((address_space(1))) void*)g,
                                   (__attribute__((address_space(3))) void*)l,
                                   16, 0, 0);
}

// ---------- W (KxN) -> W^T bf16 (NxK) ----------
__global__ __launch_bounds__(256) void wT_single(const float* __restrict__ W,
                                                 unsigned short* __restrict__ WT) {
  const int idx = blockIdx.x * 256 + threadIdx.x;   // 1M threads
  const int n = idx >> 10, kk = idx & 1023;
  WT[idx] = f2bf(W[kk * 1024 + n]);
}

// ---------- fused-convert bf16 GEMM, full-tensor grids, BK=64 pipelined A ----------
// smem layout: sB[2][4096] linear (gload_lds), sA[2][128*ASTR] padded; MODE1's sC
// aliases smem after the K-loop. All modes: 36.9 KB LDS -> 4 blocks/CU.
// MODE 0: bf16 row-major C (stride 1024) + bias          (K projection, 2048 blocks)
// MODE 1: bf16 transposed VT[(b*1024+col)][l] + bias     (V projection, 2048 blocks)
// MODE 2: fp32 C (stride NP_), per-batch B = Ph          (QK-sample,   1536 blocks)
template <int MODE>
__global__ __launch_bounds__(256) void gemm_f(const float* __restrict__ Af,
    const unsigned short* __restrict__ Bg, const float* __restrict__ bias,
    void* __restrict__ Cout) {
  constexpr int K = 1024;
  constexpr int NX = (MODE == 2) ? 6 : 8;
  constexpr int NWG = NX * 256;
  __shared__ unsigned short smem[2 * 4096 + 2 * 128 * ASTR];   // 36864 B
  unsigned short* sB0 = smem;                                   // [2][4096]
  unsigned short* sA0 = smem + 2 * 4096;                        // [2][128*ASTR]
  const int tid = threadIdx.x, wid = tid >> 6, lane = tid & 63;
  const int orig = blockIdx.y * NX + blockIdx.x;
  const int g = (orig & 7) * (NWG / 8) + (orig >> 3);   // bijective (NWG % 8 == 0)
  const int by = g / NX, bx = g % NX;
  const int m0 = by * 128, n0 = bx * 128;
  const unsigned short* __restrict__ Bgh =
      (MODE == 2) ? Bg + (size_t)(by >> 5) * NP_ * K : Bg;
  const int wr = wid >> 1, wc = wid & 1;
  const int fr = lane & 15, fq = lane >> 4;
  const int srow = lane >> 2, scol = (lane & 3) * 8;
  const int arow = tid >> 3, acol = (tid & 7) * 4;
  f32x4 acc[4][4];
#pragma unroll
  for (int i = 0; i < 4; i++)
#pragma unroll
    for (int j = 0; j < 4; j++) acc[i][j] = f32x4{0.f, 0.f, 0.f, 0.f};

  float4 xr[2][4];
#pragma unroll
  for (int s = 0; s < 2; s++)
#pragma unroll
    for (int pq = 0; pq < 4; pq++)
      xr[s][pq] = *(const float4*)&Af[(size_t)(m0 + pq * 32 + arow) * K + s * 32 + acol];

  for (int k0 = 0; k0 < K; k0 += 64) {
    // B: async global->LDS for both halves
#pragma unroll
    for (int s = 0; s < 2; s++)
#pragma unroll
      for (int c = 0; c < 2; c++) {
        const int ch = wid * 2 + c;
        const int row = ch * 16 + srow;
        gload16(Bgh + (size_t)(n0 + row) * K + (k0 + s * 32 + scol),
                sB0 + s * 4096 + ch * 512);
      }
    // A: write previously-staged regs (no wait), convert in-flight
#pragma unroll
    for (int s = 0; s < 2; s++)
#pragma unroll
      for (int pq = 0; pq < 4; pq++) {
        const int row = pq * 32 + arow;
        ushort4 hv;
        hv.x = f2bf(xr[s][pq].x); hv.y = f2bf(xr[s][pq].y);
        hv.z = f2bf(xr[s][pq].z); hv.w = f2bf(xr[s][pq].w);
        *(ushort4*)&sA0[s * 128 * ASTR + row * ASTR + acol] = hv;
      }
    if (k0 + 64 < K) {
#pragma unroll
      for (int s = 0; s < 2; s++)
#pragma unroll
        for (int pq = 0; pq < 4; pq++)
          xr[s][pq] = *(const float4*)&Af[(size_t)(m0 + pq * 32 + arow) * K +
                                          (k0 + 64 + s * 32) + acol];
    }
    __syncthreads();
#pragma unroll
    for (int s = 0; s < 2; s++) {
      short8 ah[4], bh[4];
#pragma unroll
      for (int i = 0; i < 4; i++) {
        ah[i] = *(const short8*)&sA0[s * 128 * ASTR + (wr * 64 + i * 16 + fr) * ASTR + fq * 8];
        bh[i] = *(const short8*)&sB0[s * 4096 + (wc * 64 + i * 16 + fr) * 32 + fq * 8];
      }
#pragma unroll
      for (int i = 0; i < 4; i++)
#pragma unroll
        for (int j = 0; j < 4; j++)
          acc[i][j] = __builtin_amdgcn_mfma_f32_16x16x32_bf16(ah[i], bh[j], acc[i][j], 0, 0, 0);
    }
    __syncthreads();
  }

  if (MODE == 0) {
    unsigned short* C = (unsigned short*)Cout;
#pragma unroll
    for (int j = 0; j < 4; j++) {
      const int col = n0 + wc * 64 + j * 16 + fr;
      const float bv = bias[col];
#pragma unroll
      for (int i = 0; i < 4; i++) {
        const int row = m0 + wr * 64 + i * 16 + fq * 4;
#pragma unroll
        for (int r = 0; r < 4; r++)
          C[(size_t)(row + r) * 1024 + col] = f2bf(acc[i][j][r] + bv);
      }
    }
  } else if (MODE == 2) {
    float* C = (float*)Cout;
#pragma unroll
    for (int j = 0; j < 4; j++) {
      const int col = n0 + wc * 64 + j * 16 + fr;
#pragma unroll
      for (int i = 0; i < 4; i++) {
        const int row = m0 + wr * 64 + i * 16 + fq * 4;
#pragma unroll
        for (int r = 0; r < 4; r++) C[(size_t)(row + r) * NP_ + col] = acc[i][j][r];
      }
    }
  } else {
    // MODE 1: transpose via aliased-LDS in two 64-l half-passes, coalesced writes
    unsigned short (*sC)[68] = (unsigned short(*)[68])smem;   // 17408 B <= 36864
    unsigned short* VT = (unsigned short*)Cout;
    const int b = m0 >> 12, l0 = m0 & 4095;                    // L_ = 4096
    __syncthreads();                       // all MFMA reads of smem done
#pragma unroll
    for (int pass = 0; pass < 2; pass++) {
      if (pass) __syncthreads();
      if (wr == pass) {
#pragma unroll
        for (int j = 0; j < 4; j++) {
          const int col = wc * 64 + j * 16 + fr;       // d within tile
          const float bv = bias[n0 + col];
#pragma unroll
          for (int i = 0; i < 4; i++) {
            const int lrow = i * 16 + fq * 4;          // l within half
#pragma unroll
            for (int r = 0; r < 4; r++) sC[col][lrow + r] = f2bf(acc[i][j][r] + bv);
          }
        }
      }
      __syncthreads();
#pragma unroll
      for (int it = 0; it < 8; it++) {
        const int row = it * 16 + (tid >> 4);
        const int seg = (tid & 15) * 4;
        const ushort4 v = *(const ushort4*)&sC[row][seg];
        *(ushort4*)&VT[((size_t)(b * 1024 + n0 + row)) * L_ + l0 + pass * 64 + seg] = v;
      }
    }
  }
}

// ---------- ksel3: exact fp32 sampled-K rows, split-K column-parallel ----------
__global__ __launch_bounds__(256) void ksel3(const float* __restrict__ X,
    const float* __restrict__ Wk, const int* __restrict__ sidx,
    float* __restrict__ kpart) {
  const int t = threadIdx.x;
  const int col = blockIdx.x * 256 + t;
  const int b = blockIdx.y;
  const int ug = blockIdx.z >> 2, kc = blockIdx.z & 3;
  __shared__ float Xs[15][256];
  __shared__ int rows[15];
  if (t < 15) rows[t] = sidx[ug * 15 + t];
  __syncthreads();
#pragma unroll
  for (int i = 0; i < 15; i++)
    Xs[i][t] = X[((size_t)b * L_ + rows[i]) * DM_ + kc * 256 + t];
  __syncthreads();
  float acc[15];
#pragma unroll
  for (int r = 0; r < 15; r++) acc[r] = 0.f;
  for (int k4 = 0; k4 < 64; k4++) {
    const int kb = kc * 256 + k4 * 4;
    const float w0 = Wk[(size_t)(kb + 0) * DM_ + col];
    const float w1 = Wk[(size_t)(kb + 1) * DM_ + col];
    const float w2 = Wk[(size_t)(kb + 2) * DM_ + col];
    const float w3 = Wk[(size_t)(kb + 3) * DM_ + col];
#pragma unroll
    for (int r = 0; r < 15; r++) {
      const float4 x = *(const float4*)&Xs[r][k4 * 4];
      acc[r] += x.x * w0 + x.y * w1 + x.z * w2 + x.w * w3;
    }
  }
  float* dst = kpart + (((size_t)kc * B_ + b) * U_ + ug * 15) * 1024 + col;
#pragma unroll
  for (int r = 0; r < 15; r++) dst[(size_t)r * 1024] = acc[r];
}

// combine: Ksamp = sum_kc kpart + bias (fixed order)
__global__ __launch_bounds__(256) void ksel_comb(const float* __restrict__ kpart,
    const float* __restrict__ bk, float* __restrict__ Ksamp) {
  const int idx = blockIdx.x * 256 + threadIdx.x;   // < 360*1024
  const int col = idx & 1023, ru = idx >> 10;
  const int b = ru / U_, u = ru - b * U_;
  const size_t o = ((size_t)b * U_ + u) * 1024 + col;
  const size_t stride = (size_t)B_ * U_ * 1024;
  float s = kpart[o] + kpart[o + stride] + kpart[o + 2 * stride] + kpart[o + 3 * stride]
          + bk[col];
  const int h = col >> 6, d = col & 63;
  Ksamp[((size_t)(b * 16 + h) * U_ + u) * 64 + d] = s;
}

// ---------- P^T[b][h*48+u][k] = sum_d Wq[k][h*64+d]*Ksamp (bf16 hi) ----------
__global__ __launch_bounds__(256) void pform_k(const float* __restrict__ Wq,
    const float* __restrict__ Ksamp, unsigned short* __restrict__ Ph) {
  const int bh = blockIdx.x, b = bh >> 4, h = bh & 15;
  __shared__ float Ks[U_][68];
  const int t = threadIdx.x;
  for (int e = t; e < U_ * 64; e += 256) {
    const int u = e >> 6, d = e & 63;
    Ks[u][d] = Ksamp[((size_t)bh * U_ + u) * 64 + d];
  }
  __syncthreads();
  for (int kc = 0; kc < 4; kc++) {
    const int k = kc * 256 + t;
    float wr[64];
#pragma unroll
    for (int dd = 0; dd < 16; dd++) {
      const float4 w4 = *(const float4*)&Wq[(size_t)k * DM_ + h * 64 + dd * 4];
      wr[dd * 4 + 0] = w4.x; wr[dd * 4 + 1] = w4.y;
      wr[dd * 4 + 2] = w4.z; wr[dd * 4 + 3] = w4.w;
    }
    for (int u = 0; u < 48; u++) {
      size_t o = ((size_t)b * NP_ + h * 48 + u) * 1024 + k;
      if (u < U_) {
        float acc = 0.f;
#pragma unroll
        for (int d = 0; d < 64; d++) acc += wr[d] * Ks[u][d];
        Ph[o] = f2bf(acc);
      } else {
        Ph[o] = 0;
      }
    }
  }
}

// ---------- M_approx = max - mean over u (full tensor, one dispatch) ----------
__global__ __launch_bounds__(256) void mpass_k(const float* __restrict__ QKs,
                                               float* __restrict__ Mbuf) {
  const int idx = blockIdx.x * 256 + threadIdx.x;   // < ML_*16
  const int ll = idx >> 4, h = idx & 15;
  const float* row = QKs + (size_t)ll * NP_ + h * 48;
  float mx = row[0], sm = row[0];
#pragma unroll
  for (int u = 1; u < U_; u++) { const float v = row[u]; mx = fmaxf(mx, v); sm += v; }
  const int b = ll >> 12, l = ll & 4095;
  Mbuf[((size_t)(b * 16 + h)) * L_ + l] = mx - sm * (1.f / (float)U_);
}

// ---------- select_a: approx top-45 -> thr; candidates = {M >= thr - DELTA} ----------
__global__ __launch_bounds__(256) void select_a(const float* __restrict__ Mbuf,
    int* __restrict__ list, int* __restrict__ cnt) {
  const int bh = blockIdx.x, t = threadIdx.x;
  __shared__ float vals[L_];
  __shared__ float rv[256];
  __shared__ int   ri[256];
  __shared__ int   scnt;
  __shared__ float sthr;
  if (t == 0) scnt = 0;
  for (int i = t; i < L_; i += 256) vals[i] = Mbuf[(size_t)bh * L_ + i];
  __syncthreads();
  for (int it = 0; it < U_; it++) {
    float bv = vals[t * 16]; int bi = t * 16;
#pragma unroll
    for (int jj = 1; jj < 16; jj++) {
      const float v = vals[t * 16 + jj];
      if (v > bv) { bv = v; bi = t * 16 + jj; }
    }
    rv[t] = bv; ri[t] = bi;
    __syncthreads();
    for (int s = 128; s > 0; s >>= 1) {
      if (t < s) {
        if (rv[t + s] > rv[t] || (rv[t + s] == rv[t] && ri[t + s] < ri[t])) {
          rv[t] = rv[t + s]; ri[t] = ri[t + s];
        }
      }
      __syncthreads();
    }
    if (t == 0) {
      list[(size_t)bh * CAP_ + it] = ri[0];
      vals[ri[0]] = -3.4e38f;
      if (it == U_ - 1) sthr = rv[0];
    }
    __syncthreads();
  }
  const float lim = sthr - DELTA_;
  for (int i = t; i < L_; i += 256) {
    if (vals[i] >= lim) {
      const int j = atomicAdd(&scnt, 1);
      if (U_ + j < CAP_) list[(size_t)bh * CAP_ + U_ + j] = i;
    }
  }
  __syncthreads();
  if (t == 0) cnt[bh] = min(U_ + scnt, CAP_);
}

// ---------- exactM2: fp32 recompute of M for candidates ----------
__global__ __launch_bounds__(256) void exactM2(const float* __restrict__ X,
    const float* __restrict__ Wq, const float* __restrict__ bq,
    const float* __restrict__ Ksamp, const int* __restrict__ list,
    const int* __restrict__ cnt, float* __restrict__ candM) {
  const int bh = blockIdx.x, g = blockIdx.y, b = bh >> 4, h = bh & 15;
  __shared__ float Ks[U_][68];
  __shared__ float Xs[8][256];
  __shared__ float red[4][8][64];
  __shared__ float qd[8][68];
  __shared__ float sc[8][45];
  __shared__ int rows[8];
  const int t = threadIdx.x, p = t >> 6, d = t & 63;
  for (int e = t; e < U_ * 64; e += 256) {
    const int u = e >> 6, dd = e & 63;
    Ks[u][dd] = Ksamp[((size_t)bh * U_ + u) * 64 + dd];
  }
  const int n = cnt[bh];
  const int stride = 8 * gridDim.y;
  for (int c0 = g * 8; c0 < n; c0 += stride) {
    const int nc = min(8, n - c0);
    __syncthreads();
    if (t < 8) rows[t] = list[(size_t)bh * CAP_ + c0 + min(t, nc - 1)];
    float acc[8];
#pragma unroll
    for (int r = 0; r < 8; r++) acc[r] = 0.f;
    for (int kc = 0; kc < 4; kc++) {
      __syncthreads();
#pragma unroll
      for (int i = 0; i < 8; i++)
        Xs[i][t] = X[((size_t)b * L_ + rows[i]) * DM_ + kc * 256 + t];
      __syncthreads();
#pragma unroll
      for (int k4 = 0; k4 < 16; k4++) {
        const int kb = kc * 256 + p * 64 + k4 * 4;
        const float w0 = Wq[(size_t)(kb + 0) * DM_ + h * 64 + d];
        const float w1 = Wq[(size_t)(kb + 1) * DM_ + h * 64 + d];
        const float w2 = Wq[(size_t)(kb + 2) * DM_ + h * 64 + d];
        const float w3 = Wq[(size_t)(kb + 3) * DM_ + h * 64 + d];
#pragma unroll
        for (int r = 0; r < 8; r++) {
          const float4 x = *(const float4*)&Xs[r][p * 64 + k4 * 4];
          acc[r] += x.x * w0 + x.y * w1 + x.z * w2 + x.w * w3;
        }
      }
    }
#pragma unroll
    for (int r = 0; r < 8; r++) red[p][r][d] = acc[r];
    __syncthreads();
    if (p == 0) {
#pragma unroll
      for (int r = 0; r < 8; r++)
        qd[r][d] = red[0][r][d] + red[1][r][d] + red[2][r][d] + red[3][r][d] + bq[h * 64 + d];
    }
    __syncthreads();
    for (int idx = t; idx < 8 * U_; idx += 256) {
      const int c = idx / U_, u = idx - c * U_;
      float s = 0.f;
#pragma unroll 8
      for (int dd = 0; dd < 64; dd++) s += qd[c][dd] * Ks[u][dd];
      sc[c][u] = s;
    }
    __syncthreads();
    if (t < nc) {
      float mx = sc[t][0], sm = sc[t][0];
      for (int u = 1; u < U_; u++) { mx = fmaxf(mx, sc[t][u]); sm += sc[t][u]; }
      candM[(size_t)bh * CAP_ + c0 + t] = mx - sm * (1.f / (float)U_);
    }
  }
}

// ---------- select_b: final top-45 over candidates (exact M, idx tie-break) ----------
__global__ __launch_bounds__(256) void select_b(const float* __restrict__ candM,
    const int* __restrict__ list, const int* __restrict__ cnt, int* __restrict__ topidx) {
  const int bh = blockIdx.x, t = threadIdx.x;
  __shared__ float mv[CAP_];
  __shared__ int   ml[CAP_];
  __shared__ float rv[256];
  __shared__ int   ri[256];
  const int n = cnt[bh];
  for (int i = t; i < CAP_; i += 256) {
    mv[i] = (i < n) ? candM[(size_t)bh * CAP_ + i] : -3.4e38f;
    ml[i] = (i < n) ? list[(size_t)bh * CAP_ + i] : 0x7fffffff;
  }
  __syncthreads();
  for (int it = 0; it < U_; it++) {
    float bv = mv[t]; int bi = ml[t]; int bj = t;
    {
      const float v = mv[t + 256]; const int l2 = ml[t + 256];
      if (v > bv || (v == bv && l2 < bi)) { bv = v; bi = l2; bj = t + 256; }
    }
    rv[t] = bv; ri[t] = bj;
    __syncthreads();
    for (int s = 128; s > 0; s >>= 1) {
      if (t < s) {
        const float v2 = rv[t + s];
        const int slot2 = ri[t + s];
        if (v2 > rv[t] || (v2 == rv[t] && ml[slot2] < ml[ri[t]])) {
          rv[t] = v2; ri[t] = slot2;
        }
      }
      __syncthreads();
    }
    if (t == 0) {
      topidx[bh * U_ + it] = ml[ri[0]];
      mv[ri[0]] = -3.4e38f;
    }
    __syncthreads();
  }
}

// ---------- qsel3: exact selected Q rows, split-K partials ----------
__global__ __launch_bounds__(256) void qsel3(const float* __restrict__ X,
    const float* __restrict__ Wq, const int* __restrict__ topidx,
    float* __restrict__ qpart) {
  const int bh = blockIdx.x;
  const int ug = blockIdx.y >> 2, kc = blockIdx.y & 3;
  const int b = bh >> 4, h = bh & 15;
  __shared__ float Xs[15][256];
  __shared__ int rows[15];
  const int t = threadIdx.x, p = t >> 6, d = t & 63;
  if (t < 15) rows[t] = topidx[bh * U_ + ug * 15 + t];
  __syncthreads();
#pragma unroll
  for (int i = 0; i < 15; i++)
    Xs[i][t] = X[((size_t)b * L_ + rows[i]) * DM_ + kc * 256 + t];
  __syncthreads();
  float acc[15];
#pragma unroll
  for (int r = 0; r < 15; r++) acc[r] = 0.f;
#pragma unroll
  for (int k4 = 0; k4 < 16; k4++) {
    const int kb = kc * 256 + p * 64 + k4 * 4;
    const float w0 = Wq[(size_t)(kb + 0) * DM_ + h * 64 + d];
    const float w1 = Wq[(size_t)(kb + 1) * DM_ + h * 64 + d];
    const float w2 = Wq[(size_t)(kb + 2) * DM_ + h * 64 + d];
    const float w3 = Wq[(size_t)(kb + 3) * DM_ + h * 64 + d];
#pragma unroll
    for (int r = 0; r < 15; r++) {
      const float4 x = *(const float4*)&Xs[r][p * 64 + k4 * 4];
      acc[r] += x.x * w0 + x.y * w1 + x.z * w2 + x.w * w3;
    }
  }
  const int p16 = kc * 4 + p;       // partial slot 0..15
  float* dst = qpart + (((size_t)p16 * BH_ + bh) * 48 + ug * 15) * 64 + d;
#pragma unroll
  for (int r = 0; r < 15; r++) dst[(size_t)r * 64] = acc[r];
}

// combine 16 partials (fixed order) + bias -> bf16 Qbf; zero pad rows
__global__ __launch_bounds__(256) void qsel_comb(const float* __restrict__ qpart,
    const float* __restrict__ bq, unsigned short* __restrict__ Qbf) {
  const int idx = blockIdx.x * 256 + threadIdx.x;   // < BH_*48*64
  const int d = idx & 63, u48 = (idx >> 6) % 48, bh = idx / (48 * 64);
  const int h = bh & 15;
  if (u48 < U_) {
    const size_t o = (((size_t)bh) * 48 + u48) * 64 + d;
    const size_t stride = (size_t)BH_ * 48 * 64;
    float s = bq[h * 64 + d];
#pragma unroll
    for (int p16 = 0; p16 < 16; p16++) s += qpart[o + (size_t)p16 * stride];
    Qbf[o] = f2bf(s);
  } else {
    Qbf[(((size_t)bh) * 48 + u48) * 64 + d] = 0;
  }
}

// ---------- V mean from V^T rows (contiguous, deterministic) ----------
__global__ __launch_bounds__(256) void vmean_vt(const unsigned short* __restrict__ VT,
                                                float* __restrict__ Vm) {
  const int row = blockIdx.x * 4 + (threadIdx.x >> 6);   // 8192 rows total
  const int lane = threadIdx.x & 63;
  const unsigned short* src = VT + (size_t)row * L_ + lane * 64;
  float s = 0.f;
#pragma unroll
  for (int c = 0; c < 8; c++) {
    const ushort8 v = *(const ushort8*)&src[c * 8];
#pragma unroll
    for (int x = 0; x < 8; x++) s += bf2f(v[x]);
  }
  for (int off = 32; off > 0; off >>= 1) s += __shfl_xor(s, off);
  if (lane == 0) Vm[row] = s * (1.f / (float)L_);
}

// ---------- stage1: MFMA QK^T + MFMA PV over bf16 P; no-max softmax ----------
__global__ __launch_bounds__(256) void attn_stage1(const unsigned short* __restrict__ Qbf,
    const unsigned short* __restrict__ Kbf, const unsigned short* __restrict__ VT,
    float* __restrict__ part) {
  const int bh = blockIdx.x, split = blockIdx.y;
  const int b = bh >> 4, h = bh & 15;
  __shared__ unsigned short sQ[48][72];
  __shared__ unsigned short sK[64][72];
  __shared__ unsigned short sVT[64][72];   // [d][key]
  __shared__ unsigned short esb[48][68];   // P bf16 [q][key]
  __shared__ float sS[4][48];
  __shared__ float S_total[48];
  const int tid = threadIdx.x, wid = tid >> 6, lane = tid & 63;
  const int fr = lane & 15, fq = lane >> 4;
  for (int e = tid; e < 48 * 8; e += 256) {
    const int r = e >> 3, c8 = (e & 7) * 8;
    *(ushort8*)&sQ[r][c8] = *(const ushort8*)&Qbf[((size_t)bh * 48 + r) * 64 + c8];
  }
  if (tid < 48) S_total[tid] = 0.f;
  __syncthreads();
  short8 qf[3][2];
#pragma unroll
  for (int nt = 0; nt < 3; nt++)
#pragma unroll
    for (int kh = 0; kh < 2; kh++)
      qf[nt][kh] = *(const short8*)&sQ[nt * 16 + fr][kh * 32 + fq * 8];

  f32x4 acc[3];
#pragma unroll
  for (int mt = 0; mt < 3; mt++) acc[mt] = f32x4{0.f, 0.f, 0.f, 0.f};

  for (int t = 0; t < 8; t++) {
    const int k0 = split * 512 + t * 64;
    if (t) __syncthreads();               // barrier A: prev PV + S_total add done
    for (int e = tid; e < 64 * 8; e += 256) {
      const int r = e >> 3, c8 = (e & 7) * 8;
      *(ushort8*)&sK[r][c8] =
          *(const ushort8*)&Kbf[((size_t)b * L_ + k0 + r) * DM_ + h * 64 + c8];
      *(ushort8*)&sVT[r][c8] =
          *(const ushort8*)&VT[((size_t)(b * 1024 + h * 64 + r)) * L_ + k0 + c8];
    }
    __syncthreads();                      // barrier B
    const short8 kf0 = *(const short8*)&sK[wid * 16 + fr][fq * 8];
    const short8 kf1 = *(const short8*)&sK[wid * 16 + fr][32 + fq * 8];
    f32x4 accq[3];
#pragma unroll
    for (int nt = 0; nt < 3; nt++) {
      accq[nt] = f32x4{0.f, 0.f, 0.f, 0.f};
      accq[nt] = __builtin_amdgcn_mfma_f32_16x16x32_bf16(kf0, qf[nt][0], accq[nt], 0, 0, 0);
      accq[nt] = __builtin_amdgcn_mfma_f32_16x16x32_bf16(kf1, qf[nt][1], accq[nt], 0, 0, 0);
    }
#pragma unroll
    for (int nt = 0; nt < 3; nt++) {
      float sp = 0.f;
#pragma unroll
      for (int r = 0; r < 4; r++) {
        const float e = expf(accq[nt][r] * 0.125f);   // |score| bounded: no max
        sp += e;
        esb[nt * 16 + fr][wid * 16 + fq * 4 + r] = f2bf(e);
      }
      sp += __shfl_xor(sp, 16);
      sp += __shfl_xor(sp, 32);
      if (fq == 0) sS[wid][nt * 16 + fr] = sp;
    }
    __syncthreads();                      // barrier C
    if (tid < 48) S_total[tid] += sS[0][tid] + sS[1][tid] + sS[2][tid] + sS[3][tid];
    const short8 vb0 = *(const short8*)&sVT[wid * 16 + fr][fq * 8];
    const short8 vb1 = *(const short8*)&sVT[wid * 16 + fr][32 + fq * 8];
#pragma unroll
    for (int mt = 0; mt < 3; mt++) {
      const short8 pa0 = *(const short8*)&esb[mt * 16 + fr][fq * 8];
      const short8 pa1 = *(const short8*)&esb[mt * 16 + fr][32 + fq * 8];
      acc[mt] = __builtin_amdgcn_mfma_f32_16x16x32_bf16(pa0, vb0, acc[mt], 0, 0, 0);
      acc[mt] = __builtin_amdgcn_mfma_f32_16x16x32_bf16(pa1, vb1, acc[mt], 0, 0, 0);
    }
  }
  __syncthreads();
#pragma unroll
  for (int u = 0; u < U_; u++) {
    const int mt = u >> 4, fqq = (u >> 2) & 3, r = u & 3;
    float* pb = part + ((size_t)(bh * NSPLIT + split) * U_ + u) * 65;
    if (fq == fqq) pb[1 + wid * 16 + fr] = acc[mt][r];
    if (tid == fqq * 16) pb[0] = S_total[u];
  }
}

// ---------- combine splits; dctx = ctx/S - Vmean ----------
__global__ __launch_bounds__(256) void attn_stage2(const float* __restrict__ part,
    const float* __restrict__ Vm, float* __restrict__ dctx) {
  const int bh = blockIdx.x;
  const int wid = threadIdx.x >> 6, lane = threadIdx.x & 63;
  for (int u = wid; u < U_; u += 4) {
    float S = 0.f, c = 0.f;
#pragma unroll
    for (int sp = 0; sp < NSPLIT; sp++) {
      const float* pb = part + ((size_t)(bh * NSPLIT + sp) * U_ + u) * 65;
      S += pb[0];
      c += pb[1 + lane];
    }
    dctx[((size_t)bh * U_ + u) * 64 + lane] = c / S - Vm[bh * 64 + lane];
  }
}

// ---------- base[b][:] = concat_h(Vmean) @ Wo + bo ----------
__global__ __launch_bounds__(256) void base_k(const float* __restrict__ Vm,
    const float* __restrict__ Wo, const float* __restrict__ bo, float* __restrict__ base) {
  const int b = blockIdx.y;
  const int j = blockIdx.x * 256 + threadIdx.x;
  float acc = bo[j];
#pragma unroll 8
  for (int i = 0; i < DM_; i++) acc += Vm[b * DM_ + i] * Wo[(size_t)i * DM_ + j];
  base[b * DM_ + j] = acc;
}

// ---------- gemm_upd: rowupd[bh][u][:] = dctx[bh] @ Wo_h ----------
__global__ __launch_bounds__(256) void gemm_upd(const float* __restrict__ dctx,
    const float* __restrict__ Wo, float* __restrict__ rowupd) {
  const int bh = blockIdx.y, h = bh & 15;
  const int col = blockIdx.x * 256 + threadIdx.x;
  __shared__ float dc[U_][68];
  for (int e = threadIdx.x; e < U_ * 64; e += 256) {
    const int u = e >> 6, d = e & 63;
    dc[u][d] = dctx[(size_t)bh * U_ * 64 + e];
  }
  __syncthreads();
  float acc[U_];
#pragma unroll
  for (int u = 0; u < U_; u++) acc[u] = 0.f;
  for (int d = 0; d < 64; d++) {
    const float w = Wo[(size_t)(h * 64 + d) * DM_ + col];
#pragma unroll
    for (int u = 0; u < U_; u++) acc[u] += dc[u][d] * w;   // dc broadcast read
  }
#pragma unroll
  for (int u = 0; u < U_; u++)
    rowupd[((size_t)bh * U_ + u) * DM_ + col] = acc[u];
}

// ---------- build_list: per selected row, head-mask + slot ----------
__global__ __launch_bounds__(256) void build_list(const int* __restrict__ topidx,
    int* __restrict__ rowmask, unsigned char* __restrict__ slotU) {
  const int i = blockIdx.x * 256 + threadIdx.x;
  if (i >= BH_ * U_) return;
  const int bh = i / U_, u = i - bh * U_;
  const int b = bh >> 4, h = bh & 15;
  const int key = b * L_ + topidx[i];
  slotU[key * 16 + h] = (unsigned char)u;
  atomicOr(&rowmask[key], 1 << h);
}

// ---------- fill2: out[row] = base[b] (+ fixed-h-order sum of head updates) ----------
__global__ __launch_bounds__(256) void fill2(const float* __restrict__ rowupd,
    const float* __restrict__ base, const int* __restrict__ rowmask,
    const unsigned char* __restrict__ slotU, float* __restrict__ out) {
  const int key = blockIdx.x;                    // 0..ML_-1
  const int b = key >> 12;                       // L_ = 4096
  const int mask = rowmask[key];
  const int j4 = threadIdx.x * 4;
  float4 a = *(const float4*)&base[b * DM_ + j4];
  if (mask) {
#pragma unroll
    for (int h = 0; h < 16; h++) {
      if (mask & (1 << h)) {
        const int u = slotU[key * 16 + h];
        const float4 r = *(const float4*)&rowupd[((size_t)(b * 16 + h) * U_ + u) * DM_ + j4];
        a.x += r.x; a.y += r.y; a.z += r.z; a.w += r.w;
      }
    }
  }
  *(float4*)&out[(size_t)key * DM_ + j4] = a;
}

extern "C" void kernel_launch(void* const* d_in, const int* in_sizes, int n_in,
                              void* d_out, int out_size, void* d_ws, size_t ws_size,
                              hipStream_t stream) {
  const float* queries = (const float*)d_in[0];
  const float* keys    = (const float*)d_in[1];
  const float* values  = (const float*)d_in[2];
  const float* Wq = (const float*)d_in[3]; const float* bq = (const float*)d_in[4];
  const float* Wk = (const float*)d_in[5]; const float* bk = (const float*)d_in[6];
  const float* Wv = (const float*)d_in[7]; const float* bv = (const float*)d_in[8];
  const float* Wo = (const float*)d_in[9]; const float* bo = (const float*)d_in[10];
  const int* sidx = (const int*)d_in[11];

  // K (row-major) and V^T live as bf16 in d_out until the epilogue
  unsigned short* Kbf = (unsigned short*)d_out;
  unsigned short* VT  = Kbf + (size_t)ML_ * DM_;

  uint8_t* p = (uint8_t*)d_ws;
  auto carve = [&](size_t bytes) { uint8_t* r = p; p += (bytes + 255) & ~(size_t)255; return r; };
  float* QKs = (float*)carve((size_t)ML_ * NP_ * 4);                        // 100.7 MB
  unsigned short* Ph = (unsigned short*)carve((size_t)B_ * NP_ * DM_ * 2);  // 12.6 MB
  unsigned short* WkT = (unsigned short*)carve((size_t)DM_ * DM_ * 2);
  unsigned short* WvT = (unsigned short*)carve((size_t)DM_ * DM_ * 2);
  float* Mbuf  = (float*)carve((size_t)BH_ * L_ * 4);                       // 2.1 MB
  float* Ksamp = (float*)carve((size_t)BH_ * U_ * 64 * 4);                  // 1.5 MB
  float* kpart = (float*)carve((size_t)4 * B_ * U_ * 1024 * 4);             // 5.9 MB
  float* qpart = (float*)carve((size_t)16 * BH_ * 48 * 64 * 4);             // 25.2 MB
  int*   list  = (int*)carve((size_t)BH_ * CAP_ * 4);                       // 256 KB
  float* candM = (float*)carve((size_t)BH_ * CAP_ * 4);                     // 256 KB
  int*   cntb  = (int*)carve((size_t)BH_ * 4);
  int*   topidx = (int*)carve((size_t)BH_ * U_ * 4);
  float* Vm    = (float*)carve((size_t)BH_ * 64 * 4);
  unsigned short* Qbf = (unsigned short*)carve((size_t)BH_ * 48 * 64 * 2);  // 786 KB
  int*   rowmask = (int*)carve((size_t)B_ * L_ * 4);                        // 128 KB (memset)
  unsigned char* slotU = (unsigned char*)carve((size_t)B_ * L_ * 16);       // 512 KB
  const size_t need = (size_t)(p - (uint8_t*)d_ws);
  if (ws_size < need)
    fprintf(stderr, "ATHENA_WS: need %zu have %zu (WILL FAULT)\n", need, ws_size);

  // late-phase buffers alias QKs (dead after mpass)
  uint8_t* ap = (uint8_t*)QKs;
  auto acarve = [&](size_t bytes) { uint8_t* r = ap; ap += (bytes + 255) & ~(size_t)255; return r; };
  float* part  = (float*)acarve((size_t)BH_ * NSPLIT * U_ * 65 * 4);        // 12 MB
  float* dctx  = (float*)acarve((size_t)BH_ * U_ * 64 * 4);
  float* base  = (float*)acarve((size_t)B_ * DM_ * 4);
  float* rowupd = (float*)acarve((size_t)BH_ * U_ * DM_ * 4);               // 23.6 MB

  ksel3<<<dim3(4, B_, 12), 256, 0, stream>>>(keys, Wk, sidx, kpart);
  ksel_comb<<<(B_ * U_ * 1024) / 256, 256, 0, stream>>>(kpart, bk, Ksamp);
  pform_k<<<BH_, 256, 0, stream>>>(Wq, Ksamp, Ph);
  wT_single<<<4096, 256, 0, stream>>>(Wk, WkT);
  wT_single<<<4096, 256, 0, stream>>>(Wv, WvT);

  // full-tensor fused GEMMs (tail-free at 4 blocks/CU for MODE 0/1)
  gemm_f<0><<<dim3(8, 256), 256, 0, stream>>>(keys, WkT, bk, Kbf);
  gemm_f<1><<<dim3(8, 256), 256, 0, stream>>>(values, WvT, bv, VT);
  gemm_f<2><<<dim3(6, 256), 256, 0, stream>>>(queries, Ph, bq, QKs);
  mpass_k<<<(ML_ * 16) / 256, 256, 0, stream>>>(QKs, Mbuf);

  select_a<<<BH_, 256, 0, stream>>>(Mbuf, list, cntb);
  exactM2<<<dim3(BH_, 16), 256, 0, stream>>>(queries, Wq, bq, Ksamp, list, cntb, candM);
  select_b<<<BH_, 256, 0, stream>>>(candM, list, cntb, topidx);
  qsel3<<<dim3(BH_, 12), 256, 0, stream>>>(queries, Wq, topidx, qpart);
  qsel_comb<<<(BH_ * 48 * 64) / 256, 256, 0, stream>>>(qpart, bq, Qbf);
  vmean_vt<<<(BH_ * 64) / 4, 256, 0, stream>>>(VT, Vm);
  attn_stage1<<<dim3(BH_, NSPLIT), 256, 0, stream>>>(Qbf, Kbf, VT, part);
  attn_stage2<<<BH_, 256, 0, stream>>>(part, Vm, dctx);
  base_k<<<dim3(DM_ / 256, B_), 256, 0, stream>>>(Vm, Wo, bo, base);

  // epilogue: deterministic
  hipMemsetAsync(rowmask, 0, (size_t)B_ * L_ * 4, stream);
  gemm_upd<<<dim3(4, BH_), 256, 0, stream>>>(dctx, Wo, rowupd);
  build_list<<<(BH_ * U_ + 255) / 256, 256, 0, stream>>>(topidx, rowmask, slotU);
  fill2<<<ML_, 256, 0, stream>>>(rowupd, base, rowmask, slotU, (float*)d_out);
}